// Round 13
// baseline (634.157 us; speedup 1.0000x reference)
//
#include <hip/hip_runtime.h>
#include <hip/hip_bf16.h>

#define BB 8
#define NN 2048
#define KK 20
#define BN (BB*NN)
#define RSQ 0.99999500003749969f   // 1/sqrt(1+1e-5)

// ---------------- workspace layout (float-slot units) ----------------
constexpr size_t OFF_XX  = 0;                          // BN
constexpr size_t OFF_X1  = OFF_XX  + BN;               // BN*64
constexpr size_t OFF_X2  = OFF_X1  + (size_t)BN*64;    // BN*64
constexpr size_t OFF_X3  = OFF_X2  + (size_t)BN*64;    // BN*128
constexpr size_t OFF_X4  = OFF_X3  + (size_t)BN*128;   // BN*256 (split-scratch pre-gather)
constexpr size_t OFF_SC  = OFF_X4  + (size_t)BN*256;   // BN*160 (L1 qp + fallback chunked qp + W5 bf16 tail)
constexpr size_t OFF_ID  = OFF_SC  + (size_t)BN*160;   // int BN*20
constexpr size_t OFF_W5T = OFF_ID  + (size_t)BN*20;    // 512*512 (big path: tiled WT splits live here)
constexpr size_t OFF_MX  = OFF_W5T + 512*512;
constexpr size_t OFF_MN  = OFF_MX  + BB*512;
constexpr size_t OFF_WT2 = OFF_MN  + BB*512;           // cat [64][128]
constexpr size_t OFF_WT3 = OFF_WT2 + 8192;             // cat [64][256]
constexpr size_t OFF_WT4 = OFF_WT3 + 16384;            // cat [128][512]
constexpr size_t WS_END  = OFF_WT4 + 65536;            // 11,714,560 floats
// big region (probed at runtime): dist chunk (4 batches) + qp buffer + bf16 xcat post-sel
constexpr size_t OFF_BIG = WS_END;
constexpr size_t OFF_XCAT = OFF_BIG + (size_t)16*1024*1024;  // bf16 xcat h/m/l (dist region tail, post-KNN)
constexpr size_t WS_BIG_END = OFF_BIG + (size_t)BB*NN*NN;   // 172.7 MiB
static_assert(OFF_ID - OFF_X3 >= (size_t)4096*2048, "fallback dual dist fits");
static_assert(OFF_XCAT + (size_t)BN*768 <= WS_BIG_END, "xcat h/m/l fits in dist region");

typedef unsigned short u16;
typedef __attribute__((ext_vector_type(8))) short short8;
typedef __attribute__((ext_vector_type(8))) unsigned short ushort8;
typedef __attribute__((ext_vector_type(4))) float f32x4;

// tiled WT split offsets (u16 units) within the W5T region (big path only)
constexpr size_t WTS_2H = 0,      WTS_2M = 8192,   WTS_2L = 16384;
constexpr size_t WTS_3H = 24576,  WTS_3M = 40960,  WTS_3L = 57344;
constexpr size_t WTS_4H = 73728,  WTS_4M = 139264, WTS_4L = 204800;   // end 270336 u16 <= 524288

__device__ inline unsigned encf(float f){ unsigned u=__float_as_uint(f); return (u&0x80000000u)? ~u : (u|0x80000000u); }
__device__ inline float decf(unsigned e){ unsigned u=(e&0x80000000u)? (e&0x7fffffffu) : ~e; return __uint_as_float(u); }
__device__ inline float lrelu(float h){ return h>=0.f ? h : 0.2f*h; }
__device__ inline u16 bf16rne(float x){
  unsigned u = __float_as_uint(x);
  return (u16)((u + 0x7FFFu + ((u>>16)&1u)) >> 16);
}
__device__ inline float bf16f(u16 h){ return __uint_as_float((unsigned)h<<16); }
// exact 3-way split: x == h + m + l for normal fp32 (24 mantissa bits covered)
__device__ inline void bf16split3(float v, u16& h, u16& m, u16& l){
  h = bf16rne(v);  float r1 = v  - bf16f(h);
  m = bf16rne(r1); float r2 = r1 - bf16f(m);
  l = bf16rne(r2);
}

__device__ inline float readlane_f(float v, int sl){
  return __int_as_float(__builtin_amdgcn_readlane(__float_as_int(v), sl));
}

// Wave-cooperative sorted-top-20 insertion (cv known > theta on call).
#define INSERT_CAND(cv, ci) { \
  unsigned long long mge = __ballot((lv > cv) || (lv == cv && li < ci)); \
  int pos = __popcll(mge); \
  float upv = __shfl_up(lv, 1); \
  int   upi = __shfl_up(li, 1); \
  bool shift = (lane > pos) && (lane < KK); \
  lv = (lane == pos) ? cv : (shift ? upv : lv); \
  li = (lane == pos) ? ci : (shift ? upi : li); \
  theta = readlane_f(lv, KK-1); }

// Bitonic full sort of 64 (value desc, index asc on ties) across lanes; (v,vi) in registers.
#define BITONIC64_DESC(v, vi) { \
  _Pragma("unroll") \
  for(int k=2; k<=64; k<<=1){ \
    _Pragma("unroll") \
    for(int j=k>>1; j>=1; j>>=1){ \
      float ov = __shfl_xor(v, j); \
      int   oi = __shfl_xor(vi, j); \
      int partner = lane ^ j; \
      bool keepFirst = (((lane & k) == 0)) == (lane < partner); \
      bool before = (v > ov) || (v == ov && vi < oi); \
      if(keepFirst != before){ v = ov; vi = oi; } \
    } \
  } }

// 6-product split-bf16 MFMA macro: acc over Ah/Am/Al x Bh/Bm/Bl
#define MFMA6(ACC, AH, AM, AL, BH, BM, BL) { \
  ACC = __builtin_amdgcn_mfma_f32_16x16x32_bf16(AH, BH, ACC, 0, 0, 0); \
  ACC = __builtin_amdgcn_mfma_f32_16x16x32_bf16(AH, BM, ACC, 0, 0, 0); \
  ACC = __builtin_amdgcn_mfma_f32_16x16x32_bf16(AM, BH, ACC, 0, 0, 0); \
  ACC = __builtin_amdgcn_mfma_f32_16x16x32_bf16(AH, BL, ACC, 0, 0, 0); \
  ACC = __builtin_amdgcn_mfma_f32_16x16x32_bf16(AL, BH, ACC, 0, 0, 0); \
  ACC = __builtin_amdgcn_mfma_f32_16x16x32_bf16(AM, BM, ACC, 0, 0, 0); }

// ======== fragment-major tiled split layout ========
// split[rowGroup][kTile][lane=64][8]  (u16). lane l -> row = rg*16 + (l&15), k = kt*32 + (l>>4)*8.

// ---------------- prep: weights transposes + splits + enc ----------------
__global__ void prep_k(const float* W5, const float* W2, const float* W3, const float* W4,
                       float* W5T, float* WT2, float* WT3, float* WT4,
                       u16* w5h, u16* w5m, u16* w5l, u16* wts,
                       unsigned* mx, unsigned* mn, int big){
  int i = blockIdx.x*256 + threadIdx.x;     // 262144
  if(!big){ int o = i>>9, c = i&511; W5T[c*512+o] = W5[i]; }   // fp32 W5T only for fallback
  { // tiled split of W5 (B-side rows = output cols o, k = input c). KT=16.
    int rg = i>>13, kt = (i>>9)&15, l = (i>>3)&63, j = i&7;
    int o = rg*16 + (l&15);
    int c = kt*32 + ((l>>4)<<3) + j;
    u16 h,m,lo; bf16split3(W5[(size_t)o*512 + c], h, m, lo);
    w5h[i]=h; w5m[i]=m; w5l[i]=lo; }
  if(i < 65536){ int c = i>>9, o = i&511;   // W4: [256][256] -> cat [128][512]
    WT4[i] = (o<256) ? W4[(size_t)o*256 + c] : W4[(size_t)(o-256)*256 + 128 + c]; }
  if(i < 16384){ int c = i>>8, o = i&255;   // W3: [128][128] -> cat [64][256]
    WT3[i] = (o<128) ? W3[(size_t)o*128 + c] : W3[(size_t)(o-128)*128 + 64 + c]; }
  if(i <  8192){ int c = i>>7, o = i&127;   // W2: [64][128] -> cat [64][128]
    WT2[i] = (o<64) ? W2[(size_t)o*128 + c] : W2[(size_t)(o-64)*128 + 64 + c]; }
  if(big){
    if(i < 65536){ // WT4 tiled split: rg over o (32), kt over c (4)
      int rg=i>>11, kt=(i>>9)&3, l=(i>>3)&63, j=i&7;
      int o = rg*16 + (l&15);
      int c = kt*32 + ((l>>4)<<3) + j;
      float v = (o<256) ? W4[(size_t)o*256 + c] : W4[(size_t)(o-256)*256 + 128 + c];
      u16 h,m,lo; bf16split3(v,h,m,lo);
      wts[WTS_4H+i]=h; wts[WTS_4M+i]=m; wts[WTS_4L+i]=lo; }
    if(i < 16384){ // WT3 tiled split: rg over o (16), kt over c (2)
      int rg=i>>10, kt=(i>>9)&1, l=(i>>3)&63, j=i&7;
      int o = rg*16 + (l&15);
      int c = kt*32 + ((l>>4)<<3) + j;
      float v = (o<128) ? W3[(size_t)o*128 + c] : W3[(size_t)(o-128)*128 + 64 + c];
      u16 h,m,lo; bf16split3(v,h,m,lo);
      wts[WTS_3H+i]=h; wts[WTS_3M+i]=m; wts[WTS_3L+i]=lo; }
    if(i < 8192){  // WT2 tiled split: rg over o (8), kt over c (2)
      int rg=i>>10, kt=(i>>9)&1, l=(i>>3)&63, j=i&7;
      int o = rg*16 + (l&15);
      int c = kt*32 + ((l>>4)<<3) + j;
      float v = (o<64) ? W2[(size_t)o*128 + c] : W2[(size_t)(o-64)*128 + 64 + c];
      u16 h,m,lo; bf16split3(v,h,m,lo);
      wts[WTS_2H+i]=h; wts[WTS_2M+i]=m; wts[WTS_2L+i]=lo; }
  }
  if(i <  4096){ mx[i] = 0x007FFFFFu; mn[i] = 0xFF800000u; }
}

// ---------------- KNN ----------------
template<int C>
__launch_bounds__(256) __global__ void sqnorm_k(const float* X, float* xx){
  int i = blockIdx.x*256 + threadIdx.x;   // BN
  const float* r = X + (size_t)i*C;
  float s = 0.f;
  #pragma unroll
  for(int c=0;c<C;c++) s = fmaf(r[c], r[c], s);
  xx[i] = s;
}

// 3-way bf16 split of X [BN][C] into fragment-major tiled layout.
template<int C>
__launch_bounds__(256) __global__ void split_k(const float* __restrict__ X,
    u16* __restrict__ xh, u16* __restrict__ xm, u16* __restrict__ xl){
  constexpr int KT = C/32;
  const size_t t = (size_t)blockIdx.x*256 + threadIdx.x;   // BN*C/8 chunks
  const int l = (int)(t & 63);
  const size_t tile = t >> 6;               // rgG*KT + kt
  const int kt = (int)(tile & (KT-1));
  const size_t rgG = tile / KT;             // global row group (BN/16 total)
  const size_t row = rgG*16 + (l & 15);
  const int k = kt*32 + ((l>>4)<<3);
  const float* p = X + row*C + k;
  float4 v0 = *(const float4*)p;
  float4 v1 = *(const float4*)(p+4);
  float vs[8] = {v0.x,v0.y,v0.z,v0.w,v1.x,v1.y,v1.z,v1.w};
  ushort8 H,M,L;
  #pragma unroll
  for(int j=0;j<8;j++){ u16 h,m,lo; bf16split3(vs[j],h,m,lo); H[j]=h; M[j]=m; L[j]=lo; }
  *(ushort8*)(xh + t*8) = H;
  *(ushort8*)(xm + t*8) = M;
  *(ushort8*)(xl + t*8) = L;
}

#define FMA_ROW(I) \
  acc[I][0]=fmaf(a,b0v,acc[I][0]); acc[I][1]=fmaf(a,b1v,acc[I][1]); \
  acc[I][2]=fmaf(a,b2v,acc[I][2]); acc[I][3]=fmaf(a,b3v,acc[I][3]); \
  acc[I][4]=fmaf(a,b4v,acc[I][4]); acc[I][5]=fmaf(a,b5v,acc[I][5]); \
  acc[I][6]=fmaf(a,b6v,acc[I][6]); acc[I][7]=fmaf(a,b7v,acc[I][7]);

// fallback fp32 dist GEMM
template<int C>
__launch_bounds__(256) __global__ void gemm_dist_k(const float* __restrict__ X, const float* __restrict__ xx,
                                                   float* __restrict__ dist, int b0){
  constexpr int AST = 188;
  __shared__ __align__(16) float a_sh[16*AST];
  __shared__ __align__(16) float b_sh[16*AST];
  __shared__ float sxn[128], sxm[128];
  const int tid = threadIdx.x;
  const int b   = b0 + blockIdx.z;
  const int mtile = blockIdx.x*128;
  const int ntile = blockIdx.y*128;
  const int tn = tid & 15, tm = tid >> 4;
  const float* Xb  = X  + (size_t)b*NN*C;
  const float* xxb = xx + (size_t)b*NN;
  if(tid < 128) sxn[tid] = xxb[ntile + tid];
  else          sxm[tid-128] = xxb[mtile + tid-128];
  float acc[8][8];
  #pragma unroll
  for(int i=0;i<8;i++){
    #pragma unroll
    for(int j=0;j<8;j++) acc[i][j]=0.f;
  }
  for(int cc=0; cc<C; cc+=16){
    __syncthreads();
    #pragma unroll
    for(int s=0;s<2;s++){
      int ii = tid + 256*s; int r = ii>>2, q = ii&3;
      int pr = r + 4*(r>>3);
      float4 va = *(const float4*)&Xb[(size_t)(ntile + r)*C + cc + 4*q];
      a_sh[(4*q+0)*AST + pr]=va.x; a_sh[(4*q+1)*AST + pr]=va.y;
      a_sh[(4*q+2)*AST + pr]=va.z; a_sh[(4*q+3)*AST + pr]=va.w;
      float4 vb = *(const float4*)&Xb[(size_t)(mtile + r)*C + cc + 4*q];
      b_sh[(4*q+0)*AST + pr]=vb.x; b_sh[(4*q+1)*AST + pr]=vb.y;
      b_sh[(4*q+2)*AST + pr]=vb.z; b_sh[(4*q+3)*AST + pr]=vb.w;
    }
    __syncthreads();
    #pragma unroll
    for(int c=0;c<16;c++){
      float4 A0 = *(const float4*)&a_sh[c*AST + 12*tn];
      float4 A1 = *(const float4*)&a_sh[c*AST + 12*tn + 4];
      float4 B0 = *(const float4*)&b_sh[c*AST + 12*tm];
      float4 B1 = *(const float4*)&b_sh[c*AST + 12*tm + 4];
      float b0v=B0.x,b1v=B0.y,b2v=B0.z,b3v=B0.w,b4v=B1.x,b5v=B1.y,b6v=B1.z,b7v=B1.w;
      float a;
      a=A0.x; FMA_ROW(0)
      a=A0.y; FMA_ROW(1)
      a=A0.z; FMA_ROW(2)
      a=A0.w; FMA_ROW(3)
      a=A1.x; FMA_ROW(4)
      a=A1.y; FMA_ROW(5)
      a=A1.z; FMA_ROW(6)
      a=A1.w; FMA_ROW(7)
    }
  }
  float xnr[8], xmr[8];
  #pragma unroll
  for(int i=0;i<8;i++){ xnr[i]=sxn[tn*8+i]; xmr[i]=sxm[tm*8+i]; }
  const size_t rowb = (size_t)blockIdx.z*NN + ntile + tn*8;
  #pragma unroll
  for(int i=0;i<8;i++){
    float4 w0, w1;
    w0.x=(2.f*acc[i][0]-xnr[i])-xmr[0]; w0.y=(2.f*acc[i][1]-xnr[i])-xmr[1];
    w0.z=(2.f*acc[i][2]-xnr[i])-xmr[2]; w0.w=(2.f*acc[i][3]-xnr[i])-xmr[3];
    w1.x=(2.f*acc[i][4]-xnr[i])-xmr[4]; w1.y=(2.f*acc[i][5]-xnr[i])-xmr[5];
    w1.z=(2.f*acc[i][6]-xnr[i])-xmr[6]; w1.w=(2.f*acc[i][7]-xnr[i])-xmr[7];
    float* dp = dist + (rowb + i)*NN + mtile + tm*8;
    *(float4*)dp = w0;
    *(float4*)(dp+4) = w1;
  }
}

// big path: exact-fp32-quality dist via split-bf16 MFMA with LDS-staged fragments.
// Block 128q x 64c, 4 waves (2x2), wave 64q x 32c. Per kt: coop-stage 36 x 1KB chunks
// (24 A + 12 B) into LDS (each fetched once per block, not once per sharing wave),
// then ds_read_b128 fragments. Accumulation order identical to register version.
template<int C>
__launch_bounds__(256) __global__ void mfma_dist_k(const u16* __restrict__ xh, const u16* __restrict__ xm,
    const u16* __restrict__ xl, const float* __restrict__ xx, float* __restrict__ dist, int b0){
  constexpr int KT = C/32;
  __shared__ u16 lds[36*512];
  const int tid = threadIdx.x;
  const int l  = tid & 63, wv = tid >> 6;
  const int lg = l >> 4, lr = l & 15;
  const int cz = blockIdx.z;
  const int b  = b0 + cz;
  const int qrow0 = blockIdx.y*128 + (wv>>1)*64;   // query rows (A side, dist row)
  const int crow0 = blockIdx.x*64 + (wv&1)*32;     // candidate rows (B side, dist col)
  const size_t brg = (size_t)b*(NN/16);
  const size_t rgA = brg + (size_t)blockIdx.y*8;   // block A rowgroup base (8 groups)
  const size_t rgB = brg + (size_t)blockIdx.x*4;   // block B rowgroup base (4 groups)
  f32x4 acc[4][2];
  #pragma unroll
  for(int m=0;m<4;m++){
    #pragma unroll
    for(int n=0;n<2;n++) acc[m][n] = (f32x4){0.f,0.f,0.f,0.f};
  }
  for(int kt=0; kt<KT; kt++){
    __syncthreads();
    #pragma unroll
    for(int p=0;p<9;p++){
      int c  = p*4 + (tid>>6);
      int ln = tid & 63;
      const u16* src; size_t off;
      if(c < 24){ int s = c>>3, rg = c&7;
        src = (s==0) ? xh : (s==1) ? xm : xl;
        off = ((rgA + rg)*KT + kt)*512 + (size_t)ln*8;
      } else { int cc = c-24; int s = cc>>2, cg = cc&3;
        src = (s==0) ? xh : (s==1) ? xm : xl;
        off = ((rgB + cg)*KT + kt)*512 + (size_t)ln*8;
      }
      *(ushort8*)&lds[c*512 + ln*8] = *(const ushort8*)(src + off);
    }
    __syncthreads();
    short8 Bh[2], Bm[2], Bl[2];
    #pragma unroll
    for(int n=0;n<2;n++){ int cg = (wv&1)*2 + n;
      Bh[n] = *(const short8*)&lds[(24+cg)*512 + l*8];
      Bm[n] = *(const short8*)&lds[(28+cg)*512 + l*8];
      Bl[n] = *(const short8*)&lds[(32+cg)*512 + l*8];
    }
    #pragma unroll
    for(int m=0;m<4;m++){ int rg = (wv>>1)*4 + m;
      short8 Ah_ = *(const short8*)&lds[(   rg)*512 + l*8];
      short8 Am_ = *(const short8*)&lds[( 8+rg)*512 + l*8];
      short8 Al_ = *(const short8*)&lds[(16+rg)*512 + l*8];
      #pragma unroll
      for(int n=0;n<2;n++){
        MFMA6(acc[m][n], Ah_, Am_, Al_, Bh[n], Bm[n], Bl[n])
      }
    }
  }
  const float* xxb = xx + (size_t)b*NN;
  float xxc[2];
  #pragma unroll
  for(int n=0;n<2;n++) xxc[n] = xxb[crow0 + n*16 + lr];
  #pragma unroll
  for(int m=0;m<4;m++){
    #pragma unroll
    for(int r=0;r<4;r++){
      int qr = qrow0 + m*16 + 4*lg + r;
      float xq = xxb[qr];
      float* dp = dist + ((size_t)cz*NN + qr)*NN + crow0;
      #pragma unroll
      for(int n=0;n<2;n++) dp[n*16 + lr] = (2.f*acc[m][n][r] - xq) - xxc[n];
    }
  }
}

// Wave-cooperative top-20: max-of-4 bitonic warm start + slim insertions, float4 scan.
__launch_bounds__(256) __global__ void sel_k(const float* __restrict__ dist, int* __restrict__ id,
                                             int b0, int nrows){
  const int w = (blockIdx.x*256 + threadIdx.x) >> 6;
  const int lane = threadIdx.x & 63;
  if(w >= nrows) return;
  const float* dr = dist + (size_t)w*NN;
  float4 c0 = *(const float4*)&dr[4*lane];
  float cd0[4] = {c0.x, c0.y, c0.z, c0.w};
  int jbest = 0; float v = cd0[0];
  #pragma unroll
  for(int j=1;j<4;j++){ if(cd0[j] > v){ v = cd0[j]; jbest = j; } }
  int vi = 4*lane + jbest;
  BITONIC64_DESC(v, vi)
  float lv = (lane < KK) ? v : -INFINITY;
  int   li = (lane < KK) ? vi : 0;
  float theta = readlane_f(lv, KK-1);
  #pragma unroll
  for(int j=0;j<4;j++){
    float cand = (j == jbest) ? -INFINITY : cd0[j];
    unsigned long long bal = __ballot(cand > theta);
    while(bal){
      int bpos = __ffsll((unsigned long long)bal) - 1;
      bal &= bal - 1;
      float cv = readlane_f(cand, bpos);
      if(cv > theta){
        int ci = 4*bpos + j;
        INSERT_CAND(cv, ci)
      }
    }
  }
  for(int ms=256; ms<NN; ms+=256){
    float4 c4 = *(const float4*)&dr[ms + 4*lane];
    #pragma unroll
    for(int j=0;j<4;j++){
      float cand = (j==0)?c4.x:(j==1)?c4.y:(j==2)?c4.z:c4.w;
      unsigned long long bal = __ballot(cand > theta);
      while(bal){
        int bpos = __ffsll((unsigned long long)bal) - 1;
        bal &= bal - 1;
        float cv = readlane_f(cand, bpos);
        if(cv > theta){
          int ci = ms + 4*bpos + j;
          INSERT_CAND(cv, ci)
        }
      }
    }
  }
  if(lane < KK) id[((size_t)b0*NN + w)*KK + lane] = li;
}

// L1 fused: inline C=3 distances + inline sqnorm, max-of-4 bitonic warm start.
__launch_bounds__(256) __global__ void sel3_k(const float* __restrict__ X, int* __restrict__ id){
  const int gw = (blockIdx.x*256 + threadIdx.x) >> 6;
  const int lane = threadIdx.x & 63;
  const int b = gw >> 11, n = gw & 2047;
  const float* Xb  = X + (size_t)b*NN*3;
  const float x0v = Xb[n*3], x1v = Xb[n*3+1], x2v = Xb[n*3+2];
  float xxn = 0.f;
  xxn = fmaf(x0v, x0v, xxn); xxn = fmaf(x1v, x1v, xxn); xxn = fmaf(x2v, x2v, xxn);
  float lv, theta; int li;
  {
    const float* p = Xb + (size_t)(4*lane)*3;
    float4 va = *(const float4*)p;
    float4 vb = *(const float4*)(p+4);
    float4 vc = *(const float4*)(p+8);
    float cx[4] = {va.x, va.w, vb.z, vc.y};
    float cy[4] = {va.y, vb.x, vb.w, vc.z};
    float cz[4] = {va.z, vb.y, vc.x, vc.w};
    float cd[4];
    #pragma unroll
    for(int j=0;j<4;j++){
      float s = 0.f;
      s = fmaf(x0v, cx[j], s); s = fmaf(x1v, cy[j], s); s = fmaf(x2v, cz[j], s);
      float xxm = 0.f;
      xxm = fmaf(cx[j], cx[j], xxm); xxm = fmaf(cy[j], cy[j], xxm); xxm = fmaf(cz[j], cz[j], xxm);
      cd[j] = (2.f*s - xxn) - xxm;
    }
    int jbest = 0; float v = cd[0];
    #pragma unroll
    for(int j=1;j<4;j++){ if(cd[j] > v){ v = cd[j]; jbest = j; } }
    int vi = 4*lane + jbest;
    BITONIC64_DESC(v, vi)
    lv = (lane < KK) ? v : -INFINITY;
    li = (lane < KK) ? vi : 0;
    theta = readlane_f(lv, KK-1);
    #pragma unroll
    for(int j=0;j<4;j++){
      float cand = (j == jbest) ? -INFINITY : cd[j];
      unsigned long long bal = __ballot(cand > theta);
      while(bal){
        int bpos = __ffsll((unsigned long long)bal) - 1;
        bal &= bal - 1;
        float cv = readlane_f(cand, bpos);
        if(cv > theta){
          int ci = 4*bpos + j;
          INSERT_CAND(cv, ci)
        }
      }
    }
  }
  for(int ms=256; ms<NN; ms+=256){
    const float* p = Xb + (size_t)(ms + 4*lane)*3;
    float4 va = *(const float4*)p;
    float4 vb = *(const float4*)(p+4);
    float4 vc = *(const float4*)(p+8);
    float cx[4] = {va.x, va.w, vb.z, vc.y};
    float cy[4] = {va.y, vb.x, vb.w, vc.z};
    float cz[4] = {va.z, vb.y, vc.x, vc.w};
    float cd[4];
    #pragma unroll
    for(int j=0;j<4;j++){
      float s = 0.f;
      s = fmaf(x0v, cx[j], s); s = fmaf(x1v, cy[j], s); s = fmaf(x2v, cz[j], s);
      float xxm = 0.f;
      xxm = fmaf(cx[j], cx[j], xxm); xxm = fmaf(cy[j], cy[j], xxm); xxm = fmaf(cz[j], cz[j], xxm);
      cd[j] = (2.f*s - xxn) - xxm;
    }
    #pragma unroll
    for(int j=0;j<4;j++){
      float cand = cd[j];
      unsigned long long bal = __ballot(cand > theta);
      while(bal){
        int bpos = __ffsll((unsigned long long)bal) - 1;
        bal &= bal - 1;
        float cv = readlane_f(cand, bpos);
        if(cv > theta){
          int ci = ms + 4*bpos + j;
          INSERT_CAND(cv, ci)
        }
      }
    }
  }
  if(lane < KK) id[(size_t)gw*KK + lane] = li;
}

// ---------------- qp ----------------
// L1: writes interleaved qp[row][128]: q at 0..63, p at 64..127
__launch_bounds__(256) __global__ void qp3_k(const float* X, const float* W, float* qp){
  const int t   = blockIdx.x*256 + threadIdx.x;
  const int row = t >> 3;
  const int c0  = (t & 7) * 8;
  float xn[3];
  #pragma unroll
  for(int c=0;c<3;c++) xn[c] = X[(size_t)row*3 + c];
  for(int oi=c0; oi<c0+8; oi++){
    const float* w = W + (size_t)oi*6;
    float aq=0.f, ap=0.f;
    #pragma unroll
    for(int c=0;c<3;c++){ aq = fmaf(xn[c], w[c], aq); ap = fmaf(xn[c], w[3+c], ap); }
    qp[(size_t)row*128 + oi]      = aq;
    qp[(size_t)row*128 + 64 + oi] = ap;
  }
}

// qp via split-bf16 MFMA (layers 2/3/4): qp[BN][W2C] = Xsplit * WTsplit.
// Grid (BN/128, W2C/64); block 128r x 64c; wave 64r x 32c.
template<int KT, int W2C>
__launch_bounds__(256) __global__ void qp_mfma_k(const u16* __restrict__ xh, const u16* __restrict__ xm,
    const u16* __restrict__ xl,
    const u16* __restrict__ wh, const u16* __restrict__ wm, const u16* __restrict__ wl,
    float* __restrict__ qp){
  const int tid = threadIdx.x;
  const int l  = tid & 63, wv = tid >> 6;
  const int lg = l >> 4, lr = l & 15;
  const int row0 = blockIdx.x*128 + (wv>>1)*64;
  const int col0 = blockIdx.y*64 + (wv&1)*32;
  f32x4 acc[4][2];
  #pragma unroll
  for(int m=0;m<4;m++){
    #pragma unroll
    for(int n=0;n<2;n++) acc[m][n] = (f32x4){0.f,0.f,0.f,0.f};
  }
  const size_t abase = (size_t)(row0>>4)*KT*512 + (size_t)l*8;
  const size_t bbase = (size_t)(col0>>4)*KT*512 + (size_t)l*8;
  for(int kt=0; kt<KT; kt++){
    short8 Ah[4], Am[4], Al[4], Bh[2], Bm[2], Bl[2];
    #pragma unroll
    for(int m=0;m<4;m++){
      size_t o = abase + (size_t)(m*KT + kt)*512;
      Ah[m] = *(const short8*)(xh + o);
      Am[m] = *(const short8*)(xm + o);
      Al[m] = *(const short8*)(xl + o);
    }
    #pragma unroll
    for(int n=0;n<2;n++){
      size_t o = bbase + (size_t)(n*KT + kt)*512;
      Bh[n] = *(const short8*)(wh + o);
      Bm[n] = *(const short8*)(wm + o);
      Bl[n] = *(const short8*)(wl + o);
    }
    #pragma unroll
    for(int m=0;m<4;m++){
      #pragma unroll
      for(int n=0;n<2;n++){
        MFMA6(acc[m][n], Ah[m], Am[m], Al[m], Bh[n], Bm[n], Bl[n])
      }
    }
  }
  #pragma unroll
  for(int m=0;m<4;m++){
    #pragma unroll
    for(int r=0;r<4;r++){
      int row = row0 + m*16 + 4*lg + r;
      float* dp = qp + (size_t)row*W2C + col0;
      #pragma unroll
      for(int n=0;n<2;n++) dp[n*16 + lr] = acc[m][n][r];
    }
  }
}

// Gather from interleaved qp[row][2*COUT] (q | p); base = p - q computed here.
template<int COUT>
__launch_bounds__(256) __global__ void gather_qp_k(const float* __restrict__ qp, const int* __restrict__ idx,
    const float* g, const float* bb, float* out){
  const int t  = blockIdx.x*256 + threadIdx.x;   // BN*COUT
  const int o  = t % COUT;
  const int bn = t / COUT;
  const int b  = bn >> 11;
  const int* id = idx + (size_t)bn*KK;
  float qv = qp[(size_t)bn*(2*COUT) + o];
  float pv = qp[(size_t)bn*(2*COUT) + COUT + o];
  float base = pv - qv;
  float mx = -INFINITY, mn = INFINITY;
  #pragma unroll
  for(int k=0;k<KK;k++){
    int ik = id[k];
    float v = qp[((size_t)((b<<11) + ik))*(2*COUT) + o];
    mx = fmaxf(mx, v); mn = fminf(mn, v);
  }
  float a  = g[o] * RSQ;
  float bo = bb[o];
  out[(size_t)bn*COUT + o] = lrelu((a >= 0.f ? a*(mx+base) : a*(mn+base)) + bo);
}

// ---- fallback chunked qp (cat weight layout) + chunked gather ----
template<int CIN, int COUT>
__launch_bounds__(256) __global__ void qp64T_k(const float* __restrict__ X, const float* __restrict__ WT,
                                               int cb, float* __restrict__ q, float* __restrict__ bs){
  const int t   = blockIdx.x*256 + threadIdx.x;
  const int row = t >> 3;
  const int o0  = cb + (t & 7) * 8;
  float xn[CIN];
  #pragma unroll
  for(int c=0;c<CIN;c+=4){ float4 v = *(const float4*)(X + (size_t)row*CIN + c);
    xn[c]=v.x; xn[c+1]=v.y; xn[c+2]=v.z; xn[c+3]=v.w; }
  float aq[8], ap[8];
  #pragma unroll
  for(int j=0;j<8;j++){ aq[j]=0.f; ap[j]=0.f; }
  #pragma unroll 4
  for(int c=0;c<CIN;c++){
    float xc = xn[c];
    float4 wa0 = *(const float4*)&WT[(size_t)c*(2*COUT) + o0];
    float4 wa1 = *(const float4*)&WT[(size_t)c*(2*COUT) + o0 + 4];
    float4 wb0 = *(const float4*)&WT[(size_t)c*(2*COUT) + COUT + o0];
    float4 wb1 = *(const float4*)&WT[(size_t)c*(2*COUT) + COUT + o0 + 4];
    aq[0]=fmaf(xc,wa0.x,aq[0]); aq[1]=fmaf(xc,wa0.y,aq[1]); aq[2]=fmaf(xc,wa0.z,aq[2]); aq[3]=fmaf(xc,wa0.w,aq[3]);
    aq[4]=fmaf(xc,wa1.x,aq[4]); aq[5]=fmaf(xc,wa1.y,aq[5]); aq[6]=fmaf(xc,wa1.z,aq[6]); aq[7]=fmaf(xc,wa1.w,aq[7]);
    ap[0]=fmaf(xc,wb0.x,ap[0]); ap[1]=fmaf(xc,wb0.y,ap[1]); ap[2]=fmaf(xc,wb0.z,ap[2]); ap[3]=fmaf(xc,wb0.w,ap[3]);
    ap[4]=fmaf(xc,wb1.x,ap[4]); ap[5]=fmaf(xc,wb1.y,ap[5]); ap[6]=fmaf(xc,wb1.z,ap[6]); ap[7]=fmaf(xc,wb1.w,ap[7]);
  }
  float* qpp = q  + (size_t)row*64 + (o0-cb);
  float* bpp = bs + (size_t)row*64 + (o0-cb);
  *(float4*)qpp     = make_float4(aq[0],aq[1],aq[2],aq[3]);
  *(float4*)(qpp+4) = make_float4(aq[4],aq[5],aq[6],aq[7]);
  *(float4*)bpp     = make_float4(ap[0]-aq[0],ap[1]-aq[1],ap[2]-aq[2],ap[3]-aq[3]);
  *(float4*)(bpp+4) = make_float4(ap[4]-aq[4],ap[5]-aq[5],ap[6]-aq[6],ap[7]-aq[7]);
}

template<int CFULL>
__launch_bounds__(256) __global__ void gather_chunk_k(const float* q, const float* bs, const int* idx,
    const float* g, const float* bb, int cb, float* out){
  const int t  = blockIdx.x*256 + threadIdx.x;
  const int o  = t & 63;
  const int bn = t >> 6;
  const int b  = bn >> 11;
  const int* id = idx + (size_t)bn*KK;
  float base = bs[t];
  float mx = -INFINITY, mn = INFINITY;
  #pragma unroll
  for(int k=0;k<KK;k++){
    int ik = id[k];
    float v = q[((size_t)((b<<11) + ik))*64 + o];
    mx = fmaxf(mx, v); mn = fminf(mn, v);
  }
  float a  = g[cb+o] * RSQ;
  float bo = bb[cb+o];
  out[(size_t)bn*CFULL + cb + o] = lrelu((a >= 0.f ? a*(mx+base) : a*(mn+base)) + bo);
}

// ---------------- head (fallback): fp32 GEMM-tiled cat x W5T with fused max/min ----------------
__launch_bounds__(256) __global__ void w5gemm_k(const float* __restrict__ x1, const float* __restrict__ x2,
    const float* __restrict__ x3, const float* __restrict__ x4,
    const float* __restrict__ W5T, unsigned* mxe, unsigned* mne){
  constexpr int ASTA = 92;
  constexpr int ASTB = 188;
  __shared__ __align__(16) float a_sh[16*ASTA];
  __shared__ __align__(16) float b_sh[16*ASTB];
  const int tid = threadIdx.x;
  const int otile = blockIdx.x*128;
  const int rtile = blockIdx.y*64;
  const int b     = blockIdx.z;
  const int tn = tid & 15, tm = tid >> 4;
  const int aoff = 4*tn + 4*(tn>>1);
  const size_t row0 = (size_t)b*NN + rtile;
  float acc[4][8];
  #pragma unroll
  for(int i=0;i<4;i++){
    #pragma unroll
    for(int j=0;j<8;j++) acc[i][j]=0.f;
  }
  for(int cc=0; cc<512; cc+=16){
    const float* src; int stride, coff;
    if(cc<64)      { src=x1; stride=64;  coff=cc; }
    else if(cc<128){ src=x2; stride=64;  coff=cc-64; }
    else if(cc<256){ src=x3; stride=128; coff=cc-128; }
    else           { src=x4; stride=256; coff=cc-256; }
    __syncthreads();
    { int r = tid>>2, q = tid&3;
      int pr = r + 4*(r>>3);
      float4 va = *(const float4*)&src[(row0 + r)*stride + coff + 4*q];
      a_sh[(4*q+0)*ASTA + pr]=va.x; a_sh[(4*q+1)*ASTA + pr]=va.y;
      a_sh[(4*q+2)*ASTA + pr]=va.z; a_sh[(4*q+3)*ASTA + pr]=va.w; }
    #pragma unroll
    for(int s=0;s<2;s++){
      int ii = tid + 256*s;
      int cl = ii>>5, o4 = ii&31;
      float4 vb = *(const float4*)&W5T[(size_t)(cc+cl)*512 + otile + 4*o4];
      *(float4*)&b_sh[cl*ASTB + 4*o4 + 4*(o4>>1)] = vb;
    }
    __syncthreads();
    #pragma unroll
    for(int c=0;c<16;c++){
      float4 A0 = *(const float4*)&a_sh[c*ASTA + aoff];
      float4 B0 = *(const float4*)&b_sh[c*ASTB + 12*tm];
      float4 B1 = *(const float4*)&b_sh[c*ASTB + 12*tm + 4];
      float b0v=B0.x,b1v=B0.y,b2v=B0.z,b3v=B0.w,b4v=B1.x,b5v=B1.y,b6v=B1.z,b7v=B1.w;
      float a;
      a=A0.x; FMA_ROW(0)
      a=A0.y; FMA_ROW(1)
      a=A0.z; FMA_ROW(2)
      a=A0.w; FMA_ROW(3)
    }
  }
  #pragma unroll
  for(int j=0;j<8;j++){
    float M=-INFINITY, m=INFINITY;
    #pragma unroll
    for(int i=0;i<4;i++){ M=fmaxf(M,acc[i][j]); m=fminf(m,acc[i][j]); }
    #pragma unroll
    for(int d=1; d<16; d<<=1){
      M = fmaxf(M, __shfl_xor(M, d));
      m = fminf(m, __shfl_xor(m, d));
    }
    if(tn == 0){
      int o = otile + tm*8 + j;
      atomicMax(&mxe[b*512+o], encf(M));
      atomicMin(&mne[b*512+o], encf(m));
    }
  }
}

// ---------------- head (big): split-bf16 MFMA ----------------
// xcat 3-split into fragment-major tiled layout (KT=16, row space = BN).
__launch_bounds__(256) __global__ void cvt_k(const float* __restrict__ x1, const float* __restrict__ x2,
    const float* __restrict__ x3, const float* __restrict__ x4,
    u16* __restrict__ xh, u16* __restrict__ xm, u16* __restrict__ xl){
  const size_t t = (size_t)blockIdx.x*256 + threadIdx.x;   // BN*512/8 chunks
  const int l = (int)(t & 63);
  const size_t tile = t >> 6;           // rgG*16 + kt
  const int kt = (int)(tile & 15);
  const size_t rgG = tile >> 4;
  const size_t row = rgG*16 + (l & 15);
  const int col = kt*32 + ((l>>4)<<3);
  const float* src; int stride, coff;
  if(col<64)      { src=x1; stride=64;  coff=col; }
  else if(col<128){ src=x2; stride=64;  coff=col-64; }
  else if(col<256){ src=x3; stride=128; coff=col-128; }
  else            { src=x4; stride=256; coff=col-256; }
  const float* p = src + row*stride + coff;
  float4 v0 = *(const float4*)p;
  float4 v1 = *(const float4*)(p+4);
  float vs[8] = {v0.x,v0.y,v0.z,v0.w,v1.x,v1.y,v1.z,v1.w};
  ushort8 H, M, L;
  #pragma unroll
  for(int j=0;j<8;j++){ u16 h,m,lo; bf16split3(vs[j],h,m,lo); H[j]=h; M[j]=m; L[j]=lo; }
  *(ushort8*)(xh + t*8) = H;
  *(ushort8*)(xm + t*8) = M;
  *(ushort8*)(xl + t*8) = L;
}

// C[16384x512] = xcat * W5^T via 6 bf16 MFMA products, LDS-staged fragments, fused max/min.
// Block 128r x 64c, 4 waves (2x2), wave 64r x 32c; grid (128 rowblk, 8 colblk) row-major-x.
__launch_bounds__(256) __global__ void w5mfma_k(const u16* __restrict__ xh, const u16* __restrict__ xm,
    const u16* __restrict__ xl,
    const u16* __restrict__ wh, const u16* __restrict__ wm, const u16* __restrict__ wl,
    unsigned* mxe, unsigned* mne){
  __shared__ u16 lds[36*512];
  const int tid = threadIdx.x;
  const int l  = tid & 63, wv = tid >> 6;
  const int lg = l >> 4, lr = l & 15;
  const int col0 = blockIdx.y*64 + (wv&1)*32;     // N base of this wave
  const int b = blockIdx.x >> 4;                  // 16 M-blocks per batch
  const size_t rgA = (size_t)blockIdx.x*8;        // block A rowgroup base (8 groups)
  const size_t cgB = (size_t)blockIdx.y*4;        // block B colgroup base (4 groups)
  f32x4 acc[4][2];
  #pragma unroll
  for(int m=0;m<4;m++){
    #pragma unroll
    for(int n=0;n<2;n++) acc[m][n] = (f32x4){0.f,0.f,0.f,0.f};
  }
  for(int kt=0; kt<16; kt++){
    __syncthreads();
    #pragma unroll
    for(int p=0;p<9;p++){
      int c  = p*4 + (tid>>6);
      int ln = tid & 63;
      const u16* src; size_t off;
      if(c < 24){ int s = c>>3, rg = c&7;
        src = (s==0) ? xh : (s==1) ? xm : xl;
        off = ((rgA + rg)*16 + kt)*512 + (size_t)ln*8;
      } else { int cc = c-24; int s = cc>>2, cg = cc&3;
        src = (s==0) ? wh : (s==1) ? wm : wl;
        off = ((cgB + cg)*16 + kt)*512 + (size_t)ln*8;
      }
      *(ushort8*)&lds[c*512 + ln*8] = *(const ushort8*)(src + off);
    }
    __syncthreads();
    short8 Bh[2], Bm[2], Bl[2];
    #pragma unroll
    for(int n=0;n<2;n++){ int cg = (wv&1)*2 + n;
      Bh[n] = *(const short8*)&lds[(24+cg)*512 + l*8];
      Bm[n] = *(const short8*)&lds[(28+cg)*512 + l*8];
      Bl[n] = *(const short8*)&lds[(32+cg)*512 + l*8];
    }
    #pragma unroll
    for(int m=0;m<4;m++){ int rg = (wv>>1)*4 + m;
      short8 Ah_ = *(const short8*)&lds[(   rg)*512 + l*8];
      short8 Am_ = *(const short8*)&lds[( 8+rg)*512 + l*8];
      short8 Al_ = *(const short8*)&lds[(16+rg)*512 + l*8];
      #pragma unroll
      for(int n=0;n<2;n++){
        MFMA6(acc[m][n], Ah_, Am_, Al_, Bh[n], Bm[n], Bl[n])
      }
    }
  }
  #pragma unroll
  for(int n=0;n<2;n++){
    float M = -INFINITY, mnv = INFINITY;
    #pragma unroll
    for(int m=0;m<4;m++){
      #pragma unroll
      for(int r=0;r<4;r++){ float v = acc[m][n][r]; M = fmaxf(M, v); mnv = fminf(mnv, v); }
    }
    M   = fmaxf(M,   __shfl_xor(M, 16));   M   = fmaxf(M,   __shfl_xor(M, 32));
    mnv = fminf(mnv, __shfl_xor(mnv, 16)); mnv = fminf(mnv, __shfl_xor(mnv, 32));
    if(lg == 0){
      int o = col0 + n*16 + lr;
      atomicMax(&mxe[b*512+o], encf(M));
      atomicMin(&mne[b*512+o], encf(mnv));
    }
  }
}

__launch_bounds__(256) __global__ void final_k(const unsigned* mxe, const unsigned* mne,
    const float* g5, const float* b5, const float* Wemb, float* out){
  const int b = blockIdx.x, t = threadIdx.x;
  __shared__ float h[512];
  for(int o=t; o<512; o+=256){
    float mx = decf(mxe[b*512+o]);
    float mn = decf(mne[b*512+o]);
    float a  = g5[o] * RSQ;
    float bo = b5[o];
    float hv = lrelu((a >= 0.f ? a*mx : a*mn) + bo);
    h[o] = hv;
    out[b*512+o] = hv;
  }
  __syncthreads();
  const float* wr = Wemb + (size_t)t*512;
  float s = 0.f;
  for(int o=0;o<512;o+=4){
    float4 w4 = *(const float4*)(wr+o);
    s = fmaf(h[o],w4.x, fmaf(h[o+1],w4.y, fmaf(h[o+2],w4.z, fmaf(h[o+3],w4.w, s))));
  }
  out[4096 + b*256 + t] = s;
}

// ---------------- launch ----------------
extern "C" void kernel_launch(void* const* d_in, const int* in_sizes, int n_in,
                              void* d_out, int out_size, void* d_ws, size_t ws_size,
                              hipStream_t stream) {
  if (ws_size < WS_END * sizeof(float)) return;
  const bool big = ws_size >= WS_BIG_END * sizeof(float);   // deterministic per call

  const float* x0   = (const float*)d_in[0];
  const float* W1   = (const float*)d_in[1];
  const float* g1   = (const float*)d_in[2];
  const float* b1   = (const float*)d_in[3];
  const float* W2   = (const float*)d_in[4];
  const float* g2   = (const float*)d_in[5];
  const float* b2   = (const float*)d_in[6];
  const float* W3   = (const float*)d_in[7];
  const float* g3   = (const float*)d_in[8];
  const float* b3   = (const float*)d_in[9];
  const float* W4   = (const float*)d_in[10];
  const float* g4   = (const float*)d_in[11];
  const float* b4   = (const float*)d_in[12];
  const float* W5   = (const float*)d_in[13];
  const float* g5   = (const float*)d_in[14];
  const float* b5   = (const float*)d_in[15];
  const float* Wemb = (const float*)d_in[16];

  float* ws = (float*)d_ws;
  float* xx = ws + OFF_XX;
  float* x1 = ws + OFF_X1;  float* x2 = ws + OFF_X2;
  float* x3 = ws + OFF_X3;  float* x4 = ws + OFF_X4;
  float* qpS = ws + OFF_SC;               // L1 qp (width 128) + fallback chunked q/bs
  float* bsS = ws + OFF_SC + (size_t)BN*64;
  int*   id = (int*)(ws + OFF_ID);
  float* W5Tf = ws + OFF_W5T;
  unsigned* mxe = (unsigned*)(ws + OFF_MX);
  unsigned* mne = (unsigned*)(ws + OFF_MN);
  float* WT2 = ws + OFF_WT2;
  float* WT3 = ws + OFF_WT3;
  float* WT4 = ws + OFF_WT4;
  float* distD = ws + OFF_X3;   // fallback dual-batch
  float* distS = ws + OFF_X4;   // fallback single-batch
  float* distB = ws + OFF_BIG;  // big: 4-batch dist chunk, then reused as qp buffer / bf16 xcat
  u16* w5h = (u16*)(ws + OFF_SC + (size_t)BN*128);   // SC tail (free in both paths): 3x256KB
  u16* w5m = w5h + 512*512;
  u16* w5l = w5m + 512*512;
  u16* wts = (u16*)W5Tf;         // big path: tiled WT splits live in the (unused) W5T region
  float* out = (float*)d_out;

  prep_k<<<1024,256,0,stream>>>(W5, W2, W3, W4, W5Tf, WT2, WT3, WT4,
                                w5h, w5m, w5l, wts, mxe, mne, big ? 1 : 0);

  // layer 1 (3 -> 64)
  sel3_k<<<BN*64/256,256,0,stream>>>(x0, id);
  qp3_k<<<BN*8/256,256,0,stream>>>(x0, W1, qpS);
  gather_qp_k<64><<<BN*64/256,256,0,stream>>>(qpS, id, g1, b1, x1);

  if(big){
    float* qpB = distB;                      // reuse dist region post-sel
    // split scratch lives in x4 region (dead until layer-4 gather)
    u16* sh = (u16*)x4;
    // layer 2 (CIN=64 -> COUT=64, qp width 128)
    { u16* sm = sh + (size_t)BN*64; u16* sl = sm + (size_t)BN*64;
      sqnorm_k<64><<<BN/256,256,0,stream>>>(x1, xx);
      split_k<64><<<BN*64/8/256,256,0,stream>>>(x1, sh, sm, sl);
      for(int c0=0;c0<BB;c0+=4){
        mfma_dist_k<64><<<dim3(32,16,4),256,0,stream>>>(sh, sm, sl, xx, distB, c0);
        sel_k<<<(4*NN)/4,256,0,stream>>>(distB, id, c0, 4*NN);
      }
      qp_mfma_k<2,128><<<dim3(BN/128,2),256,0,stream>>>(sh, sm, sl,
          wts+WTS_2H, wts+WTS_2M, wts+WTS_2L, qpB);
      gather_qp_k<64><<<BN*64/256,256,0,stream>>>(qpB, id, g2, b2, x2); }
    // layer 3 (64 -> 128, qp width 256)
    { u16* sm = sh + (size_t)BN*64; u16* sl = sm + (size_t)BN*64;
      sqnorm_k<64><<<BN/256,256,0,stream>>>(x2, xx);
      split_k<64><<<BN*64/8/256,256,0,stream>>>(x2, sh, sm, sl);
      for(int c0=0;c0<BB;c0+=4){
        mfma_dist_k<64><<<dim3(32,16,4),256,0,stream>>>(sh, sm, sl, xx, distB, c0);
        sel_k<<<(4*NN)/4,256,0,stream>>>(distB, id, c0, 4*NN);
      }
      qp_mfma_k<2,256><<<dim3(BN/128,4),256,0,stream>>>(sh, sm, sl,
          wts+WTS_3H, wts+WTS_3M, wts+WTS_3L, qpB);
      gather_qp_k<128><<<BN*128/256,256,0,stream>>>(qpB, id, g3, b3, x3); }
    // layer 4 (128 -> 256, qp width 512)
    { u16* sm = sh + (size_t)BN*128; u16* sl = sm + (size_t)BN*128;
      sqnorm_k<128><<<BN/256,256,0,stream>>>(x3, xx);
      split_k<128><<<BN*128/8/256,256,0,stream>>>(x3, sh, sm, sl);
      for(int c0=0;c0<BB;c0+=4){
        mfma_dist_k<128><<<dim3(32,16,4),256,0,stream>>>(sh, sm, sl, xx, distB, c0);
        sel_k<<<(4*NN)/4,256,0,stream>>>(distB, id, c0, 4*NN);
      }
      qp_mfma_k<4,512><<<dim3(BN/128,8),256,0,stream>>>(sh, sm, sl,
          wts+WTS_4H, wts+WTS_4M, wts+WTS_4L, qpB);
      gather_qp_k<256><<<BN*256/256,256,0,stream>>>(qpB, id, g4, b4, x4); }
    // head: bf16 3-split (tiled) + 6-product MFMA with LDS staging
    u16* xh = (u16*)(ws + OFF_XCAT);
    u16* xm = xh + (size_t)BN*512;
    u16* xl = xm + (size_t)BN*512;
    cvt_k<<<BN*512/8/256,256,0,stream>>>(x1, x2, x3, x4, xh, xm, xl);
    w5mfma_k<<<dim3(128,8),256,0,stream>>>(xh, xm, xl, w5h, w5m, w5l, mxe, mne);
  } else {
    // fallback: chunked (R12 structure, cat weight layout)
    sqnorm_k<64><<<BN/256,256,0,stream>>>(x1, xx);
    for(int r=0;r<4;r++){
      gemm_dist_k<64><<<dim3(16,16,2),256,0,stream>>>(x1, xx, distD, 2*r);
      sel_k<<<(2*NN)/4,256,0,stream>>>(distD, id, 2*r, 2*NN);
    }
    qp64T_k<64,64><<<BN*8/256,256,0,stream>>>(x1, WT2, 0, qpS, bsS);
    gather_chunk_k<64><<<BN*64/256,256,0,stream>>>(qpS, bsS, id, g2, b2, 0, x2);

    sqnorm_k<64><<<BN/256,256,0,stream>>>(x2, xx);
    for(int r=0;r<4;r++){
      gemm_dist_k<64><<<dim3(16,16,2),256,0,stream>>>(x2, xx, distD, 2*r);
      sel_k<<<(2*NN)/4,256,0,stream>>>(distD, id, 2*r, 2*NN);
    }
    for(int cb=0; cb<128; cb+=64){
      qp64T_k<64,128><<<BN*8/256,256,0,stream>>>(x2, WT3, cb, qpS, bsS);
      gather_chunk_k<128><<<BN*64/256,256,0,stream>>>(qpS, bsS, id, g3, b3, cb, x3);
    }

    sqnorm_k<128><<<BN/256,256,0,stream>>>(x3, xx);
    for(int r=0;r<8;r++){
      gemm_dist_k<128><<<dim3(16,16,1),256,0,stream>>>(x3, xx, distS, r);
      sel_k<<<NN/4,256,0,stream>>>(distS, id, r, NN);
    }
    for(int cb=0; cb<256; cb+=64){
      qp64T_k<128,256><<<BN*8/256,256,0,stream>>>(x3, WT4, cb, qpS, bsS);
      gather_chunk_k<256><<<BN*64/256,256,0,stream>>>(qpS, bsS, id, g4, b4, cb, x4);
    }
    w5gemm_k<<<dim3(4,32,8),256,0,stream>>>(x1, x2, x3, x4, W5Tf, mxe, mne);
  }

  final_k<<<BB,256,0,stream>>>(mxe, mne, g5, b5, Wemb, out);
}

// Round 14
// 604.532 us; speedup vs baseline: 1.0490x; 1.0490x over previous
//
#include <hip/hip_runtime.h>
#include <hip/hip_bf16.h>

#define BB 8
#define NN 2048
#define KK 20
#define BN (BB*NN)
#define RSQ 0.99999500003749969f   // 1/sqrt(1+1e-5)

// ---------------- workspace layout (float-slot units) ----------------
constexpr size_t OFF_XX  = 0;                          // BN
constexpr size_t OFF_X1  = OFF_XX  + BN;               // BN*64
constexpr size_t OFF_X2  = OFF_X1  + (size_t)BN*64;    // BN*64
constexpr size_t OFF_X3  = OFF_X2  + (size_t)BN*64;    // BN*128
constexpr size_t OFF_X4  = OFF_X3  + (size_t)BN*128;   // BN*256 (split-scratch pre-gather)
constexpr size_t OFF_SC  = OFF_X4  + (size_t)BN*256;   // BN*160 (L1 qp + fallback chunked qp + W5 bf16 tail)
constexpr size_t OFF_ID  = OFF_SC  + (size_t)BN*160;   // int BN*20
constexpr size_t OFF_W5T = OFF_ID  + (size_t)BN*20;    // 512*512 (big path: tiled WT splits live here)
constexpr size_t OFF_MX  = OFF_W5T + 512*512;
constexpr size_t OFF_MN  = OFF_MX  + BB*512;
constexpr size_t OFF_WT2 = OFF_MN  + BB*512;           // cat [64][128]
constexpr size_t OFF_WT3 = OFF_WT2 + 8192;             // cat [64][256]
constexpr size_t OFF_WT4 = OFF_WT3 + 16384;            // cat [128][512]
constexpr size_t WS_END  = OFF_WT4 + 65536;            // 11,714,560 floats
// big region (probed at runtime): dist chunk (4 batches) + qp buffer + bf16 xcat post-sel
constexpr size_t OFF_BIG = WS_END;
constexpr size_t OFF_XCAT = OFF_BIG + (size_t)16*1024*1024;  // bf16 xcat h/m/l (dist region tail, post-KNN)
constexpr size_t WS_BIG_END = OFF_BIG + (size_t)BB*NN*NN;   // 172.7 MiB
static_assert(OFF_ID - OFF_X3 >= (size_t)4096*2048, "fallback dual dist fits");
static_assert(OFF_XCAT + (size_t)BN*768 <= WS_BIG_END, "xcat h/m/l fits in dist region");

typedef unsigned short u16;
typedef __attribute__((ext_vector_type(8))) short short8;
typedef __attribute__((ext_vector_type(8))) unsigned short ushort8;
typedef __attribute__((ext_vector_type(4))) float f32x4;

// tiled WT split offsets (u16 units) within the W5T region (big path only)
constexpr size_t WTS_2H = 0,      WTS_2M = 8192,   WTS_2L = 16384;
constexpr size_t WTS_3H = 24576,  WTS_3M = 40960,  WTS_3L = 57344;
constexpr size_t WTS_4H = 73728,  WTS_4M = 139264, WTS_4L = 204800;   // end 270336 u16 <= 524288

__device__ inline unsigned encf(float f){ unsigned u=__float_as_uint(f); return (u&0x80000000u)? ~u : (u|0x80000000u); }
__device__ inline float decf(unsigned e){ unsigned u=(e&0x80000000u)? (e&0x7fffffffu) : ~e; return __uint_as_float(u); }
__device__ inline float lrelu(float h){ return h>=0.f ? h : 0.2f*h; }
__device__ inline u16 bf16rne(float x){
  unsigned u = __float_as_uint(x);
  return (u16)((u + 0x7FFFu + ((u>>16)&1u)) >> 16);
}
__device__ inline float bf16f(u16 h){ return __uint_as_float((unsigned)h<<16); }
// exact 3-way split: x == h + m + l for normal fp32 (24 mantissa bits covered)
__device__ inline void bf16split3(float v, u16& h, u16& m, u16& l){
  h = bf16rne(v);  float r1 = v  - bf16f(h);
  m = bf16rne(r1); float r2 = r1 - bf16f(m);
  l = bf16rne(r2);
}

__device__ inline float readlane_f(float v, int sl){
  return __int_as_float(__builtin_amdgcn_readlane(__float_as_int(v), sl));
}

// Wave-cooperative sorted-top-20 insertion (cv known > theta on call).
#define INSERT_CAND(cv, ci) { \
  unsigned long long mge = __ballot((lv > cv) || (lv == cv && li < ci)); \
  int pos = __popcll(mge); \
  float upv = __shfl_up(lv, 1); \
  int   upi = __shfl_up(li, 1); \
  bool shift = (lane > pos) && (lane < KK); \
  lv = (lane == pos) ? cv : (shift ? upv : lv); \
  li = (lane == pos) ? ci : (shift ? upi : li); \
  theta = readlane_f(lv, KK-1); }

// Bitonic full sort of 64 (value desc, index asc on ties) across lanes; (v,vi) in registers.
#define BITONIC64_DESC(v, vi) { \
  _Pragma("unroll") \
  for(int k=2; k<=64; k<<=1){ \
    _Pragma("unroll") \
    for(int j=k>>1; j>=1; j>>=1){ \
      float ov = __shfl_xor(v, j); \
      int   oi = __shfl_xor(vi, j); \
      int partner = lane ^ j; \
      bool keepFirst = (((lane & k) == 0)) == (lane < partner); \
      bool before = (v > ov) || (v == ov && vi < oi); \
      if(keepFirst != before){ v = ov; vi = oi; } \
    } \
  } }

// 6-product split-bf16 MFMA macro: acc over Ah/Am/Al x Bh/Bm/Bl
#define MFMA6(ACC, AH, AM, AL, BH, BM, BL) { \
  ACC = __builtin_amdgcn_mfma_f32_16x16x32_bf16(AH, BH, ACC, 0, 0, 0); \
  ACC = __builtin_amdgcn_mfma_f32_16x16x32_bf16(AH, BM, ACC, 0, 0, 0); \
  ACC = __builtin_amdgcn_mfma_f32_16x16x32_bf16(AM, BH, ACC, 0, 0, 0); \
  ACC = __builtin_amdgcn_mfma_f32_16x16x32_bf16(AH, BL, ACC, 0, 0, 0); \
  ACC = __builtin_amdgcn_mfma_f32_16x16x32_bf16(AL, BH, ACC, 0, 0, 0); \
  ACC = __builtin_amdgcn_mfma_f32_16x16x32_bf16(AM, BM, ACC, 0, 0, 0); }

// ======== fragment-major tiled split layout ========
// split[rowGroup][kTile][lane=64][8]  (u16). lane l -> row = rg*16 + (l&15), k = kt*32 + (l>>4)*8.

// ---------------- prep: weights transposes + splits + enc ----------------
__global__ void prep_k(const float* W5, const float* W2, const float* W3, const float* W4,
                       float* W5T, float* WT2, float* WT3, float* WT4,
                       u16* w5h, u16* w5m, u16* w5l, u16* wts,
                       unsigned* mx, unsigned* mn, int big){
  int i = blockIdx.x*256 + threadIdx.x;     // 262144
  if(!big){ int o = i>>9, c = i&511; W5T[c*512+o] = W5[i]; }   // fp32 W5T only for fallback
  { // tiled split of W5 (B-side rows = output cols o, k = input c). KT=16.
    int rg = i>>13, kt = (i>>9)&15, l = (i>>3)&63, j = i&7;
    int o = rg*16 + (l&15);
    int c = kt*32 + ((l>>4)<<3) + j;
    u16 h,m,lo; bf16split3(W5[(size_t)o*512 + c], h, m, lo);
    w5h[i]=h; w5m[i]=m; w5l[i]=lo; }
  if(i < 65536){ int c = i>>9, o = i&511;   // W4: [256][256] -> cat [128][512]
    WT4[i] = (o<256) ? W4[(size_t)o*256 + c] : W4[(size_t)(o-256)*256 + 128 + c]; }
  if(i < 16384){ int c = i>>8, o = i&255;   // W3: [128][128] -> cat [64][256]
    WT3[i] = (o<128) ? W3[(size_t)o*128 + c] : W3[(size_t)(o-128)*128 + 64 + c]; }
  if(i <  8192){ int c = i>>7, o = i&127;   // W2: [64][128] -> cat [64][128]
    WT2[i] = (o<64) ? W2[(size_t)o*128 + c] : W2[(size_t)(o-64)*128 + 64 + c]; }
  if(big){
    if(i < 65536){ // WT4 tiled split: rg over o (32), kt over c (4)
      int rg=i>>11, kt=(i>>9)&3, l=(i>>3)&63, j=i&7;
      int o = rg*16 + (l&15);
      int c = kt*32 + ((l>>4)<<3) + j;
      float v = (o<256) ? W4[(size_t)o*256 + c] : W4[(size_t)(o-256)*256 + 128 + c];
      u16 h,m,lo; bf16split3(v,h,m,lo);
      wts[WTS_4H+i]=h; wts[WTS_4M+i]=m; wts[WTS_4L+i]=lo; }
    if(i < 16384){ // WT3 tiled split: rg over o (16), kt over c (2)
      int rg=i>>10, kt=(i>>9)&1, l=(i>>3)&63, j=i&7;
      int o = rg*16 + (l&15);
      int c = kt*32 + ((l>>4)<<3) + j;
      float v = (o<128) ? W3[(size_t)o*128 + c] : W3[(size_t)(o-128)*128 + 64 + c];
      u16 h,m,lo; bf16split3(v,h,m,lo);
      wts[WTS_3H+i]=h; wts[WTS_3M+i]=m; wts[WTS_3L+i]=lo; }
    if(i < 8192){  // WT2 tiled split: rg over o (8), kt over c (2)
      int rg=i>>10, kt=(i>>9)&1, l=(i>>3)&63, j=i&7;
      int o = rg*16 + (l&15);
      int c = kt*32 + ((l>>4)<<3) + j;
      float v = (o<64) ? W2[(size_t)o*128 + c] : W2[(size_t)(o-64)*128 + 64 + c];
      u16 h,m,lo; bf16split3(v,h,m,lo);
      wts[WTS_2H+i]=h; wts[WTS_2M+i]=m; wts[WTS_2L+i]=lo; }
  }
  if(i <  4096){ mx[i] = 0x007FFFFFu; mn[i] = 0xFF800000u; }
}

// ---------------- KNN ----------------
template<int C>
__launch_bounds__(256) __global__ void sqnorm_k(const float* X, float* xx){
  int i = blockIdx.x*256 + threadIdx.x;   // BN
  const float* r = X + (size_t)i*C;
  float s = 0.f;
  #pragma unroll
  for(int c=0;c<C;c++) s = fmaf(r[c], r[c], s);
  xx[i] = s;
}

// 3-way bf16 split of X [BN][C] into fragment-major tiled layout.
template<int C>
__launch_bounds__(256) __global__ void split_k(const float* __restrict__ X,
    u16* __restrict__ xh, u16* __restrict__ xm, u16* __restrict__ xl){
  constexpr int KT = C/32;
  const size_t t = (size_t)blockIdx.x*256 + threadIdx.x;   // BN*C/8 chunks
  const int l = (int)(t & 63);
  const size_t tile = t >> 6;               // rgG*KT + kt
  const int kt = (int)(tile & (KT-1));
  const size_t rgG = tile / KT;             // global row group (BN/16 total)
  const size_t row = rgG*16 + (l & 15);
  const int k = kt*32 + ((l>>4)<<3);
  const float* p = X + row*C + k;
  float4 v0 = *(const float4*)p;
  float4 v1 = *(const float4*)(p+4);
  float vs[8] = {v0.x,v0.y,v0.z,v0.w,v1.x,v1.y,v1.z,v1.w};
  ushort8 H,M,L;
  #pragma unroll
  for(int j=0;j<8;j++){ u16 h,m,lo; bf16split3(vs[j],h,m,lo); H[j]=h; M[j]=m; L[j]=lo; }
  *(ushort8*)(xh + t*8) = H;
  *(ushort8*)(xm + t*8) = M;
  *(ushort8*)(xl + t*8) = L;
}

#define FMA_ROW(I) \
  acc[I][0]=fmaf(a,b0v,acc[I][0]); acc[I][1]=fmaf(a,b1v,acc[I][1]); \
  acc[I][2]=fmaf(a,b2v,acc[I][2]); acc[I][3]=fmaf(a,b3v,acc[I][3]); \
  acc[I][4]=fmaf(a,b4v,acc[I][4]); acc[I][5]=fmaf(a,b5v,acc[I][5]); \
  acc[I][6]=fmaf(a,b6v,acc[I][6]); acc[I][7]=fmaf(a,b7v,acc[I][7]);

// fallback fp32 dist GEMM
template<int C>
__launch_bounds__(256) __global__ void gemm_dist_k(const float* __restrict__ X, const float* __restrict__ xx,
                                                   float* __restrict__ dist, int b0){
  constexpr int AST = 188;
  __shared__ __align__(16) float a_sh[16*AST];
  __shared__ __align__(16) float b_sh[16*AST];
  __shared__ float sxn[128], sxm[128];
  const int tid = threadIdx.x;
  const int b   = b0 + blockIdx.z;
  const int mtile = blockIdx.x*128;
  const int ntile = blockIdx.y*128;
  const int tn = tid & 15, tm = tid >> 4;
  const float* Xb  = X  + (size_t)b*NN*C;
  const float* xxb = xx + (size_t)b*NN;
  if(tid < 128) sxn[tid] = xxb[ntile + tid];
  else          sxm[tid-128] = xxb[mtile + tid-128];
  float acc[8][8];
  #pragma unroll
  for(int i=0;i<8;i++){
    #pragma unroll
    for(int j=0;j<8;j++) acc[i][j]=0.f;
  }
  for(int cc=0; cc<C; cc+=16){
    __syncthreads();
    #pragma unroll
    for(int s=0;s<2;s++){
      int ii = tid + 256*s; int r = ii>>2, q = ii&3;
      int pr = r + 4*(r>>3);
      float4 va = *(const float4*)&Xb[(size_t)(ntile + r)*C + cc + 4*q];
      a_sh[(4*q+0)*AST + pr]=va.x; a_sh[(4*q+1)*AST + pr]=va.y;
      a_sh[(4*q+2)*AST + pr]=va.z; a_sh[(4*q+3)*AST + pr]=va.w;
      float4 vb = *(const float4*)&Xb[(size_t)(mtile + r)*C + cc + 4*q];
      b_sh[(4*q+0)*AST + pr]=vb.x; b_sh[(4*q+1)*AST + pr]=vb.y;
      b_sh[(4*q+2)*AST + pr]=vb.z; b_sh[(4*q+3)*AST + pr]=vb.w;
    }
    __syncthreads();
    #pragma unroll
    for(int c=0;c<16;c++){
      float4 A0 = *(const float4*)&a_sh[c*AST + 12*tn];
      float4 A1 = *(const float4*)&a_sh[c*AST + 12*tn + 4];
      float4 B0 = *(const float4*)&b_sh[c*AST + 12*tm];
      float4 B1 = *(const float4*)&b_sh[c*AST + 12*tm + 4];
      float b0v=B0.x,b1v=B0.y,b2v=B0.z,b3v=B0.w,b4v=B1.x,b5v=B1.y,b6v=B1.z,b7v=B1.w;
      float a;
      a=A0.x; FMA_ROW(0)
      a=A0.y; FMA_ROW(1)
      a=A0.z; FMA_ROW(2)
      a=A0.w; FMA_ROW(3)
      a=A1.x; FMA_ROW(4)
      a=A1.y; FMA_ROW(5)
      a=A1.z; FMA_ROW(6)
      a=A1.w; FMA_ROW(7)
    }
  }
  float xnr[8], xmr[8];
  #pragma unroll
  for(int i=0;i<8;i++){ xnr[i]=sxn[tn*8+i]; xmr[i]=sxm[tm*8+i]; }
  const size_t rowb = (size_t)blockIdx.z*NN + ntile + tn*8;
  #pragma unroll
  for(int i=0;i<8;i++){
    float4 w0, w1;
    w0.x=(2.f*acc[i][0]-xnr[i])-xmr[0]; w0.y=(2.f*acc[i][1]-xnr[i])-xmr[1];
    w0.z=(2.f*acc[i][2]-xnr[i])-xmr[2]; w0.w=(2.f*acc[i][3]-xnr[i])-xmr[3];
    w1.x=(2.f*acc[i][4]-xnr[i])-xmr[4]; w1.y=(2.f*acc[i][5]-xnr[i])-xmr[5];
    w1.z=(2.f*acc[i][6]-xnr[i])-xmr[6]; w1.w=(2.f*acc[i][7]-xnr[i])-xmr[7];
    float* dp = dist + (rowb + i)*NN + mtile + tm*8;
    *(float4*)dp = w0;
    *(float4*)(dp+4) = w1;
  }
}

// big path: exact-fp32-quality dist via split-bf16 MFMA (6 products of 3-way split).
// 64-col tiles for occupancy: grid (NN/64, 16, 4chunk); block 128q x 64c; wave 64q x 32c.
template<int C>
__launch_bounds__(256) __global__ void mfma_dist_k(const u16* __restrict__ xh, const u16* __restrict__ xm,
    const u16* __restrict__ xl, const float* __restrict__ xx, float* __restrict__ dist, int b0){
  constexpr int KT = C/32;
  const int tid = threadIdx.x;
  const int l  = tid & 63, wv = tid >> 6;
  const int lg = l >> 4, lr = l & 15;
  const int cz = blockIdx.z;
  const int b  = b0 + cz;
  const int qrow0 = blockIdx.y*128 + (wv>>1)*64;   // query rows (A side, dist row)
  const int crow0 = blockIdx.x*64 + (wv&1)*32;     // candidate rows (B side, dist col)
  const size_t brg = (size_t)b*(NN/16);
  f32x4 acc[4][2];
  #pragma unroll
  for(int m=0;m<4;m++){
    #pragma unroll
    for(int n=0;n<2;n++) acc[m][n] = (f32x4){0.f,0.f,0.f,0.f};
  }
  const size_t abase = (brg + (qrow0>>4))*KT*512 + (size_t)l*8;
  const size_t bbase = (brg + (crow0>>4))*KT*512 + (size_t)l*8;
  for(int kt=0; kt<KT; kt++){
    short8 Ah[4], Am[4], Al[4], Bh[2], Bm[2], Bl[2];
    #pragma unroll
    for(int m=0;m<4;m++){
      size_t o = abase + (size_t)(m*KT + kt)*512;
      Ah[m] = *(const short8*)(xh + o);
      Am[m] = *(const short8*)(xm + o);
      Al[m] = *(const short8*)(xl + o);
    }
    #pragma unroll
    for(int n=0;n<2;n++){
      size_t o = bbase + (size_t)(n*KT + kt)*512;
      Bh[n] = *(const short8*)(xh + o);
      Bm[n] = *(const short8*)(xm + o);
      Bl[n] = *(const short8*)(xl + o);
    }
    #pragma unroll
    for(int m=0;m<4;m++){
      #pragma unroll
      for(int n=0;n<2;n++){
        MFMA6(acc[m][n], Ah[m], Am[m], Al[m], Bh[n], Bm[n], Bl[n])
      }
    }
  }
  const float* xxb = xx + (size_t)b*NN;
  float xxc[2];
  #pragma unroll
  for(int n=0;n<2;n++) xxc[n] = xxb[crow0 + n*16 + lr];
  #pragma unroll
  for(int m=0;m<4;m++){
    #pragma unroll
    for(int r=0;r<4;r++){
      int qr = qrow0 + m*16 + 4*lg + r;
      float xq = xxb[qr];
      float* dp = dist + ((size_t)cz*NN + qr)*NN + crow0;
      #pragma unroll
      for(int n=0;n<2;n++) dp[n*16 + lr] = (2.f*acc[m][n][r] - xq) - xxc[n];
    }
  }
}

// Wave-cooperative top-20: max-of-4 bitonic warm start + slim insertions, float4 scan.
__launch_bounds__(256) __global__ void sel_k(const float* __restrict__ dist, int* __restrict__ id,
                                             int b0, int nrows){
  const int w = (blockIdx.x*256 + threadIdx.x) >> 6;
  const int lane = threadIdx.x & 63;
  if(w >= nrows) return;
  const float* dr = dist + (size_t)w*NN;
  float4 c0 = *(const float4*)&dr[4*lane];
  float cd0[4] = {c0.x, c0.y, c0.z, c0.w};
  int jbest = 0; float v = cd0[0];
  #pragma unroll
  for(int j=1;j<4;j++){ if(cd0[j] > v){ v = cd0[j]; jbest = j; } }
  int vi = 4*lane + jbest;
  BITONIC64_DESC(v, vi)
  float lv = (lane < KK) ? v : -INFINITY;
  int   li = (lane < KK) ? vi : 0;
  float theta = readlane_f(lv, KK-1);
  #pragma unroll
  for(int j=0;j<4;j++){
    float cand = (j == jbest) ? -INFINITY : cd0[j];
    unsigned long long bal = __ballot(cand > theta);
    while(bal){
      int bpos = __ffsll((unsigned long long)bal) - 1;
      bal &= bal - 1;
      float cv = readlane_f(cand, bpos);
      if(cv > theta){
        int ci = 4*bpos + j;
        INSERT_CAND(cv, ci)
      }
    }
  }
  for(int ms=256; ms<NN; ms+=256){
    float4 c4 = *(const float4*)&dr[ms + 4*lane];
    #pragma unroll
    for(int j=0;j<4;j++){
      float cand = (j==0)?c4.x:(j==1)?c4.y:(j==2)?c4.z:c4.w;
      unsigned long long bal = __ballot(cand > theta);
      while(bal){
        int bpos = __ffsll((unsigned long long)bal) - 1;
        bal &= bal - 1;
        float cv = readlane_f(cand, bpos);
        if(cv > theta){
          int ci = ms + 4*bpos + j;
          INSERT_CAND(cv, ci)
        }
      }
    }
  }
  if(lane < KK) id[((size_t)b0*NN + w)*KK + lane] = li;
}

// L1 fused: inline C=3 distances + inline sqnorm, max-of-4 bitonic warm start.
__launch_bounds__(256) __global__ void sel3_k(const float* __restrict__ X, int* __restrict__ id){
  const int gw = (blockIdx.x*256 + threadIdx.x) >> 6;
  const int lane = threadIdx.x & 63;
  const int b = gw >> 11, n = gw & 2047;
  const float* Xb  = X + (size_t)b*NN*3;
  const float x0v = Xb[n*3], x1v = Xb[n*3+1], x2v = Xb[n*3+2];
  float xxn = 0.f;
  xxn = fmaf(x0v, x0v, xxn); xxn = fmaf(x1v, x1v, xxn); xxn = fmaf(x2v, x2v, xxn);
  float lv, theta; int li;
  {
    const float* p = Xb + (size_t)(4*lane)*3;
    float4 va = *(const float4*)p;
    float4 vb = *(const float4*)(p+4);
    float4 vc = *(const float4*)(p+8);
    float cx[4] = {va.x, va.w, vb.z, vc.y};
    float cy[4] = {va.y, vb.x, vb.w, vc.z};
    float cz[4] = {va.z, vb.y, vc.x, vc.w};
    float cd[4];
    #pragma unroll
    for(int j=0;j<4;j++){
      float s = 0.f;
      s = fmaf(x0v, cx[j], s); s = fmaf(x1v, cy[j], s); s = fmaf(x2v, cz[j], s);
      float xxm = 0.f;
      xxm = fmaf(cx[j], cx[j], xxm); xxm = fmaf(cy[j], cy[j], xxm); xxm = fmaf(cz[j], cz[j], xxm);
      cd[j] = (2.f*s - xxn) - xxm;
    }
    int jbest = 0; float v = cd[0];
    #pragma unroll
    for(int j=1;j<4;j++){ if(cd[j] > v){ v = cd[j]; jbest = j; } }
    int vi = 4*lane + jbest;
    BITONIC64_DESC(v, vi)
    lv = (lane < KK) ? v : -INFINITY;
    li = (lane < KK) ? vi : 0;
    theta = readlane_f(lv, KK-1);
    #pragma unroll
    for(int j=0;j<4;j++){
      float cand = (j == jbest) ? -INFINITY : cd[j];
      unsigned long long bal = __ballot(cand > theta);
      while(bal){
        int bpos = __ffsll((unsigned long long)bal) - 1;
        bal &= bal - 1;
        float cv = readlane_f(cand, bpos);
        if(cv > theta){
          int ci = 4*bpos + j;
          INSERT_CAND(cv, ci)
        }
      }
    }
  }
  for(int ms=256; ms<NN; ms+=256){
    const float* p = Xb + (size_t)(ms + 4*lane)*3;
    float4 va = *(const float4*)p;
    float4 vb = *(const float4*)(p+4);
    float4 vc = *(const float4*)(p+8);
    float cx[4] = {va.x, va.w, vb.z, vc.y};
    float cy[4] = {va.y, vb.x, vb.w, vc.z};
    float cz[4] = {va.z, vb.y, vc.x, vc.w};
    float cd[4];
    #pragma unroll
    for(int j=0;j<4;j++){
      float s = 0.f;
      s = fmaf(x0v, cx[j], s); s = fmaf(x1v, cy[j], s); s = fmaf(x2v, cz[j], s);
      float xxm = 0.f;
      xxm = fmaf(cx[j], cx[j], xxm); xxm = fmaf(cy[j], cy[j], xxm); xxm = fmaf(cz[j], cz[j], xxm);
      cd[j] = (2.f*s - xxn) - xxm;
    }
    #pragma unroll
    for(int j=0;j<4;j++){
      float cand = cd[j];
      unsigned long long bal = __ballot(cand > theta);
      while(bal){
        int bpos = __ffsll((unsigned long long)bal) - 1;
        bal &= bal - 1;
        float cv = readlane_f(cand, bpos);
        if(cv > theta){
          int ci = ms + 4*bpos + j;
          INSERT_CAND(cv, ci)
        }
      }
    }
  }
  if(lane < KK) id[(size_t)gw*KK + lane] = li;
}

// ---------------- qp ----------------
// L1: writes interleaved qp[row][128]: q at 0..63, p at 64..127
__launch_bounds__(256) __global__ void qp3_k(const float* X, const float* W, float* qp){
  const int t   = blockIdx.x*256 + threadIdx.x;
  const int row = t >> 3;
  const int c0  = (t & 7) * 8;
  float xn[3];
  #pragma unroll
  for(int c=0;c<3;c++) xn[c] = X[(size_t)row*3 + c];
  for(int oi=c0; oi<c0+8; oi++){
    const float* w = W + (size_t)oi*6;
    float aq=0.f, ap=0.f;
    #pragma unroll
    for(int c=0;c<3;c++){ aq = fmaf(xn[c], w[c], aq); ap = fmaf(xn[c], w[3+c], ap); }
    qp[(size_t)row*128 + oi]      = aq;
    qp[(size_t)row*128 + 64 + oi] = ap;
  }
}

// qp via split-bf16 MFMA (layers 2/3/4): qp[BN][W2C] = Xsplit * WTsplit.
// Grid (BN/128, W2C/64); block 128r x 64c; wave 64r x 32c.
template<int KT, int W2C>
__launch_bounds__(256) __global__ void qp_mfma_k(const u16* __restrict__ xh, const u16* __restrict__ xm,
    const u16* __restrict__ xl,
    const u16* __restrict__ wh, const u16* __restrict__ wm, const u16* __restrict__ wl,
    float* __restrict__ qp){
  const int tid = threadIdx.x;
  const int l  = tid & 63, wv = tid >> 6;
  const int lg = l >> 4, lr = l & 15;
  const int row0 = blockIdx.x*128 + (wv>>1)*64;
  const int col0 = blockIdx.y*64 + (wv&1)*32;
  f32x4 acc[4][2];
  #pragma unroll
  for(int m=0;m<4;m++){
    #pragma unroll
    for(int n=0;n<2;n++) acc[m][n] = (f32x4){0.f,0.f,0.f,0.f};
  }
  const size_t abase = (size_t)(row0>>4)*KT*512 + (size_t)l*8;
  const size_t bbase = (size_t)(col0>>4)*KT*512 + (size_t)l*8;
  for(int kt=0; kt<KT; kt++){
    short8 Ah[4], Am[4], Al[4], Bh[2], Bm[2], Bl[2];
    #pragma unroll
    for(int m=0;m<4;m++){
      size_t o = abase + (size_t)(m*KT + kt)*512;
      Ah[m] = *(const short8*)(xh + o);
      Am[m] = *(const short8*)(xm + o);
      Al[m] = *(const short8*)(xl + o);
    }
    #pragma unroll
    for(int n=0;n<2;n++){
      size_t o = bbase + (size_t)(n*KT + kt)*512;
      Bh[n] = *(const short8*)(wh + o);
      Bm[n] = *(const short8*)(wm + o);
      Bl[n] = *(const short8*)(wl + o);
    }
    #pragma unroll
    for(int m=0;m<4;m++){
      #pragma unroll
      for(int n=0;n<2;n++){
        MFMA6(acc[m][n], Ah[m], Am[m], Al[m], Bh[n], Bm[n], Bl[n])
      }
    }
  }
  #pragma unroll
  for(int m=0;m<4;m++){
    #pragma unroll
    for(int r=0;r<4;r++){
      int row = row0 + m*16 + 4*lg + r;
      float* dp = qp + (size_t)row*W2C + col0;
      #pragma unroll
      for(int n=0;n<2;n++) dp[n*16 + lr] = acc[m][n][r];
    }
  }
}

// Gather from interleaved qp[row][2*COUT] (q | p); base = p - q computed here.
template<int COUT>
__launch_bounds__(256) __global__ void gather_qp_k(const float* __restrict__ qp, const int* __restrict__ idx,
    const float* g, const float* bb, float* out){
  const int t  = blockIdx.x*256 + threadIdx.x;   // BN*COUT
  const int o  = t % COUT;
  const int bn = t / COUT;
  const int b  = bn >> 11;
  const int* id = idx + (size_t)bn*KK;
  float qv = qp[(size_t)bn*(2*COUT) + o];
  float pv = qp[(size_t)bn*(2*COUT) + COUT + o];
  float base = pv - qv;
  float mx = -INFINITY, mn = INFINITY;
  #pragma unroll
  for(int k=0;k<KK;k++){
    int ik = id[k];
    float v = qp[((size_t)((b<<11) + ik))*(2*COUT) + o];
    mx = fmaxf(mx, v); mn = fminf(mn, v);
  }
  float a  = g[o] * RSQ;
  float bo = bb[o];
  out[(size_t)bn*COUT + o] = lrelu((a >= 0.f ? a*(mx+base) : a*(mn+base)) + bo);
}

// ---- fallback chunked qp (cat weight layout) + chunked gather ----
template<int CIN, int COUT>
__launch_bounds__(256) __global__ void qp64T_k(const float* __restrict__ X, const float* __restrict__ WT,
                                               int cb, float* __restrict__ q, float* __restrict__ bs){
  const int t   = blockIdx.x*256 + threadIdx.x;
  const int row = t >> 3;
  const int o0  = cb + (t & 7) * 8;
  float xn[CIN];
  #pragma unroll
  for(int c=0;c<CIN;c+=4){ float4 v = *(const float4*)(X + (size_t)row*CIN + c);
    xn[c]=v.x; xn[c+1]=v.y; xn[c+2]=v.z; xn[c+3]=v.w; }
  float aq[8], ap[8];
  #pragma unroll
  for(int j=0;j<8;j++){ aq[j]=0.f; ap[j]=0.f; }
  #pragma unroll 4
  for(int c=0;c<CIN;c++){
    float xc = xn[c];
    float4 wa0 = *(const float4*)&WT[(size_t)c*(2*COUT) + o0];
    float4 wa1 = *(const float4*)&WT[(size_t)c*(2*COUT) + o0 + 4];
    float4 wb0 = *(const float4*)&WT[(size_t)c*(2*COUT) + COUT + o0];
    float4 wb1 = *(const float4*)&WT[(size_t)c*(2*COUT) + COUT + o0 + 4];
    aq[0]=fmaf(xc,wa0.x,aq[0]); aq[1]=fmaf(xc,wa0.y,aq[1]); aq[2]=fmaf(xc,wa0.z,aq[2]); aq[3]=fmaf(xc,wa0.w,aq[3]);
    aq[4]=fmaf(xc,wa1.x,aq[4]); aq[5]=fmaf(xc,wa1.y,aq[5]); aq[6]=fmaf(xc,wa1.z,aq[6]); aq[7]=fmaf(xc,wa1.w,aq[7]);
    ap[0]=fmaf(xc,wb0.x,ap[0]); ap[1]=fmaf(xc,wb0.y,ap[1]); ap[2]=fmaf(xc,wb0.z,ap[2]); ap[3]=fmaf(xc,wb0.w,ap[3]);
    ap[4]=fmaf(xc,wb1.x,ap[4]); ap[5]=fmaf(xc,wb1.y,ap[5]); ap[6]=fmaf(xc,wb1.z,ap[6]); ap[7]=fmaf(xc,wb1.w,ap[7]);
  }
  float* qpp = q  + (size_t)row*64 + (o0-cb);
  float* bpp = bs + (size_t)row*64 + (o0-cb);
  *(float4*)qpp     = make_float4(aq[0],aq[1],aq[2],aq[3]);
  *(float4*)(qpp+4) = make_float4(aq[4],aq[5],aq[6],aq[7]);
  *(float4*)bpp     = make_float4(ap[0]-aq[0],ap[1]-aq[1],ap[2]-aq[2],ap[3]-aq[3]);
  *(float4*)(bpp+4) = make_float4(ap[4]-aq[4],ap[5]-aq[5],ap[6]-aq[6],ap[7]-aq[7]);
}

template<int CFULL>
__launch_bounds__(256) __global__ void gather_chunk_k(const float* q, const float* bs, const int* idx,
    const float* g, const float* bb, int cb, float* out){
  const int t  = blockIdx.x*256 + threadIdx.x;
  const int o  = t & 63;
  const int bn = t >> 6;
  const int b  = bn >> 11;
  const int* id = idx + (size_t)bn*KK;
  float base = bs[t];
  float mx = -INFINITY, mn = INFINITY;
  #pragma unroll
  for(int k=0;k<KK;k++){
    int ik = id[k];
    float v = q[((size_t)((b<<11) + ik))*64 + o];
    mx = fmaxf(mx, v); mn = fminf(mn, v);
  }
  float a  = g[cb+o] * RSQ;
  float bo = bb[cb+o];
  out[(size_t)bn*CFULL + cb + o] = lrelu((a >= 0.f ? a*(mx+base) : a*(mn+base)) + bo);
}

// ---------------- head (fallback): fp32 GEMM-tiled cat x W5T with fused max/min ----------------
__launch_bounds__(256) __global__ void w5gemm_k(const float* __restrict__ x1, const float* __restrict__ x2,
    const float* __restrict__ x3, const float* __restrict__ x4,
    const float* __restrict__ W5T, unsigned* mxe, unsigned* mne){
  constexpr int ASTA = 92;
  constexpr int ASTB = 188;
  __shared__ __align__(16) float a_sh[16*ASTA];
  __shared__ __align__(16) float b_sh[16*ASTB];
  const int tid = threadIdx.x;
  const int otile = blockIdx.x*128;
  const int rtile = blockIdx.y*64;
  const int b     = blockIdx.z;
  const int tn = tid & 15, tm = tid >> 4;
  const int aoff = 4*tn + 4*(tn>>1);
  const size_t row0 = (size_t)b*NN + rtile;
  float acc[4][8];
  #pragma unroll
  for(int i=0;i<4;i++){
    #pragma unroll
    for(int j=0;j<8;j++) acc[i][j]=0.f;
  }
  for(int cc=0; cc<512; cc+=16){
    const float* src; int stride, coff;
    if(cc<64)      { src=x1; stride=64;  coff=cc; }
    else if(cc<128){ src=x2; stride=64;  coff=cc-64; }
    else if(cc<256){ src=x3; stride=128; coff=cc-128; }
    else           { src=x4; stride=256; coff=cc-256; }
    __syncthreads();
    { int r = tid>>2, q = tid&3;
      int pr = r + 4*(r>>3);
      float4 va = *(const float4*)&src[(row0 + r)*stride + coff + 4*q];
      a_sh[(4*q+0)*ASTA + pr]=va.x; a_sh[(4*q+1)*ASTA + pr]=va.y;
      a_sh[(4*q+2)*ASTA + pr]=va.z; a_sh[(4*q+3)*ASTA + pr]=va.w; }
    #pragma unroll
    for(int s=0;s<2;s++){
      int ii = tid + 256*s;
      int cl = ii>>5, o4 = ii&31;
      float4 vb = *(const float4*)&W5T[(size_t)(cc+cl)*512 + otile + 4*o4];
      *(float4*)&b_sh[cl*ASTB + 4*o4 + 4*(o4>>1)] = vb;
    }
    __syncthreads();
    #pragma unroll
    for(int c=0;c<16;c++){
      float4 A0 = *(const float4*)&a_sh[c*ASTA + aoff];
      float4 B0 = *(const float4*)&b_sh[c*ASTB + 12*tm];
      float4 B1 = *(const float4*)&b_sh[c*ASTB + 12*tm + 4];
      float b0v=B0.x,b1v=B0.y,b2v=B0.z,b3v=B0.w,b4v=B1.x,b5v=B1.y,b6v=B1.z,b7v=B1.w;
      float a;
      a=A0.x; FMA_ROW(0)
      a=A0.y; FMA_ROW(1)
      a=A0.z; FMA_ROW(2)
      a=A0.w; FMA_ROW(3)
    }
  }
  #pragma unroll
  for(int j=0;j<8;j++){
    float M=-INFINITY, m=INFINITY;
    #pragma unroll
    for(int i=0;i<4;i++){ M=fmaxf(M,acc[i][j]); m=fminf(m,acc[i][j]); }
    #pragma unroll
    for(int d=1; d<16; d<<=1){
      M = fmaxf(M, __shfl_xor(M, d));
      m = fminf(m, __shfl_xor(m, d));
    }
    if(tn == 0){
      int o = otile + tm*8 + j;
      atomicMax(&mxe[b*512+o], encf(M));
      atomicMin(&mne[b*512+o], encf(m));
    }
  }
}

// ---------------- head (big): split-bf16 MFMA ----------------
// xcat 3-split into fragment-major tiled layout (KT=16, row space = BN).
__launch_bounds__(256) __global__ void cvt_k(const float* __restrict__ x1, const float* __restrict__ x2,
    const float* __restrict__ x3, const float* __restrict__ x4,
    u16* __restrict__ xh, u16* __restrict__ xm, u16* __restrict__ xl){
  const size_t t = (size_t)blockIdx.x*256 + threadIdx.x;   // BN*512/8 chunks
  const int l = (int)(t & 63);
  const size_t tile = t >> 6;           // rgG*16 + kt
  const int kt = (int)(tile & 15);
  const size_t rgG = tile >> 4;
  const size_t row = rgG*16 + (l & 15);
  const int col = kt*32 + ((l>>4)<<3);
  const float* src; int stride, coff;
  if(col<64)      { src=x1; stride=64;  coff=col; }
  else if(col<128){ src=x2; stride=64;  coff=col-64; }
  else if(col<256){ src=x3; stride=128; coff=col-128; }
  else            { src=x4; stride=256; coff=col-256; }
  const float* p = src + row*stride + coff;
  float4 v0 = *(const float4*)p;
  float4 v1 = *(const float4*)(p+4);
  float vs[8] = {v0.x,v0.y,v0.z,v0.w,v1.x,v1.y,v1.z,v1.w};
  ushort8 H, M, L;
  #pragma unroll
  for(int j=0;j<8;j++){ u16 h,m,lo; bf16split3(vs[j],h,m,lo); H[j]=h; M[j]=m; L[j]=lo; }
  *(ushort8*)(xh + t*8) = H;
  *(ushort8*)(xm + t*8) = M;
  *(ushort8*)(xl + t*8) = L;
}

// C[16384x512] = xcat * W5^T via 6 bf16 MFMA products, fused per-column max/min.
// 64-col tiles: grid (128 rowblk, 8 colblk); A-sharing blocks 128 apart -> same XCD L2.
__launch_bounds__(256) __global__ void w5mfma_k(const u16* __restrict__ xh, const u16* __restrict__ xm,
    const u16* __restrict__ xl,
    const u16* __restrict__ wh, const u16* __restrict__ wm, const u16* __restrict__ wl,
    unsigned* mxe, unsigned* mne){
  const int tid = threadIdx.x;
  const int l  = tid & 63, wv = tid >> 6;
  const int lg = l >> 4, lr = l & 15;
  const int row0 = blockIdx.x*128 + (wv>>1)*64;   // M base of this wave (global BN rows)
  const int col0 = blockIdx.y*64 + (wv&1)*32;     // N base of this wave
  const int b = blockIdx.x >> 4;                  // 16 M-blocks per batch
  f32x4 acc[4][2];
  #pragma unroll
  for(int m=0;m<4;m++){
    #pragma unroll
    for(int n=0;n<2;n++) acc[m][n] = (f32x4){0.f,0.f,0.f,0.f};
  }
  const size_t abase = (size_t)(row0>>4)*16*512 + (size_t)l*8;
  const size_t bbase = (size_t)(col0>>4)*16*512 + (size_t)l*8;
  for(int kt=0; kt<16; kt++){
    short8 Ah[4], Am[4], Al[4], Bh[2], Bm[2], Bl[2];
    #pragma unroll
    for(int m=0;m<4;m++){
      size_t o = abase + (size_t)(m*16 + kt)*512;
      Ah[m] = *(const short8*)(xh + o);
      Am[m] = *(const short8*)(xm + o);
      Al[m] = *(const short8*)(xl + o);
    }
    #pragma unroll
    for(int n=0;n<2;n++){
      size_t o = bbase + (size_t)(n*16 + kt)*512;
      Bh[n] = *(const short8*)(wh + o);
      Bm[n] = *(const short8*)(wm + o);
      Bl[n] = *(const short8*)(wl + o);
    }
    #pragma unroll
    for(int m=0;m<4;m++){
      #pragma unroll
      for(int n=0;n<2;n++){
        MFMA6(acc[m][n], Ah[m], Am[m], Al[m], Bh[n], Bm[n], Bl[n])
      }
    }
  }
  #pragma unroll
  for(int n=0;n<2;n++){
    float M = -INFINITY, mnv = INFINITY;
    #pragma unroll
    for(int m=0;m<4;m++){
      #pragma unroll
      for(int r=0;r<4;r++){ float v = acc[m][n][r]; M = fmaxf(M, v); mnv = fminf(mnv, v); }
    }
    M   = fmaxf(M,   __shfl_xor(M, 16));   M   = fmaxf(M,   __shfl_xor(M, 32));
    mnv = fminf(mnv, __shfl_xor(mnv, 16)); mnv = fminf(mnv, __shfl_xor(mnv, 32));
    if(lg == 0){
      int o = col0 + n*16 + lr;
      atomicMax(&mxe[b*512+o], encf(M));
      atomicMin(&mne[b*512+o], encf(mnv));
    }
  }
}

__launch_bounds__(256) __global__ void final_k(const unsigned* mxe, const unsigned* mne,
    const float* g5, const float* b5, const float* Wemb, float* out){
  const int b = blockIdx.x, t = threadIdx.x;
  __shared__ float h[512];
  for(int o=t; o<512; o+=256){
    float mx = decf(mxe[b*512+o]);
    float mn = decf(mne[b*512+o]);
    float a  = g5[o] * RSQ;
    float bo = b5[o];
    float hv = lrelu((a >= 0.f ? a*mx : a*mn) + bo);
    h[o] = hv;
    out[b*512+o] = hv;
  }
  __syncthreads();
  const float* wr = Wemb + (size_t)t*512;
  float s = 0.f;
  for(int o=0;o<512;o+=4){
    float4 w4 = *(const float4*)(wr+o);
    s = fmaf(h[o],w4.x, fmaf(h[o+1],w4.y, fmaf(h[o+2],w4.z, fmaf(h[o+3],w4.w, s))));
  }
  out[4096 + b*256 + t] = s;
}

// ---------------- launch ----------------
extern "C" void kernel_launch(void* const* d_in, const int* in_sizes, int n_in,
                              void* d_out, int out_size, void* d_ws, size_t ws_size,
                              hipStream_t stream) {
  if (ws_size < WS_END * sizeof(float)) return;
  const bool big = ws_size >= WS_BIG_END * sizeof(float);   // deterministic per call

  const float* x0   = (const float*)d_in[0];
  const float* W1   = (const float*)d_in[1];
  const float* g1   = (const float*)d_in[2];
  const float* b1   = (const float*)d_in[3];
  const float* W2   = (const float*)d_in[4];
  const float* g2   = (const float*)d_in[5];
  const float* b2   = (const float*)d_in[6];
  const float* W3   = (const float*)d_in[7];
  const float* g3   = (const float*)d_in[8];
  const float* b3   = (const float*)d_in[9];
  const float* W4   = (const float*)d_in[10];
  const float* g4   = (const float*)d_in[11];
  const float* b4   = (const float*)d_in[12];
  const float* W5   = (const float*)d_in[13];
  const float* g5   = (const float*)d_in[14];
  const float* b5   = (const float*)d_in[15];
  const float* Wemb = (const float*)d_in[16];

  float* ws = (float*)d_ws;
  float* xx = ws + OFF_XX;
  float* x1 = ws + OFF_X1;  float* x2 = ws + OFF_X2;
  float* x3 = ws + OFF_X3;  float* x4 = ws + OFF_X4;
  float* qpS = ws + OFF_SC;               // L1 qp (width 128) + fallback chunked q/bs
  float* bsS = ws + OFF_SC + (size_t)BN*64;
  int*   id = (int*)(ws + OFF_ID);
  float* W5Tf = ws + OFF_W5T;
  unsigned* mxe = (unsigned*)(ws + OFF_MX);
  unsigned* mne = (unsigned*)(ws + OFF_MN);
  float* WT2 = ws + OFF_WT2;
  float* WT3 = ws + OFF_WT3;
  float* WT4 = ws + OFF_WT4;
  float* distD = ws + OFF_X3;   // fallback dual-batch
  float* distS = ws + OFF_X4;   // fallback single-batch
  float* distB = ws + OFF_BIG;  // big: 4-batch dist chunk, then reused as qp buffer / bf16 xcat
  u16* w5h = (u16*)(ws + OFF_SC + (size_t)BN*128);   // SC tail (free in both paths): 3x256KB
  u16* w5m = w5h + 512*512;
  u16* w5l = w5m + 512*512;
  u16* wts = (u16*)W5Tf;         // big path: tiled WT splits live in the (unused) W5T region
  float* out = (float*)d_out;

  prep_k<<<1024,256,0,stream>>>(W5, W2, W3, W4, W5Tf, WT2, WT3, WT4,
                                w5h, w5m, w5l, wts, mxe, mne, big ? 1 : 0);

  // layer 1 (3 -> 64)
  sel3_k<<<BN*64/256,256,0,stream>>>(x0, id);
  qp3_k<<<BN*8/256,256,0,stream>>>(x0, W1, qpS);
  gather_qp_k<64><<<BN*64/256,256,0,stream>>>(qpS, id, g1, b1, x1);

  if(big){
    float* qpB = distB;                      // reuse dist region post-sel
    // split scratch lives in x4 region (dead until layer-4 gather)
    u16* sh = (u16*)x4;
    // layer 2 (CIN=64 -> COUT=64, qp width 128)
    { u16* sm = sh + (size_t)BN*64; u16* sl = sm + (size_t)BN*64;
      sqnorm_k<64><<<BN/256,256,0,stream>>>(x1, xx);
      split_k<64><<<BN*64/8/256,256,0,stream>>>(x1, sh, sm, sl);
      for(int c0=0;c0<BB;c0+=4){
        mfma_dist_k<64><<<dim3(32,16,4),256,0,stream>>>(sh, sm, sl, xx, distB, c0);
        sel_k<<<(4*NN)/4,256,0,stream>>>(distB, id, c0, 4*NN);
      }
      qp_mfma_k<2,128><<<dim3(BN/128,2),256,0,stream>>>(sh, sm, sl,
          wts+WTS_2H, wts+WTS_2M, wts+WTS_2L, qpB);
      gather_qp_k<64><<<BN*64/256,256,0,stream>>>(qpB, id, g2, b2, x2); }
    // layer 3 (64 -> 128, qp width 256)
    { u16* sm = sh + (size_t)BN*64; u16* sl = sm + (size_t)BN*64;
      sqnorm_k<64><<<BN/256,256,0,stream>>>(x2, xx);
      split_k<64><<<BN*64/8/256,256,0,stream>>>(x2, sh, sm, sl);
      for(int c0=0;c0<BB;c0+=4){
        mfma_dist_k<64><<<dim3(32,16,4),256,0,stream>>>(sh, sm, sl, xx, distB, c0);
        sel_k<<<(4*NN)/4,256,0,stream>>>(distB, id, c0, 4*NN);
      }
      qp_mfma_k<2,256><<<dim3(BN/128,4),256,0,stream>>>(sh, sm, sl,
          wts+WTS_3H, wts+WTS_3M, wts+WTS_3L, qpB);
      gather_qp_k<128><<<BN*128/256,256,0,stream>>>(qpB, id, g3, b3, x3); }
    // layer 4 (128 -> 256, qp width 512)
    { u16* sm = sh + (size_t)BN*128; u16* sl = sm + (size_t)BN*128;
      sqnorm_k<128><<<BN/256,256,0,stream>>>(x3, xx);
      split_k<128><<<BN*128/8/256,256,0,stream>>>(x3, sh, sm, sl);
      for(int c0=0;c0<BB;c0+=4){
        mfma_dist_k<128><<<dim3(32,16,4),256,0,stream>>>(sh, sm, sl, xx, distB, c0);
        sel_k<<<(4*NN)/4,256,0,stream>>>(distB, id, c0, 4*NN);
      }
      qp_mfma_k<4,512><<<dim3(BN/128,8),256,0,stream>>>(sh, sm, sl,
          wts+WTS_4H, wts+WTS_4M, wts+WTS_4L, qpB);
      gather_qp_k<256><<<BN*256/256,256,0,stream>>>(qpB, id, g4, b4, x4); }
    // head: bf16 3-split (tiled) + 6-product MFMA
    u16* xh = (u16*)(ws + OFF_XCAT);
    u16* xm = xh + (size_t)BN*512;
    u16* xl = xm + (size_t)BN*512;
    cvt_k<<<BN*512/8/256,256,0,stream>>>(x1, x2, x3, x4, xh, xm, xl);
    w5mfma_k<<<dim3(128,8),256,0,stream>>>(xh, xm, xl, w5h, w5m, w5l, mxe, mne);
  } else {
    // fallback: chunked (R12 structure, cat weight layout)
    sqnorm_k<64><<<BN/256,256,0,stream>>>(x1, xx);
    for(int r=0;r<4;r++){
      gemm_dist_k<64><<<dim3(16,16,2),256,0,stream>>>(x1, xx, distD, 2*r);
      sel_k<<<(2*NN)/4,256,0,stream>>>(distD, id, 2*r, 2*NN);
    }
    qp64T_k<64,64><<<BN*8/256,256,0,stream>>>(x1, WT2, 0, qpS, bsS);
    gather_chunk_k<64><<<BN*64/256,256,0,stream>>>(qpS, bsS, id, g2, b2, 0, x2);

    sqnorm_k<64><<<BN/256,256,0,stream>>>(x2, xx);
    for(int r=0;r<4;r++){
      gemm_dist_k<64><<<dim3(16,16,2),256,0,stream>>>(x2, xx, distD, 2*r);
      sel_k<<<(2*NN)/4,256,0,stream>>>(distD, id, 2*r, 2*NN);
    }
    for(int cb=0; cb<128; cb+=64){
      qp64T_k<64,128><<<BN*8/256,256,0,stream>>>(x2, WT3, cb, qpS, bsS);
      gather_chunk_k<128><<<BN*64/256,256,0,stream>>>(qpS, bsS, id, g3, b3, cb, x3);
    }

    sqnorm_k<128><<<BN/256,256,0,stream>>>(x3, xx);
    for(int r=0;r<8;r++){
      gemm_dist_k<128><<<dim3(16,16,1),256,0,stream>>>(x3, xx, distS, r);
      sel_k<<<NN/4,256,0,stream>>>(distS, id, r, NN);
    }
    for(int cb=0; cb<256; cb+=64){
      qp64T_k<128,256><<<BN*8/256,256,0,stream>>>(x3, WT4, cb, qpS, bsS);
      gather_chunk_k<256><<<BN*64/256,256,0,stream>>>(qpS, bsS, id, g4, b4, cb, x4);
    }
    w5gemm_k<<<dim3(4,32,8),256,0,stream>>>(x1, x2, x3, x4, W5Tf, mxe, mne);
  }

  final_k<<<BB,256,0,stream>>>(mxe, mne, g5, b5, Wemb, out);
}

// Round 15
// 581.784 us; speedup vs baseline: 1.0900x; 1.0391x over previous
//
#include <hip/hip_runtime.h>
#include <hip/hip_bf16.h>

#define BB 8
#define NN 2048
#define KK 20
#define BN (BB*NN)
#define RSQ 0.99999500003749969f   // 1/sqrt(1+1e-5)

// ---------------- workspace layout (float-slot units) ----------------
constexpr size_t OFF_XX  = 0;                          // BN
constexpr size_t OFF_X1  = OFF_XX  + BN;               // BN*64
constexpr size_t OFF_X2  = OFF_X1  + (size_t)BN*64;    // BN*64
constexpr size_t OFF_X3  = OFF_X2  + (size_t)BN*64;    // BN*128
constexpr size_t OFF_X4  = OFF_X3  + (size_t)BN*128;   // BN*256 (split-scratch pre-gather)
constexpr size_t OFF_SC  = OFF_X4  + (size_t)BN*256;   // BN*160 (L1 qp + fallback chunked qp + W5 bf16 tail)
constexpr size_t OFF_ID  = OFF_SC  + (size_t)BN*160;   // int BN*20
constexpr size_t OFF_W5T = OFF_ID  + (size_t)BN*20;    // 512*512 (big path: tiled WT splits live here)
constexpr size_t OFF_MX  = OFF_W5T + 512*512;
constexpr size_t OFF_MN  = OFF_MX  + BB*512;
constexpr size_t OFF_WT2 = OFF_MN  + BB*512;           // cat [64][128]
constexpr size_t OFF_WT3 = OFF_WT2 + 8192;             // cat [64][256]
constexpr size_t OFF_WT4 = OFF_WT3 + 16384;            // cat [128][512]
constexpr size_t WS_END  = OFF_WT4 + 65536;            // 11,714,560 floats
// big region (probed at runtime): dist chunk (4 batches) + qp buffer + bf16 xcat post-sel
constexpr size_t OFF_BIG = WS_END;
constexpr size_t OFF_XCAT = OFF_BIG + (size_t)16*1024*1024;  // bf16 xcat h/m (dist region tail, post-KNN)
constexpr size_t WS_BIG_END = OFF_BIG + (size_t)BB*NN*NN;   // 172.7 MiB
static_assert(OFF_ID - OFF_X3 >= (size_t)4096*2048, "fallback dual dist fits");
static_assert(OFF_XCAT + (size_t)BN*512 <= WS_BIG_END, "xcat h/m fits in dist region");

typedef unsigned short u16;
typedef __attribute__((ext_vector_type(8))) short short8;
typedef __attribute__((ext_vector_type(8))) unsigned short ushort8;
typedef __attribute__((ext_vector_type(4))) float f32x4;

// tiled WT split offsets (u16 units) within the W5T region (big path only)
constexpr size_t WTS_2H = 0,      WTS_2M = 8192,   WTS_2L = 16384;
constexpr size_t WTS_3H = 24576,  WTS_3M = 40960,  WTS_3L = 57344;
constexpr size_t WTS_4H = 73728,  WTS_4M = 139264, WTS_4L = 204800;   // end 270336 u16 <= 524288

__device__ inline unsigned encf(float f){ unsigned u=__float_as_uint(f); return (u&0x80000000u)? ~u : (u|0x80000000u); }
__device__ inline float decf(unsigned e){ unsigned u=(e&0x80000000u)? (e&0x7fffffffu) : ~e; return __uint_as_float(u); }
__device__ inline float lrelu(float h){ return h>=0.f ? h : 0.2f*h; }
__device__ inline u16 bf16rne(float x){
  unsigned u = __float_as_uint(x);
  return (u16)((u + 0x7FFFu + ((u>>16)&1u)) >> 16);
}
__device__ inline float bf16f(u16 h){ return __uint_as_float((unsigned)h<<16); }
// exact 3-way split: x == h + m + l for normal fp32 (24 mantissa bits covered)
__device__ inline void bf16split3(float v, u16& h, u16& m, u16& l){
  h = bf16rne(v);  float r1 = v  - bf16f(h);
  m = bf16rne(r1); float r2 = r1 - bf16f(m);
  l = bf16rne(r2);
}

__device__ inline float readlane_f(float v, int sl){
  return __int_as_float(__builtin_amdgcn_readlane(__float_as_int(v), sl));
}

// Wave-cooperative sorted-top-20 insertion (cv known > theta on call).
#define INSERT_CAND(cv, ci) { \
  unsigned long long mge = __ballot((lv > cv) || (lv == cv && li < ci)); \
  int pos = __popcll(mge); \
  float upv = __shfl_up(lv, 1); \
  int   upi = __shfl_up(li, 1); \
  bool shift = (lane > pos) && (lane < KK); \
  lv = (lane == pos) ? cv : (shift ? upv : lv); \
  li = (lane == pos) ? ci : (shift ? upi : li); \
  theta = readlane_f(lv, KK-1); }

// Bitonic full sort of 64 (value desc, index asc on ties) across lanes; (v,vi) in registers.
#define BITONIC64_DESC(v, vi) { \
  _Pragma("unroll") \
  for(int k=2; k<=64; k<<=1){ \
    _Pragma("unroll") \
    for(int j=k>>1; j>=1; j>>=1){ \
      float ov = __shfl_xor(v, j); \
      int   oi = __shfl_xor(vi, j); \
      int partner = lane ^ j; \
      bool keepFirst = (((lane & k) == 0)) == (lane < partner); \
      bool before = (v > ov) || (v == ov && vi < oi); \
      if(keepFirst != before){ v = ov; vi = oi; } \
    } \
  } }

// 6-product split-bf16 MFMA macro (fp32-exact to ~2^-27): KNN-critical GEMMs.
#define MFMA6(ACC, AH, AM, AL, BH, BM, BL) { \
  ACC = __builtin_amdgcn_mfma_f32_16x16x32_bf16(AH, BH, ACC, 0, 0, 0); \
  ACC = __builtin_amdgcn_mfma_f32_16x16x32_bf16(AH, BM, ACC, 0, 0, 0); \
  ACC = __builtin_amdgcn_mfma_f32_16x16x32_bf16(AM, BH, ACC, 0, 0, 0); \
  ACC = __builtin_amdgcn_mfma_f32_16x16x32_bf16(AH, BL, ACC, 0, 0, 0); \
  ACC = __builtin_amdgcn_mfma_f32_16x16x32_bf16(AL, BH, ACC, 0, 0, 0); \
  ACC = __builtin_amdgcn_mfma_f32_16x16x32_bf16(AM, BM, ACC, 0, 0, 0); }

// 3-product variant (error ~3*2^-18 relative): terminal GEMMs only (head, layer-4 qp).
#define MFMA3(ACC, AH, AM, BH, BM) { \
  ACC = __builtin_amdgcn_mfma_f32_16x16x32_bf16(AH, BH, ACC, 0, 0, 0); \
  ACC = __builtin_amdgcn_mfma_f32_16x16x32_bf16(AH, BM, ACC, 0, 0, 0); \
  ACC = __builtin_amdgcn_mfma_f32_16x16x32_bf16(AM, BH, ACC, 0, 0, 0); }

// ======== fragment-major tiled split layout ========
// split[rowGroup][kTile][lane=64][8]  (u16). lane l -> row = rg*16 + (l&15), k = kt*32 + (l>>4)*8.

// ---------------- prep: weights transposes + splits + enc ----------------
__global__ void prep_k(const float* W5, const float* W2, const float* W3, const float* W4,
                       float* W5T, float* WT2, float* WT3, float* WT4,
                       u16* w5h, u16* w5m, u16* w5l, u16* wts,
                       unsigned* mx, unsigned* mn, int big){
  int i = blockIdx.x*256 + threadIdx.x;     // 262144
  if(!big){ int o = i>>9, c = i&511; W5T[c*512+o] = W5[i]; }   // fp32 W5T only for fallback
  { // tiled split of W5 (B-side rows = output cols o, k = input c). KT=16.
    int rg = i>>13, kt = (i>>9)&15, l = (i>>3)&63, j = i&7;
    int o = rg*16 + (l&15);
    int c = kt*32 + ((l>>4)<<3) + j;
    u16 h,m,lo; bf16split3(W5[(size_t)o*512 + c], h, m, lo);
    w5h[i]=h; w5m[i]=m; w5l[i]=lo; }
  if(i < 65536){ int c = i>>9, o = i&511;   // W4: [256][256] -> cat [128][512]
    WT4[i] = (o<256) ? W4[(size_t)o*256 + c] : W4[(size_t)(o-256)*256 + 128 + c]; }
  if(i < 16384){ int c = i>>8, o = i&255;   // W3: [128][128] -> cat [64][256]
    WT3[i] = (o<128) ? W3[(size_t)o*128 + c] : W3[(size_t)(o-128)*128 + 64 + c]; }
  if(i <  8192){ int c = i>>7, o = i&127;   // W2: [64][128] -> cat [64][128]
    WT2[i] = (o<64) ? W2[(size_t)o*128 + c] : W2[(size_t)(o-64)*128 + 64 + c]; }
  if(big){
    if(i < 65536){ // WT4 tiled split: rg over o (32), kt over c (4)
      int rg=i>>11, kt=(i>>9)&3, l=(i>>3)&63, j=i&7;
      int o = rg*16 + (l&15);
      int c = kt*32 + ((l>>4)<<3) + j;
      float v = (o<256) ? W4[(size_t)o*256 + c] : W4[(size_t)(o-256)*256 + 128 + c];
      u16 h,m,lo; bf16split3(v,h,m,lo);
      wts[WTS_4H+i]=h; wts[WTS_4M+i]=m; wts[WTS_4L+i]=lo; }
    if(i < 16384){ // WT3 tiled split: rg over o (16), kt over c (2)
      int rg=i>>10, kt=(i>>9)&1, l=(i>>3)&63, j=i&7;
      int o = rg*16 + (l&15);
      int c = kt*32 + ((l>>4)<<3) + j;
      float v = (o<128) ? W3[(size_t)o*128 + c] : W3[(size_t)(o-128)*128 + 64 + c];
      u16 h,m,lo; bf16split3(v,h,m,lo);
      wts[WTS_3H+i]=h; wts[WTS_3M+i]=m; wts[WTS_3L+i]=lo; }
    if(i < 8192){  // WT2 tiled split: rg over o (8), kt over c (2)
      int rg=i>>10, kt=(i>>9)&1, l=(i>>3)&63, j=i&7;
      int o = rg*16 + (l&15);
      int c = kt*32 + ((l>>4)<<3) + j;
      float v = (o<64) ? W2[(size_t)o*128 + c] : W2[(size_t)(o-64)*128 + 64 + c];
      u16 h,m,lo; bf16split3(v,h,m,lo);
      wts[WTS_2H+i]=h; wts[WTS_2M+i]=m; wts[WTS_2L+i]=lo; }
  }
  if(i <  4096){ mx[i] = 0x007FFFFFu; mn[i] = 0xFF800000u; }
}

// ---------------- KNN ----------------
template<int C>
__launch_bounds__(256) __global__ void sqnorm_k(const float* X, float* xx){
  int i = blockIdx.x*256 + threadIdx.x;   // BN
  const float* r = X + (size_t)i*C;
  float s = 0.f;
  #pragma unroll
  for(int c=0;c<C;c++) s = fmaf(r[c], r[c], s);
  xx[i] = s;
}

// 3-way bf16 split of X [BN][C] into fragment-major tiled layout.
template<int C>
__launch_bounds__(256) __global__ void split_k(const float* __restrict__ X,
    u16* __restrict__ xh, u16* __restrict__ xm, u16* __restrict__ xl){
  constexpr int KT = C/32;
  const size_t t = (size_t)blockIdx.x*256 + threadIdx.x;   // BN*C/8 chunks
  const int l = (int)(t & 63);
  const size_t tile = t >> 6;               // rgG*KT + kt
  const int kt = (int)(tile & (KT-1));
  const size_t rgG = tile / KT;             // global row group (BN/16 total)
  const size_t row = rgG*16 + (l & 15);
  const int k = kt*32 + ((l>>4)<<3);
  const float* p = X + row*C + k;
  float4 v0 = *(const float4*)p;
  float4 v1 = *(const float4*)(p+4);
  float vs[8] = {v0.x,v0.y,v0.z,v0.w,v1.x,v1.y,v1.z,v1.w};
  ushort8 H,M,L;
  #pragma unroll
  for(int j=0;j<8;j++){ u16 h,m,lo; bf16split3(vs[j],h,m,lo); H[j]=h; M[j]=m; L[j]=lo; }
  *(ushort8*)(xh + t*8) = H;
  *(ushort8*)(xm + t*8) = M;
  *(ushort8*)(xl + t*8) = L;
}

#define FMA_ROW(I) \
  acc[I][0]=fmaf(a,b0v,acc[I][0]); acc[I][1]=fmaf(a,b1v,acc[I][1]); \
  acc[I][2]=fmaf(a,b2v,acc[I][2]); acc[I][3]=fmaf(a,b3v,acc[I][3]); \
  acc[I][4]=fmaf(a,b4v,acc[I][4]); acc[I][5]=fmaf(a,b5v,acc[I][5]); \
  acc[I][6]=fmaf(a,b6v,acc[I][6]); acc[I][7]=fmaf(a,b7v,acc[I][7]);

// fallback fp32 dist GEMM
template<int C>
__launch_bounds__(256) __global__ void gemm_dist_k(const float* __restrict__ X, const float* __restrict__ xx,
                                                   float* __restrict__ dist, int b0){
  constexpr int AST = 188;
  __shared__ __align__(16) float a_sh[16*AST];
  __shared__ __align__(16) float b_sh[16*AST];
  __shared__ float sxn[128], sxm[128];
  const int tid = threadIdx.x;
  const int b   = b0 + blockIdx.z;
  const int mtile = blockIdx.x*128;
  const int ntile = blockIdx.y*128;
  const int tn = tid & 15, tm = tid >> 4;
  const float* Xb  = X  + (size_t)b*NN*C;
  const float* xxb = xx + (size_t)b*NN;
  if(tid < 128) sxn[tid] = xxb[ntile + tid];
  else          sxm[tid-128] = xxb[mtile + tid-128];
  float acc[8][8];
  #pragma unroll
  for(int i=0;i<8;i++){
    #pragma unroll
    for(int j=0;j<8;j++) acc[i][j]=0.f;
  }
  for(int cc=0; cc<C; cc+=16){
    __syncthreads();
    #pragma unroll
    for(int s=0;s<2;s++){
      int ii = tid + 256*s; int r = ii>>2, q = ii&3;
      int pr = r + 4*(r>>3);
      float4 va = *(const float4*)&Xb[(size_t)(ntile + r)*C + cc + 4*q];
      a_sh[(4*q+0)*AST + pr]=va.x; a_sh[(4*q+1)*AST + pr]=va.y;
      a_sh[(4*q+2)*AST + pr]=va.z; a_sh[(4*q+3)*AST + pr]=va.w;
      float4 vb = *(const float4*)&Xb[(size_t)(mtile + r)*C + cc + 4*q];
      b_sh[(4*q+0)*AST + pr]=vb.x; b_sh[(4*q+1)*AST + pr]=vb.y;
      b_sh[(4*q+2)*AST + pr]=vb.z; b_sh[(4*q+3)*AST + pr]=vb.w;
    }
    __syncthreads();
    #pragma unroll
    for(int c=0;c<16;c++){
      float4 A0 = *(const float4*)&a_sh[c*AST + 12*tn];
      float4 A1 = *(const float4*)&a_sh[c*AST + 12*tn + 4];
      float4 B0 = *(const float4*)&b_sh[c*AST + 12*tm];
      float4 B1 = *(const float4*)&b_sh[c*AST + 12*tm + 4];
      float b0v=B0.x,b1v=B0.y,b2v=B0.z,b3v=B0.w,b4v=B1.x,b5v=B1.y,b6v=B1.z,b7v=B1.w;
      float a;
      a=A0.x; FMA_ROW(0)
      a=A0.y; FMA_ROW(1)
      a=A0.z; FMA_ROW(2)
      a=A0.w; FMA_ROW(3)
      a=A1.x; FMA_ROW(4)
      a=A1.y; FMA_ROW(5)
      a=A1.z; FMA_ROW(6)
      a=A1.w; FMA_ROW(7)
    }
  }
  float xnr[8], xmr[8];
  #pragma unroll
  for(int i=0;i<8;i++){ xnr[i]=sxn[tn*8+i]; xmr[i]=sxm[tm*8+i]; }
  const size_t rowb = (size_t)blockIdx.z*NN + ntile + tn*8;
  #pragma unroll
  for(int i=0;i<8;i++){
    float4 w0, w1;
    w0.x=(2.f*acc[i][0]-xnr[i])-xmr[0]; w0.y=(2.f*acc[i][1]-xnr[i])-xmr[1];
    w0.z=(2.f*acc[i][2]-xnr[i])-xmr[2]; w0.w=(2.f*acc[i][3]-xnr[i])-xmr[3];
    w1.x=(2.f*acc[i][4]-xnr[i])-xmr[4]; w1.y=(2.f*acc[i][5]-xnr[i])-xmr[5];
    w1.z=(2.f*acc[i][6]-xnr[i])-xmr[6]; w1.w=(2.f*acc[i][7]-xnr[i])-xmr[7];
    float* dp = dist + (rowb + i)*NN + mtile + tm*8;
    *(float4*)dp = w0;
    *(float4*)(dp+4) = w1;
  }
}

// big path: exact-fp32-quality dist via split-bf16 MFMA (6 products of 3-way split).
// 64-col tiles for occupancy: grid (NN/64, 16, 4chunk); block 128q x 64c; wave 64q x 32c.
template<int C>
__launch_bounds__(256) __global__ void mfma_dist_k(const u16* __restrict__ xh, const u16* __restrict__ xm,
    const u16* __restrict__ xl, const float* __restrict__ xx, float* __restrict__ dist, int b0){
  constexpr int KT = C/32;
  const int tid = threadIdx.x;
  const int l  = tid & 63, wv = tid >> 6;
  const int lg = l >> 4, lr = l & 15;
  const int cz = blockIdx.z;
  const int b  = b0 + cz;
  const int qrow0 = blockIdx.y*128 + (wv>>1)*64;   // query rows (A side, dist row)
  const int crow0 = blockIdx.x*64 + (wv&1)*32;     // candidate rows (B side, dist col)
  const size_t brg = (size_t)b*(NN/16);
  f32x4 acc[4][2];
  #pragma unroll
  for(int m=0;m<4;m++){
    #pragma unroll
    for(int n=0;n<2;n++) acc[m][n] = (f32x4){0.f,0.f,0.f,0.f};
  }
  const size_t abase = (brg + (qrow0>>4))*KT*512 + (size_t)l*8;
  const size_t bbase = (brg + (crow0>>4))*KT*512 + (size_t)l*8;
  for(int kt=0; kt<KT; kt++){
    short8 Ah[4], Am[4], Al[4], Bh[2], Bm[2], Bl[2];
    #pragma unroll
    for(int m=0;m<4;m++){
      size_t o = abase + (size_t)(m*KT + kt)*512;
      Ah[m] = *(const short8*)(xh + o);
      Am[m] = *(const short8*)(xm + o);
      Al[m] = *(const short8*)(xl + o);
    }
    #pragma unroll
    for(int n=0;n<2;n++){
      size_t o = bbase + (size_t)(n*KT + kt)*512;
      Bh[n] = *(const short8*)(xh + o);
      Bm[n] = *(const short8*)(xm + o);
      Bl[n] = *(const short8*)(xl + o);
    }
    #pragma unroll
    for(int m=0;m<4;m++){
      #pragma unroll
      for(int n=0;n<2;n++){
        MFMA6(acc[m][n], Ah[m], Am[m], Al[m], Bh[n], Bm[n], Bl[n])
      }
    }
  }
  const float* xxb = xx + (size_t)b*NN;
  float xxc[2];
  #pragma unroll
  for(int n=0;n<2;n++) xxc[n] = xxb[crow0 + n*16 + lr];
  #pragma unroll
  for(int m=0;m<4;m++){
    #pragma unroll
    for(int r=0;r<4;r++){
      int qr = qrow0 + m*16 + 4*lg + r;
      float xq = xxb[qr];
      float* dp = dist + ((size_t)cz*NN + qr)*NN + crow0;
      #pragma unroll
      for(int n=0;n<2;n++) dp[n*16 + lr] = (2.f*acc[m][n][r] - xq) - xxc[n];
    }
  }
}

// Wave-cooperative top-20: max-of-4 bitonic warm start + slim insertions, float4 scan.
__launch_bounds__(256) __global__ void sel_k(const float* __restrict__ dist, int* __restrict__ id,
                                             int b0, int nrows){
  const int w = (blockIdx.x*256 + threadIdx.x) >> 6;
  const int lane = threadIdx.x & 63;
  if(w >= nrows) return;
  const float* dr = dist + (size_t)w*NN;
  float4 c0 = *(const float4*)&dr[4*lane];
  float cd0[4] = {c0.x, c0.y, c0.z, c0.w};
  int jbest = 0; float v = cd0[0];
  #pragma unroll
  for(int j=1;j<4;j++){ if(cd0[j] > v){ v = cd0[j]; jbest = j; } }
  int vi = 4*lane + jbest;
  BITONIC64_DESC(v, vi)
  float lv = (lane < KK) ? v : -INFINITY;
  int   li = (lane < KK) ? vi : 0;
  float theta = readlane_f(lv, KK-1);
  #pragma unroll
  for(int j=0;j<4;j++){
    float cand = (j == jbest) ? -INFINITY : cd0[j];
    unsigned long long bal = __ballot(cand > theta);
    while(bal){
      int bpos = __ffsll((unsigned long long)bal) - 1;
      bal &= bal - 1;
      float cv = readlane_f(cand, bpos);
      if(cv > theta){
        int ci = 4*bpos + j;
        INSERT_CAND(cv, ci)
      }
    }
  }
  for(int ms=256; ms<NN; ms+=256){
    float4 c4 = *(const float4*)&dr[ms + 4*lane];
    #pragma unroll
    for(int j=0;j<4;j++){
      float cand = (j==0)?c4.x:(j==1)?c4.y:(j==2)?c4.z:c4.w;
      unsigned long long bal = __ballot(cand > theta);
      while(bal){
        int bpos = __ffsll((unsigned long long)bal) - 1;
        bal &= bal - 1;
        float cv = readlane_f(cand, bpos);
        if(cv > theta){
          int ci = ms + 4*bpos + j;
          INSERT_CAND(cv, ci)
        }
      }
    }
  }
  if(lane < KK) id[((size_t)b0*NN + w)*KK + lane] = li;
}

// L1 fused: inline C=3 distances + inline sqnorm, max-of-4 bitonic warm start.
__launch_bounds__(256) __global__ void sel3_k(const float* __restrict__ X, int* __restrict__ id){
  const int gw = (blockIdx.x*256 + threadIdx.x) >> 6;
  const int lane = threadIdx.x & 63;
  const int b = gw >> 11, n = gw & 2047;
  const float* Xb  = X + (size_t)b*NN*3;
  const float x0v = Xb[n*3], x1v = Xb[n*3+1], x2v = Xb[n*3+2];
  float xxn = 0.f;
  xxn = fmaf(x0v, x0v, xxn); xxn = fmaf(x1v, x1v, xxn); xxn = fmaf(x2v, x2v, xxn);
  float lv, theta; int li;
  {
    const float* p = Xb + (size_t)(4*lane)*3;
    float4 va = *(const float4*)p;
    float4 vb = *(const float4*)(p+4);
    float4 vc = *(const float4*)(p+8);
    float cx[4] = {va.x, va.w, vb.z, vc.y};
    float cy[4] = {va.y, vb.x, vb.w, vc.z};
    float cz[4] = {va.z, vb.y, vc.x, vc.w};
    float cd[4];
    #pragma unroll
    for(int j=0;j<4;j++){
      float s = 0.f;
      s = fmaf(x0v, cx[j], s); s = fmaf(x1v, cy[j], s); s = fmaf(x2v, cz[j], s);
      float xxm = 0.f;
      xxm = fmaf(cx[j], cx[j], xxm); xxm = fmaf(cy[j], cy[j], xxm); xxm = fmaf(cz[j], cz[j], xxm);
      cd[j] = (2.f*s - xxn) - xxm;
    }
    int jbest = 0; float v = cd[0];
    #pragma unroll
    for(int j=1;j<4;j++){ if(cd[j] > v){ v = cd[j]; jbest = j; } }
    int vi = 4*lane + jbest;
    BITONIC64_DESC(v, vi)
    lv = (lane < KK) ? v : -INFINITY;
    li = (lane < KK) ? vi : 0;
    theta = readlane_f(lv, KK-1);
    #pragma unroll
    for(int j=0;j<4;j++){
      float cand = (j == jbest) ? -INFINITY : cd[j];
      unsigned long long bal = __ballot(cand > theta);
      while(bal){
        int bpos = __ffsll((unsigned long long)bal) - 1;
        bal &= bal - 1;
        float cv = readlane_f(cand, bpos);
        if(cv > theta){
          int ci = 4*bpos + j;
          INSERT_CAND(cv, ci)
        }
      }
    }
  }
  for(int ms=256; ms<NN; ms+=256){
    const float* p = Xb + (size_t)(ms + 4*lane)*3;
    float4 va = *(const float4*)p;
    float4 vb = *(const float4*)(p+4);
    float4 vc = *(const float4*)(p+8);
    float cx[4] = {va.x, va.w, vb.z, vc.y};
    float cy[4] = {va.y, vb.x, vb.w, vc.z};
    float cz[4] = {va.z, vb.y, vc.x, vc.w};
    float cd[4];
    #pragma unroll
    for(int j=0;j<4;j++){
      float s = 0.f;
      s = fmaf(x0v, cx[j], s); s = fmaf(x1v, cy[j], s); s = fmaf(x2v, cz[j], s);
      float xxm = 0.f;
      xxm = fmaf(cx[j], cx[j], xxm); xxm = fmaf(cy[j], cy[j], xxm); xxm = fmaf(cz[j], cz[j], xxm);
      cd[j] = (2.f*s - xxn) - xxm;
    }
    #pragma unroll
    for(int j=0;j<4;j++){
      float cand = cd[j];
      unsigned long long bal = __ballot(cand > theta);
      while(bal){
        int bpos = __ffsll((unsigned long long)bal) - 1;
        bal &= bal - 1;
        float cv = readlane_f(cand, bpos);
        if(cv > theta){
          int ci = ms + 4*bpos + j;
          INSERT_CAND(cv, ci)
        }
      }
    }
  }
  if(lane < KK) id[(size_t)gw*KK + lane] = li;
}

// ---------------- qp ----------------
// L1: writes interleaved qp[row][128]: q at 0..63, p at 64..127
__launch_bounds__(256) __global__ void qp3_k(const float* X, const float* W, float* qp){
  const int t   = blockIdx.x*256 + threadIdx.x;
  const int row = t >> 3;
  const int c0  = (t & 7) * 8;
  float xn[3];
  #pragma unroll
  for(int c=0;c<3;c++) xn[c] = X[(size_t)row*3 + c];
  for(int oi=c0; oi<c0+8; oi++){
    const float* w = W + (size_t)oi*6;
    float aq=0.f, ap=0.f;
    #pragma unroll
    for(int c=0;c<3;c++){ aq = fmaf(xn[c], w[c], aq); ap = fmaf(xn[c], w[3+c], ap); }
    qp[(size_t)row*128 + oi]      = aq;
    qp[(size_t)row*128 + 64 + oi] = ap;
  }
}

// qp via split-bf16 MFMA: qp[BN][W2C] = Xsplit * WTsplit.
// FULL=true: 6-product (KNN-critical layers 2/3). FULL=false: 3-product (terminal layer 4).
// Grid (BN/128, W2C/64); block 128r x 64c; wave 64r x 32c.
template<int KT, int W2C, bool FULL>
__launch_bounds__(256) __global__ void qp_mfma_k(const u16* __restrict__ xh, const u16* __restrict__ xm,
    const u16* __restrict__ xl,
    const u16* __restrict__ wh, const u16* __restrict__ wm, const u16* __restrict__ wl,
    float* __restrict__ qp){
  const int tid = threadIdx.x;
  const int l  = tid & 63, wv = tid >> 6;
  const int lg = l >> 4, lr = l & 15;
  const int row0 = blockIdx.x*128 + (wv>>1)*64;
  const int col0 = blockIdx.y*64 + (wv&1)*32;
  f32x4 acc[4][2];
  #pragma unroll
  for(int m=0;m<4;m++){
    #pragma unroll
    for(int n=0;n<2;n++) acc[m][n] = (f32x4){0.f,0.f,0.f,0.f};
  }
  const size_t abase = (size_t)(row0>>4)*KT*512 + (size_t)l*8;
  const size_t bbase = (size_t)(col0>>4)*KT*512 + (size_t)l*8;
  for(int kt=0; kt<KT; kt++){
    short8 Ah[4], Am[4], Al[4], Bh[2], Bm[2], Bl[2];
    #pragma unroll
    for(int m=0;m<4;m++){
      size_t o = abase + (size_t)(m*KT + kt)*512;
      Ah[m] = *(const short8*)(xh + o);
      Am[m] = *(const short8*)(xm + o);
      if constexpr (FULL) Al[m] = *(const short8*)(xl + o);
    }
    #pragma unroll
    for(int n=0;n<2;n++){
      size_t o = bbase + (size_t)(n*KT + kt)*512;
      Bh[n] = *(const short8*)(wh + o);
      Bm[n] = *(const short8*)(wm + o);
      if constexpr (FULL) Bl[n] = *(const short8*)(wl + o);
    }
    #pragma unroll
    for(int m=0;m<4;m++){
      #pragma unroll
      for(int n=0;n<2;n++){
        if constexpr (FULL) {
          MFMA6(acc[m][n], Ah[m], Am[m], Al[m], Bh[n], Bm[n], Bl[n])
        } else {
          MFMA3(acc[m][n], Ah[m], Am[m], Bh[n], Bm[n])
        }
      }
    }
  }
  #pragma unroll
  for(int m=0;m<4;m++){
    #pragma unroll
    for(int r=0;r<4;r++){
      int row = row0 + m*16 + 4*lg + r;
      float* dp = qp + (size_t)row*W2C + col0;
      #pragma unroll
      for(int n=0;n<2;n++) dp[n*16 + lr] = acc[m][n][r];
    }
  }
}

// Gather from interleaved qp[row][2*COUT] (q | p); base = p - q computed here.
template<int COUT>
__launch_bounds__(256) __global__ void gather_qp_k(const float* __restrict__ qp, const int* __restrict__ idx,
    const float* g, const float* bb, float* out){
  const int t  = blockIdx.x*256 + threadIdx.x;   // BN*COUT
  const int o  = t % COUT;
  const int bn = t / COUT;
  const int b  = bn >> 11;
  const int* id = idx + (size_t)bn*KK;
  float qv = qp[(size_t)bn*(2*COUT) + o];
  float pv = qp[(size_t)bn*(2*COUT) + COUT + o];
  float base = pv - qv;
  float mx = -INFINITY, mn = INFINITY;
  #pragma unroll
  for(int k=0;k<KK;k++){
    int ik = id[k];
    float v = qp[((size_t)((b<<11) + ik))*(2*COUT) + o];
    mx = fmaxf(mx, v); mn = fminf(mn, v);
  }
  float a  = g[o] * RSQ;
  float bo = bb[o];
  out[(size_t)bn*COUT + o] = lrelu((a >= 0.f ? a*(mx+base) : a*(mn+base)) + bo);
}

// ---- fallback chunked qp (cat weight layout) + chunked gather ----
template<int CIN, int COUT>
__launch_bounds__(256) __global__ void qp64T_k(const float* __restrict__ X, const float* __restrict__ WT,
                                               int cb, float* __restrict__ q, float* __restrict__ bs){
  const int t   = blockIdx.x*256 + threadIdx.x;
  const int row = t >> 3;
  const int o0  = cb + (t & 7) * 8;
  float xn[CIN];
  #pragma unroll
  for(int c=0;c<CIN;c+=4){ float4 v = *(const float4*)(X + (size_t)row*CIN + c);
    xn[c]=v.x; xn[c+1]=v.y; xn[c+2]=v.z; xn[c+3]=v.w; }
  float aq[8], ap[8];
  #pragma unroll
  for(int j=0;j<8;j++){ aq[j]=0.f; ap[j]=0.f; }
  #pragma unroll 4
  for(int c=0;c<CIN;c++){
    float xc = xn[c];
    float4 wa0 = *(const float4*)&WT[(size_t)c*(2*COUT) + o0];
    float4 wa1 = *(const float4*)&WT[(size_t)c*(2*COUT) + o0 + 4];
    float4 wb0 = *(const float4*)&WT[(size_t)c*(2*COUT) + COUT + o0];
    float4 wb1 = *(const float4*)&WT[(size_t)c*(2*COUT) + COUT + o0 + 4];
    aq[0]=fmaf(xc,wa0.x,aq[0]); aq[1]=fmaf(xc,wa0.y,aq[1]); aq[2]=fmaf(xc,wa0.z,aq[2]); aq[3]=fmaf(xc,wa0.w,aq[3]);
    aq[4]=fmaf(xc,wa1.x,aq[4]); aq[5]=fmaf(xc,wa1.y,aq[5]); aq[6]=fmaf(xc,wa1.z,aq[6]); aq[7]=fmaf(xc,wa1.w,aq[7]);
    ap[0]=fmaf(xc,wb0.x,ap[0]); ap[1]=fmaf(xc,wb0.y,ap[1]); ap[2]=fmaf(xc,wb0.z,ap[2]); ap[3]=fmaf(xc,wb0.w,ap[3]);
    ap[4]=fmaf(xc,wb1.x,ap[4]); ap[5]=fmaf(xc,wb1.y,ap[5]); ap[6]=fmaf(xc,wb1.z,ap[6]); ap[7]=fmaf(xc,wb1.w,ap[7]);
  }
  float* qpp = q  + (size_t)row*64 + (o0-cb);
  float* bpp = bs + (size_t)row*64 + (o0-cb);
  *(float4*)qpp     = make_float4(aq[0],aq[1],aq[2],aq[3]);
  *(float4*)(qpp+4) = make_float4(aq[4],aq[5],aq[6],aq[7]);
  *(float4*)bpp     = make_float4(ap[0]-aq[0],ap[1]-aq[1],ap[2]-aq[2],ap[3]-aq[3]);
  *(float4*)(bpp+4) = make_float4(ap[4]-aq[4],ap[5]-aq[5],ap[6]-aq[6],ap[7]-aq[7]);
}

template<int CFULL>
__launch_bounds__(256) __global__ void gather_chunk_k(const float* q, const float* bs, const int* idx,
    const float* g, const float* bb, int cb, float* out){
  const int t  = blockIdx.x*256 + threadIdx.x;
  const int o  = t & 63;
  const int bn = t >> 6;
  const int b  = bn >> 11;
  const int* id = idx + (size_t)bn*KK;
  float base = bs[t];
  float mx = -INFINITY, mn = INFINITY;
  #pragma unroll
  for(int k=0;k<KK;k++){
    int ik = id[k];
    float v = q[((size_t)((b<<11) + ik))*64 + o];
    mx = fmaxf(mx, v); mn = fminf(mn, v);
  }
  float a  = g[cb+o] * RSQ;
  float bo = bb[cb+o];
  out[(size_t)bn*CFULL + cb + o] = lrelu((a >= 0.f ? a*(mx+base) : a*(mn+base)) + bo);
}

// ---------------- head (fallback): fp32 GEMM-tiled cat x W5T with fused max/min ----------------
__launch_bounds__(256) __global__ void w5gemm_k(const float* __restrict__ x1, const float* __restrict__ x2,
    const float* __restrict__ x3, const float* __restrict__ x4,
    const float* __restrict__ W5T, unsigned* mxe, unsigned* mne){
  constexpr int ASTA = 92;
  constexpr int ASTB = 188;
  __shared__ __align__(16) float a_sh[16*ASTA];
  __shared__ __align__(16) float b_sh[16*ASTB];
  const int tid = threadIdx.x;
  const int otile = blockIdx.x*128;
  const int rtile = blockIdx.y*64;
  const int b     = blockIdx.z;
  const int tn = tid & 15, tm = tid >> 4;
  const int aoff = 4*tn + 4*(tn>>1);
  const size_t row0 = (size_t)b*NN + rtile;
  float acc[4][8];
  #pragma unroll
  for(int i=0;i<4;i++){
    #pragma unroll
    for(int j=0;j<8;j++) acc[i][j]=0.f;
  }
  for(int cc=0; cc<512; cc+=16){
    const float* src; int stride, coff;
    if(cc<64)      { src=x1; stride=64;  coff=cc; }
    else if(cc<128){ src=x2; stride=64;  coff=cc-64; }
    else if(cc<256){ src=x3; stride=128; coff=cc-128; }
    else           { src=x4; stride=256; coff=cc-256; }
    __syncthreads();
    { int r = tid>>2, q = tid&3;
      int pr = r + 4*(r>>3);
      float4 va = *(const float4*)&src[(row0 + r)*stride + coff + 4*q];
      a_sh[(4*q+0)*ASTA + pr]=va.x; a_sh[(4*q+1)*ASTA + pr]=va.y;
      a_sh[(4*q+2)*ASTA + pr]=va.z; a_sh[(4*q+3)*ASTA + pr]=va.w; }
    #pragma unroll
    for(int s=0;s<2;s++){
      int ii = tid + 256*s;
      int cl = ii>>5, o4 = ii&31;
      float4 vb = *(const float4*)&W5T[(size_t)(cc+cl)*512 + otile + 4*o4];
      *(float4*)&b_sh[cl*ASTB + 4*o4 + 4*(o4>>1)] = vb;
    }
    __syncthreads();
    #pragma unroll
    for(int c=0;c<16;c++){
      float4 A0 = *(const float4*)&a_sh[c*ASTA + aoff];
      float4 B0 = *(const float4*)&b_sh[c*ASTB + 12*tm];
      float4 B1 = *(const float4*)&b_sh[c*ASTB + 12*tm + 4];
      float b0v=B0.x,b1v=B0.y,b2v=B0.z,b3v=B0.w,b4v=B1.x,b5v=B1.y,b6v=B1.z,b7v=B1.w;
      float a;
      a=A0.x; FMA_ROW(0)
      a=A0.y; FMA_ROW(1)
      a=A0.z; FMA_ROW(2)
      a=A0.w; FMA_ROW(3)
    }
  }
  #pragma unroll
  for(int j=0;j<8;j++){
    float M=-INFINITY, m=INFINITY;
    #pragma unroll
    for(int i=0;i<4;i++){ M=fmaxf(M,acc[i][j]); m=fminf(m,acc[i][j]); }
    #pragma unroll
    for(int d=1; d<16; d<<=1){
      M = fmaxf(M, __shfl_xor(M, d));
      m = fminf(m, __shfl_xor(m, d));
    }
    if(tn == 0){
      int o = otile + tm*8 + j;
      atomicMax(&mxe[b*512+o], encf(M));
      atomicMin(&mne[b*512+o], encf(m));
    }
  }
}

// ---------------- head (big): split-bf16 MFMA (3-product, terminal) ----------------
// xcat 2-split (h/m only) into fragment-major tiled layout (KT=16, row space = BN).
__launch_bounds__(256) __global__ void cvt_k(const float* __restrict__ x1, const float* __restrict__ x2,
    const float* __restrict__ x3, const float* __restrict__ x4,
    u16* __restrict__ xh, u16* __restrict__ xm){
  const size_t t = (size_t)blockIdx.x*256 + threadIdx.x;   // BN*512/8 chunks
  const int l = (int)(t & 63);
  const size_t tile = t >> 6;           // rgG*16 + kt
  const int kt = (int)(tile & 15);
  const size_t rgG = tile >> 4;
  const size_t row = rgG*16 + (l & 15);
  const int col = kt*32 + ((l>>4)<<3);
  const float* src; int stride, coff;
  if(col<64)      { src=x1; stride=64;  coff=col; }
  else if(col<128){ src=x2; stride=64;  coff=col-64; }
  else if(col<256){ src=x3; stride=128; coff=col-128; }
  else            { src=x4; stride=256; coff=col-256; }
  const float* p = src + row*stride + coff;
  float4 v0 = *(const float4*)p;
  float4 v1 = *(const float4*)(p+4);
  float vs[8] = {v0.x,v0.y,v0.z,v0.w,v1.x,v1.y,v1.z,v1.w};
  ushort8 H, M;
  #pragma unroll
  for(int j=0;j<8;j++){ u16 h,m,lo; bf16split3(vs[j],h,m,lo); H[j]=h; M[j]=m; (void)lo; }
  *(ushort8*)(xh + t*8) = H;
  *(ushort8*)(xm + t*8) = M;
}

// C[16384x512] = xcat * W5^T via 3 bf16 MFMA products (hh+hm+mh, terminal-GEMM precision),
// fused per-column max/min. 64-col tiles: grid (128 rowblk, 8 colblk); A-sharing blocks
// 128 apart -> same XCD L2.
__launch_bounds__(256) __global__ void w5mfma_k(const u16* __restrict__ xh, const u16* __restrict__ xm,
    const u16* __restrict__ wh, const u16* __restrict__ wm,
    unsigned* mxe, unsigned* mne){
  const int tid = threadIdx.x;
  const int l  = tid & 63, wv = tid >> 6;
  const int lg = l >> 4, lr = l & 15;
  const int row0 = blockIdx.x*128 + (wv>>1)*64;   // M base of this wave (global BN rows)
  const int col0 = blockIdx.y*64 + (wv&1)*32;     // N base of this wave
  const int b = blockIdx.x >> 4;                  // 16 M-blocks per batch
  f32x4 acc[4][2];
  #pragma unroll
  for(int m=0;m<4;m++){
    #pragma unroll
    for(int n=0;n<2;n++) acc[m][n] = (f32x4){0.f,0.f,0.f,0.f};
  }
  const size_t abase = (size_t)(row0>>4)*16*512 + (size_t)l*8;
  const size_t bbase = (size_t)(col0>>4)*16*512 + (size_t)l*8;
  for(int kt=0; kt<16; kt++){
    short8 Ah[4], Am[4], Bh[2], Bm[2];
    #pragma unroll
    for(int m=0;m<4;m++){
      size_t o = abase + (size_t)(m*16 + kt)*512;
      Ah[m] = *(const short8*)(xh + o);
      Am[m] = *(const short8*)(xm + o);
    }
    #pragma unroll
    for(int n=0;n<2;n++){
      size_t o = bbase + (size_t)(n*16 + kt)*512;
      Bh[n] = *(const short8*)(wh + o);
      Bm[n] = *(const short8*)(wm + o);
    }
    #pragma unroll
    for(int m=0;m<4;m++){
      #pragma unroll
      for(int n=0;n<2;n++){
        MFMA3(acc[m][n], Ah[m], Am[m], Bh[n], Bm[n])
      }
    }
  }
  #pragma unroll
  for(int n=0;n<2;n++){
    float M = -INFINITY, mnv = INFINITY;
    #pragma unroll
    for(int m=0;m<4;m++){
      #pragma unroll
      for(int r=0;r<4;r++){ float v = acc[m][n][r]; M = fmaxf(M, v); mnv = fminf(mnv, v); }
    }
    M   = fmaxf(M,   __shfl_xor(M, 16));   M   = fmaxf(M,   __shfl_xor(M, 32));
    mnv = fminf(mnv, __shfl_xor(mnv, 16)); mnv = fminf(mnv, __shfl_xor(mnv, 32));
    if(lg == 0){
      int o = col0 + n*16 + lr;
      atomicMax(&mxe[b*512+o], encf(M));
      atomicMin(&mne[b*512+o], encf(mnv));
    }
  }
}

__launch_bounds__(256) __global__ void final_k(const unsigned* mxe, const unsigned* mne,
    const float* g5, const float* b5, const float* Wemb, float* out){
  const int b = blockIdx.x, t = threadIdx.x;
  __shared__ float h[512];
  for(int o=t; o<512; o+=256){
    float mx = decf(mxe[b*512+o]);
    float mn = decf(mne[b*512+o]);
    float a  = g5[o] * RSQ;
    float bo = b5[o];
    float hv = lrelu((a >= 0.f ? a*mx : a*mn) + bo);
    h[o] = hv;
    out[b*512+o] = hv;
  }
  __syncthreads();
  const float* wr = Wemb + (size_t)t*512;
  float s = 0.f;
  for(int o=0;o<512;o+=4){
    float4 w4 = *(const float4*)(wr+o);
    s = fmaf(h[o],w4.x, fmaf(h[o+1],w4.y, fmaf(h[o+2],w4.z, fmaf(h[o+3],w4.w, s))));
  }
  out[4096 + b*256 + t] = s;
}

// ---------------- launch ----------------
extern "C" void kernel_launch(void* const* d_in, const int* in_sizes, int n_in,
                              void* d_out, int out_size, void* d_ws, size_t ws_size,
                              hipStream_t stream) {
  if (ws_size < WS_END * sizeof(float)) return;
  const bool big = ws_size >= WS_BIG_END * sizeof(float);   // deterministic per call

  const float* x0   = (const float*)d_in[0];
  const float* W1   = (const float*)d_in[1];
  const float* g1   = (const float*)d_in[2];
  const float* b1   = (const float*)d_in[3];
  const float* W2   = (const float*)d_in[4];
  const float* g2   = (const float*)d_in[5];
  const float* b2   = (const float*)d_in[6];
  const float* W3   = (const float*)d_in[7];
  const float* g3   = (const float*)d_in[8];
  const float* b3   = (const float*)d_in[9];
  const float* W4   = (const float*)d_in[10];
  const float* g4   = (const float*)d_in[11];
  const float* b4   = (const float*)d_in[12];
  const float* W5   = (const float*)d_in[13];
  const float* g5   = (const float*)d_in[14];
  const float* b5   = (const float*)d_in[15];
  const float* Wemb = (const float*)d_in[16];

  float* ws = (float*)d_ws;
  float* xx = ws + OFF_XX;
  float* x1 = ws + OFF_X1;  float* x2 = ws + OFF_X2;
  float* x3 = ws + OFF_X3;  float* x4 = ws + OFF_X4;
  float* qpS = ws + OFF_SC;               // L1 qp (width 128) + fallback chunked q/bs
  float* bsS = ws + OFF_SC + (size_t)BN*64;
  int*   id = (int*)(ws + OFF_ID);
  float* W5Tf = ws + OFF_W5T;
  unsigned* mxe = (unsigned*)(ws + OFF_MX);
  unsigned* mne = (unsigned*)(ws + OFF_MN);
  float* WT2 = ws + OFF_WT2;
  float* WT3 = ws + OFF_WT3;
  float* WT4 = ws + OFF_WT4;
  float* distD = ws + OFF_X3;   // fallback dual-batch
  float* distS = ws + OFF_X4;   // fallback single-batch
  float* distB = ws + OFF_BIG;  // big: 4-batch dist chunk, then reused as qp buffer / bf16 xcat
  u16* w5h = (u16*)(ws + OFF_SC + (size_t)BN*128);   // SC tail (free in both paths): 3x256KB
  u16* w5m = w5h + 512*512;
  u16* w5l = w5m + 512*512;
  u16* wts = (u16*)W5Tf;         // big path: tiled WT splits live in the (unused) W5T region
  float* out = (float*)d_out;

  prep_k<<<1024,256,0,stream>>>(W5, W2, W3, W4, W5Tf, WT2, WT3, WT4,
                                w5h, w5m, w5l, wts, mxe, mne, big ? 1 : 0);

  // layer 1 (3 -> 64)
  sel3_k<<<BN*64/256,256,0,stream>>>(x0, id);
  qp3_k<<<BN*8/256,256,0,stream>>>(x0, W1, qpS);
  gather_qp_k<64><<<BN*64/256,256,0,stream>>>(qpS, id, g1, b1, x1);

  if(big){
    float* qpB = distB;                      // reuse dist region post-sel
    // split scratch lives in x4 region (dead until layer-4 gather)
    u16* sh = (u16*)x4;
    // layer 2 (CIN=64 -> COUT=64, qp width 128)
    { u16* sm = sh + (size_t)BN*64; u16* sl = sm + (size_t)BN*64;
      sqnorm_k<64><<<BN/256,256,0,stream>>>(x1, xx);
      split_k<64><<<BN*64/8/256,256,0,stream>>>(x1, sh, sm, sl);
      for(int c0=0;c0<BB;c0+=4){
        mfma_dist_k<64><<<dim3(32,16,4),256,0,stream>>>(sh, sm, sl, xx, distB, c0);
        sel_k<<<(4*NN)/4,256,0,stream>>>(distB, id, c0, 4*NN);
      }
      qp_mfma_k<2,128,true><<<dim3(BN/128,2),256,0,stream>>>(sh, sm, sl,
          wts+WTS_2H, wts+WTS_2M, wts+WTS_2L, qpB);
      gather_qp_k<64><<<BN*64/256,256,0,stream>>>(qpB, id, g2, b2, x2); }
    // layer 3 (64 -> 128, qp width 256)
    { u16* sm = sh + (size_t)BN*64; u16* sl = sm + (size_t)BN*64;
      sqnorm_k<64><<<BN/256,256,0,stream>>>(x2, xx);
      split_k<64><<<BN*64/8/256,256,0,stream>>>(x2, sh, sm, sl);
      for(int c0=0;c0<BB;c0+=4){
        mfma_dist_k<64><<<dim3(32,16,4),256,0,stream>>>(sh, sm, sl, xx, distB, c0);
        sel_k<<<(4*NN)/4,256,0,stream>>>(distB, id, c0, 4*NN);
      }
      qp_mfma_k<2,256,true><<<dim3(BN/128,4),256,0,stream>>>(sh, sm, sl,
          wts+WTS_3H, wts+WTS_3M, wts+WTS_3L, qpB);
      gather_qp_k<128><<<BN*128/256,256,0,stream>>>(qpB, id, g3, b3, x3); }
    // layer 4 (128 -> 256, qp width 512): terminal for KNN -> 3-product qp
    { u16* sm = sh + (size_t)BN*128; u16* sl = sm + (size_t)BN*128;
      sqnorm_k<128><<<BN/256,256,0,stream>>>(x3, xx);
      split_k<128><<<BN*128/8/256,256,0,stream>>>(x3, sh, sm, sl);
      for(int c0=0;c0<BB;c0+=4){
        mfma_dist_k<128><<<dim3(32,16,4),256,0,stream>>>(sh, sm, sl, xx, distB, c0);
        sel_k<<<(4*NN)/4,256,0,stream>>>(distB, id, c0, 4*NN);
      }
      qp_mfma_k<4,512,false><<<dim3(BN/128,8),256,0,stream>>>(sh, sm, sl,
          wts+WTS_4H, wts+WTS_4M, wts+WTS_4L, qpB);
      gather_qp_k<256><<<BN*256/256,256,0,stream>>>(qpB, id, g4, b4, x4); }
    // head: bf16 2-split (tiled) + 3-product MFMA (terminal-GEMM precision)
    u16* xh = (u16*)(ws + OFF_XCAT);
    u16* xm = xh + (size_t)BN*512;
    cvt_k<<<BN*512/8/256,256,0,stream>>>(x1, x2, x3, x4, xh, xm);
    w5mfma_k<<<dim3(128,8),256,0,stream>>>(xh, xm, w5h, w5m, mxe, mne);
  } else {
    // fallback: chunked (R12 structure, cat weight layout)
    sqnorm_k<64><<<BN/256,256,0,stream>>>(x1, xx);
    for(int r=0;r<4;r++){
      gemm_dist_k<64><<<dim3(16,16,2),256,0,stream>>>(x1, xx, distD, 2*r);
      sel_k<<<(2*NN)/4,256,0,stream>>>(distD, id, 2*r, 2*NN);
    }
    qp64T_k<64,64><<<BN*8/256,256,0,stream>>>(x1, WT2, 0, qpS, bsS);
    gather_chunk_k<64><<<BN*64/256,256,0,stream>>>(qpS, bsS, id, g2, b2, 0, x2);

    sqnorm_k<64><<<BN/256,256,0,stream>>>(x2, xx);
    for(int r=0;r<4;r++){
      gemm_dist_k<64><<<dim3(16,16,2),256,0,stream>>>(x2, xx, distD, 2*r);
      sel_k<<<(2*NN)/4,256,0,stream>>>(distD, id, 2*r, 2*NN);
    }
    for(int cb=0; cb<128; cb+=64){
      qp64T_k<64,128><<<BN*8/256,256,0,stream>>>(x2, WT3, cb, qpS, bsS);
      gather_chunk_k<128><<<BN*64/256,256,0,stream>>>(qpS, bsS, id, g3, b3, cb, x3);
    }

    sqnorm_k<128><<<BN/256,256,0,stream>>>(x3, xx);
    for(int r=0;r<8;r++){
      gemm_dist_k<128><<<dim3(16,16,1),256,0,stream>>>(x3, xx, distS, r);
      sel_k<<<NN/4,256,0,stream>>>(distS, id, r, NN);
    }
    for(int cb=0; cb<256; cb+=64){
      qp64T_k<128,256><<<BN*8/256,256,0,stream>>>(x3, WT4, cb, qpS, bsS);
      gather_chunk_k<256><<<BN*64/256,256,0,stream>>>(qpS, bsS, id, g4, b4, cb, x4);
    }
    w5gemm_k<<<dim3(4,32,8),256,0,stream>>>(x1, x2, x3, x4, W5Tf, mxe, mne);
  }

  final_k<<<BB,256,0,stream>>>(mxe, mne, g5, b5, Wemb, out);
}

// Round 16
// 545.197 us; speedup vs baseline: 1.1632x; 1.0671x over previous
//
#include <hip/hip_runtime.h>
#include <hip/hip_bf16.h>

#define BB 8
#define NN 2048
#define KK 20
#define BN (BB*NN)
#define RSQ 0.99999500003749969f   // 1/sqrt(1+1e-5)

// ---------------- workspace layout (float-slot units) ----------------
constexpr size_t OFF_XX  = 0;                          // BN
constexpr size_t OFF_X1  = OFF_XX  + BN;               // BN*64
constexpr size_t OFF_X2  = OFF_X1  + (size_t)BN*64;    // BN*64
constexpr size_t OFF_X3  = OFF_X2  + (size_t)BN*64;    // BN*128
constexpr size_t OFF_X4  = OFF_X3  + (size_t)BN*128;   // BN*256 (split-scratch pre-gather)
constexpr size_t OFF_SC  = OFF_X4  + (size_t)BN*256;   // BN*160 (L1 qp + fallback chunked qp + W5 bf16 tail)
constexpr size_t OFF_ID  = OFF_SC  + (size_t)BN*160;   // int BN*20
constexpr size_t OFF_W5T = OFF_ID  + (size_t)BN*20;    // 512*512 (big path: tiled WT splits live here)
constexpr size_t OFF_MX  = OFF_W5T + 512*512;
constexpr size_t OFF_MN  = OFF_MX  + BB*512;
constexpr size_t OFF_WT2 = OFF_MN  + BB*512;           // cat [64][128]
constexpr size_t OFF_WT3 = OFF_WT2 + 8192;             // cat [64][256]
constexpr size_t OFF_WT4 = OFF_WT3 + 16384;            // cat [128][512]
constexpr size_t WS_END  = OFF_WT4 + 65536;            // 11,714,560 floats
// big region (probed at runtime): dist chunk (4 batches) + qp buffer + bf16 xcat post-sel
constexpr size_t OFF_BIG = WS_END;
constexpr size_t OFF_XCAT = OFF_BIG + (size_t)16*1024*1024;  // bf16 xcat h/m (dist region tail, post-KNN)
constexpr size_t WS_BIG_END = OFF_BIG + (size_t)BB*NN*NN;   // 172.7 MiB
static_assert(OFF_ID - OFF_X3 >= (size_t)4096*2048, "fallback dual dist fits");
static_assert(OFF_XCAT + (size_t)BN*512 <= WS_BIG_END, "xcat h/m fits in dist region");

typedef unsigned short u16;
typedef __attribute__((ext_vector_type(8))) short short8;
typedef __attribute__((ext_vector_type(8))) unsigned short ushort8;
typedef __attribute__((ext_vector_type(4))) float f32x4;

// tiled WT split offsets (u16 units) within the W5T region (big path only)
constexpr size_t WTS_2H = 0,      WTS_2M = 8192,   WTS_2L = 16384;
constexpr size_t WTS_3H = 24576,  WTS_3M = 40960,  WTS_3L = 57344;
constexpr size_t WTS_4H = 73728,  WTS_4M = 139264, WTS_4L = 204800;   // end 270336 u16 <= 524288

__device__ inline unsigned encf(float f){ unsigned u=__float_as_uint(f); return (u&0x80000000u)? ~u : (u|0x80000000u); }
__device__ inline float decf(unsigned e){ unsigned u=(e&0x80000000u)? (e&0x7fffffffu) : ~e; return __uint_as_float(u); }
__device__ inline float lrelu(float h){ return h>=0.f ? h : 0.2f*h; }
__device__ inline u16 bf16rne(float x){
  unsigned u = __float_as_uint(x);
  return (u16)((u + 0x7FFFu + ((u>>16)&1u)) >> 16);
}
__device__ inline float bf16f(u16 h){ return __uint_as_float((unsigned)h<<16); }
// exact 3-way split: x == h + m + l for normal fp32 (24 mantissa bits covered)
__device__ inline void bf16split3(float v, u16& h, u16& m, u16& l){
  h = bf16rne(v);  float r1 = v  - bf16f(h);
  m = bf16rne(r1); float r2 = r1 - bf16f(m);
  l = bf16rne(r2);
}

__device__ inline float readlane_f(float v, int sl){
  return __int_as_float(__builtin_amdgcn_readlane(__float_as_int(v), sl));
}

// Wave-cooperative sorted-top-20 insertion (cv known > theta on call).
#define INSERT_CAND(cv, ci) { \
  unsigned long long mge = __ballot((lv > cv) || (lv == cv && li < ci)); \
  int pos = __popcll(mge); \
  float upv = __shfl_up(lv, 1); \
  int   upi = __shfl_up(li, 1); \
  bool shift = (lane > pos) && (lane < KK); \
  lv = (lane == pos) ? cv : (shift ? upv : lv); \
  li = (lane == pos) ? ci : (shift ? upi : li); \
  theta = readlane_f(lv, KK-1); }

// Bitonic full sort of 64 (value desc, index asc on ties) across lanes; (v,vi) in registers.
#define BITONIC64_DESC(v, vi) { \
  _Pragma("unroll") \
  for(int k=2; k<=64; k<<=1){ \
    _Pragma("unroll") \
    for(int j=k>>1; j>=1; j>>=1){ \
      float ov = __shfl_xor(v, j); \
      int   oi = __shfl_xor(vi, j); \
      int partner = lane ^ j; \
      bool keepFirst = (((lane & k) == 0)) == (lane < partner); \
      bool before = (v > ov) || (v == ov && vi < oi); \
      if(keepFirst != before){ v = ov; vi = oi; } \
    } \
  } }

// 6-product split-bf16 MFMA macro (fp32-exact to ~2^-27): KNN-critical GEMMs.
#define MFMA6(ACC, AH, AM, AL, BH, BM, BL) { \
  ACC = __builtin_amdgcn_mfma_f32_16x16x32_bf16(AH, BH, ACC, 0, 0, 0); \
  ACC = __builtin_amdgcn_mfma_f32_16x16x32_bf16(AH, BM, ACC, 0, 0, 0); \
  ACC = __builtin_amdgcn_mfma_f32_16x16x32_bf16(AM, BH, ACC, 0, 0, 0); \
  ACC = __builtin_amdgcn_mfma_f32_16x16x32_bf16(AH, BL, ACC, 0, 0, 0); \
  ACC = __builtin_amdgcn_mfma_f32_16x16x32_bf16(AL, BH, ACC, 0, 0, 0); \
  ACC = __builtin_amdgcn_mfma_f32_16x16x32_bf16(AM, BM, ACC, 0, 0, 0); }

// 3-product variant (error ~3*2^-18 relative): terminal GEMMs only (head, layer-4 qp).
#define MFMA3(ACC, AH, AM, BH, BM) { \
  ACC = __builtin_amdgcn_mfma_f32_16x16x32_bf16(AH, BH, ACC, 0, 0, 0); \
  ACC = __builtin_amdgcn_mfma_f32_16x16x32_bf16(AH, BM, ACC, 0, 0, 0); \
  ACC = __builtin_amdgcn_mfma_f32_16x16x32_bf16(AM, BH, ACC, 0, 0, 0); }

// ======== fragment-major tiled split layout ========
// split[rowGroup][kTile][lane=64][8]  (u16). lane l -> row = rg*16 + (l&15), k = kt*32 + (l>>4)*8.

// ---------------- prep: weights transposes + splits + enc ----------------
__global__ void prep_k(const float* W5, const float* W2, const float* W3, const float* W4,
                       float* W5T, float* WT2, float* WT3, float* WT4,
                       u16* w5h, u16* w5m, u16* w5l, u16* wts,
                       unsigned* mx, unsigned* mn, int big){
  int i = blockIdx.x*256 + threadIdx.x;     // 262144
  if(!big){ int o = i>>9, c = i&511; W5T[c*512+o] = W5[i]; }   // fp32 W5T only for fallback
  { // tiled split of W5 (B-side rows = output cols o, k = input c). KT=16.
    int rg = i>>13, kt = (i>>9)&15, l = (i>>3)&63, j = i&7;
    int o = rg*16 + (l&15);
    int c = kt*32 + ((l>>4)<<3) + j;
    u16 h,m,lo; bf16split3(W5[(size_t)o*512 + c], h, m, lo);
    w5h[i]=h; w5m[i]=m; w5l[i]=lo; }
  if(i < 65536){ int c = i>>9, o = i&511;   // W4: [256][256] -> cat [128][512]
    WT4[i] = (o<256) ? W4[(size_t)o*256 + c] : W4[(size_t)(o-256)*256 + 128 + c]; }
  if(i < 16384){ int c = i>>8, o = i&255;   // W3: [128][128] -> cat [64][256]
    WT3[i] = (o<128) ? W3[(size_t)o*128 + c] : W3[(size_t)(o-128)*128 + 64 + c]; }
  if(i <  8192){ int c = i>>7, o = i&127;   // W2: [64][128] -> cat [64][128]
    WT2[i] = (o<64) ? W2[(size_t)o*128 + c] : W2[(size_t)(o-64)*128 + 64 + c]; }
  if(big){
    if(i < 65536){ // WT4 tiled split: rg over o (32), kt over c (4)
      int rg=i>>11, kt=(i>>9)&3, l=(i>>3)&63, j=i&7;
      int o = rg*16 + (l&15);
      int c = kt*32 + ((l>>4)<<3) + j;
      float v = (o<256) ? W4[(size_t)o*256 + c] : W4[(size_t)(o-256)*256 + 128 + c];
      u16 h,m,lo; bf16split3(v,h,m,lo);
      wts[WTS_4H+i]=h; wts[WTS_4M+i]=m; wts[WTS_4L+i]=lo; }
    if(i < 16384){ // WT3 tiled split: rg over o (16), kt over c (2)
      int rg=i>>10, kt=(i>>9)&1, l=(i>>3)&63, j=i&7;
      int o = rg*16 + (l&15);
      int c = kt*32 + ((l>>4)<<3) + j;
      float v = (o<128) ? W3[(size_t)o*128 + c] : W3[(size_t)(o-128)*128 + 64 + c];
      u16 h,m,lo; bf16split3(v,h,m,lo);
      wts[WTS_3H+i]=h; wts[WTS_3M+i]=m; wts[WTS_3L+i]=lo; }
    if(i < 8192){  // WT2 tiled split: rg over o (8), kt over c (2)
      int rg=i>>10, kt=(i>>9)&1, l=(i>>3)&63, j=i&7;
      int o = rg*16 + (l&15);
      int c = kt*32 + ((l>>4)<<3) + j;
      float v = (o<64) ? W2[(size_t)o*128 + c] : W2[(size_t)(o-64)*128 + 64 + c];
      u16 h,m,lo; bf16split3(v,h,m,lo);
      wts[WTS_2H+i]=h; wts[WTS_2M+i]=m; wts[WTS_2L+i]=lo; }
  }
  if(i <  4096){ mx[i] = 0x007FFFFFu; mn[i] = 0xFF800000u; }
}

// ---------------- KNN ----------------
template<int C>
__launch_bounds__(256) __global__ void sqnorm_k(const float* X, float* xx){
  int i = blockIdx.x*256 + threadIdx.x;   // BN
  const float* r = X + (size_t)i*C;
  float s = 0.f;
  #pragma unroll
  for(int c=0;c<C;c++) s = fmaf(r[c], r[c], s);
  xx[i] = s;
}

// 3-way bf16 split of X [BN][C] into fragment-major tiled layout.
template<int C>
__launch_bounds__(256) __global__ void split_k(const float* __restrict__ X,
    u16* __restrict__ xh, u16* __restrict__ xm, u16* __restrict__ xl){
  constexpr int KT = C/32;
  const size_t t = (size_t)blockIdx.x*256 + threadIdx.x;   // BN*C/8 chunks
  const int l = (int)(t & 63);
  const size_t tile = t >> 6;               // rgG*KT + kt
  const int kt = (int)(tile & (KT-1));
  const size_t rgG = tile / KT;             // global row group (BN/16 total)
  const size_t row = rgG*16 + (l & 15);
  const int k = kt*32 + ((l>>4)<<3);
  const float* p = X + row*C + k;
  float4 v0 = *(const float4*)p;
  float4 v1 = *(const float4*)(p+4);
  float vs[8] = {v0.x,v0.y,v0.z,v0.w,v1.x,v1.y,v1.z,v1.w};
  ushort8 H,M,L;
  #pragma unroll
  for(int j=0;j<8;j++){ u16 h,m,lo; bf16split3(vs[j],h,m,lo); H[j]=h; M[j]=m; L[j]=lo; }
  *(ushort8*)(xh + t*8) = H;
  *(ushort8*)(xm + t*8) = M;
  *(ushort8*)(xl + t*8) = L;
}

#define FMA_ROW(I) \
  acc[I][0]=fmaf(a,b0v,acc[I][0]); acc[I][1]=fmaf(a,b1v,acc[I][1]); \
  acc[I][2]=fmaf(a,b2v,acc[I][2]); acc[I][3]=fmaf(a,b3v,acc[I][3]); \
  acc[I][4]=fmaf(a,b4v,acc[I][4]); acc[I][5]=fmaf(a,b5v,acc[I][5]); \
  acc[I][6]=fmaf(a,b6v,acc[I][6]); acc[I][7]=fmaf(a,b7v,acc[I][7]);

// fallback fp32 dist GEMM
template<int C>
__launch_bounds__(256) __global__ void gemm_dist_k(const float* __restrict__ X, const float* __restrict__ xx,
                                                   float* __restrict__ dist, int b0){
  constexpr int AST = 188;
  __shared__ __align__(16) float a_sh[16*AST];
  __shared__ __align__(16) float b_sh[16*AST];
  __shared__ float sxn[128], sxm[128];
  const int tid = threadIdx.x;
  const int b   = b0 + blockIdx.z;
  const int mtile = blockIdx.x*128;
  const int ntile = blockIdx.y*128;
  const int tn = tid & 15, tm = tid >> 4;
  const float* Xb  = X  + (size_t)b*NN*C;
  const float* xxb = xx + (size_t)b*NN;
  if(tid < 128) sxn[tid] = xxb[ntile + tid];
  else          sxm[tid-128] = xxb[mtile + tid-128];
  float acc[8][8];
  #pragma unroll
  for(int i=0;i<8;i++){
    #pragma unroll
    for(int j=0;j<8;j++) acc[i][j]=0.f;
  }
  for(int cc=0; cc<C; cc+=16){
    __syncthreads();
    #pragma unroll
    for(int s=0;s<2;s++){
      int ii = tid + 256*s; int r = ii>>2, q = ii&3;
      int pr = r + 4*(r>>3);
      float4 va = *(const float4*)&Xb[(size_t)(ntile + r)*C + cc + 4*q];
      a_sh[(4*q+0)*AST + pr]=va.x; a_sh[(4*q+1)*AST + pr]=va.y;
      a_sh[(4*q+2)*AST + pr]=va.z; a_sh[(4*q+3)*AST + pr]=va.w;
      float4 vb = *(const float4*)&Xb[(size_t)(mtile + r)*C + cc + 4*q];
      b_sh[(4*q+0)*AST + pr]=vb.x; b_sh[(4*q+1)*AST + pr]=vb.y;
      b_sh[(4*q+2)*AST + pr]=vb.z; b_sh[(4*q+3)*AST + pr]=vb.w;
    }
    __syncthreads();
    #pragma unroll
    for(int c=0;c<16;c++){
      float4 A0 = *(const float4*)&a_sh[c*AST + 12*tn];
      float4 A1 = *(const float4*)&a_sh[c*AST + 12*tn + 4];
      float4 B0 = *(const float4*)&b_sh[c*AST + 12*tm];
      float4 B1 = *(const float4*)&b_sh[c*AST + 12*tm + 4];
      float b0v=B0.x,b1v=B0.y,b2v=B0.z,b3v=B0.w,b4v=B1.x,b5v=B1.y,b6v=B1.z,b7v=B1.w;
      float a;
      a=A0.x; FMA_ROW(0)
      a=A0.y; FMA_ROW(1)
      a=A0.z; FMA_ROW(2)
      a=A0.w; FMA_ROW(3)
      a=A1.x; FMA_ROW(4)
      a=A1.y; FMA_ROW(5)
      a=A1.z; FMA_ROW(6)
      a=A1.w; FMA_ROW(7)
    }
  }
  float xnr[8], xmr[8];
  #pragma unroll
  for(int i=0;i<8;i++){ xnr[i]=sxn[tn*8+i]; xmr[i]=sxm[tm*8+i]; }
  const size_t rowb = (size_t)blockIdx.z*NN + ntile + tn*8;
  #pragma unroll
  for(int i=0;i<8;i++){
    float4 w0, w1;
    w0.x=(2.f*acc[i][0]-xnr[i])-xmr[0]; w0.y=(2.f*acc[i][1]-xnr[i])-xmr[1];
    w0.z=(2.f*acc[i][2]-xnr[i])-xmr[2]; w0.w=(2.f*acc[i][3]-xnr[i])-xmr[3];
    w1.x=(2.f*acc[i][4]-xnr[i])-xmr[4]; w1.y=(2.f*acc[i][5]-xnr[i])-xmr[5];
    w1.z=(2.f*acc[i][6]-xnr[i])-xmr[6]; w1.w=(2.f*acc[i][7]-xnr[i])-xmr[7];
    float* dp = dist + (rowb + i)*NN + mtile + tm*8;
    *(float4*)dp = w0;
    *(float4*)(dp+4) = w1;
  }
}

// big path: exact-fp32-quality dist via split-bf16 MFMA (6 products of 3-way split).
// 64-col tiles for occupancy: grid (NN/64, 16, 4chunk); block 128q x 64c; wave 64q x 32c.
template<int C>
__launch_bounds__(256) __global__ void mfma_dist_k(const u16* __restrict__ xh, const u16* __restrict__ xm,
    const u16* __restrict__ xl, const float* __restrict__ xx, float* __restrict__ dist, int b0){
  constexpr int KT = C/32;
  const int tid = threadIdx.x;
  const int l  = tid & 63, wv = tid >> 6;
  const int lg = l >> 4, lr = l & 15;
  const int cz = blockIdx.z;
  const int b  = b0 + cz;
  const int qrow0 = blockIdx.y*128 + (wv>>1)*64;   // query rows (A side, dist row)
  const int crow0 = blockIdx.x*64 + (wv&1)*32;     // candidate rows (B side, dist col)
  const size_t brg = (size_t)b*(NN/16);
  f32x4 acc[4][2];
  #pragma unroll
  for(int m=0;m<4;m++){
    #pragma unroll
    for(int n=0;n<2;n++) acc[m][n] = (f32x4){0.f,0.f,0.f,0.f};
  }
  const size_t abase = (brg + (qrow0>>4))*KT*512 + (size_t)l*8;
  const size_t bbase = (brg + (crow0>>4))*KT*512 + (size_t)l*8;
  for(int kt=0; kt<KT; kt++){
    short8 Ah[4], Am[4], Al[4], Bh[2], Bm[2], Bl[2];
    #pragma unroll
    for(int m=0;m<4;m++){
      size_t o = abase + (size_t)(m*KT + kt)*512;
      Ah[m] = *(const short8*)(xh + o);
      Am[m] = *(const short8*)(xm + o);
      Al[m] = *(const short8*)(xl + o);
    }
    #pragma unroll
    for(int n=0;n<2;n++){
      size_t o = bbase + (size_t)(n*KT + kt)*512;
      Bh[n] = *(const short8*)(xh + o);
      Bm[n] = *(const short8*)(xm + o);
      Bl[n] = *(const short8*)(xl + o);
    }
    #pragma unroll
    for(int m=0;m<4;m++){
      #pragma unroll
      for(int n=0;n<2;n++){
        MFMA6(acc[m][n], Ah[m], Am[m], Al[m], Bh[n], Bm[n], Bl[n])
      }
    }
  }
  const float* xxb = xx + (size_t)b*NN;
  float xxc[2];
  #pragma unroll
  for(int n=0;n<2;n++) xxc[n] = xxb[crow0 + n*16 + lr];
  #pragma unroll
  for(int m=0;m<4;m++){
    #pragma unroll
    for(int r=0;r<4;r++){
      int qr = qrow0 + m*16 + 4*lg + r;
      float xq = xxb[qr];
      float* dp = dist + ((size_t)cz*NN + qr)*NN + crow0;
      #pragma unroll
      for(int n=0;n<2;n++) dp[n*16 + lr] = (2.f*acc[m][n][r] - xq) - xxc[n];
    }
  }
}

// Wave-cooperative top-20: max-of-8 bitonic warm start (512 cands) + slim insertions.
__launch_bounds__(256) __global__ void sel_k(const float* __restrict__ dist, int* __restrict__ id,
                                             int b0, int nrows){
  const int w = (blockIdx.x*256 + threadIdx.x) >> 6;
  const int lane = threadIdx.x & 63;
  if(w >= nrows) return;
  const float* dr = dist + (size_t)w*NN;
  float4 c0 = *(const float4*)&dr[4*lane];
  float4 c1 = *(const float4*)&dr[256 + 4*lane];
  float cd0[8] = {c0.x, c0.y, c0.z, c0.w, c1.x, c1.y, c1.z, c1.w};
  int jbest = 0; float v = cd0[0];
  #pragma unroll
  for(int j=1;j<8;j++){ if(cd0[j] > v){ v = cd0[j]; jbest = j; } }
  int vi = (jbest < 4) ? (4*lane + jbest) : (256 + 4*lane + (jbest-4));
  BITONIC64_DESC(v, vi)
  float lv = (lane < KK) ? v : -INFINITY;
  int   li = (lane < KK) ? vi : 0;
  float theta = readlane_f(lv, KK-1);
  #pragma unroll
  for(int j=0;j<8;j++){
    float cand = (j == jbest) ? -INFINITY : cd0[j];
    unsigned long long bal = __ballot(cand > theta);
    while(bal){
      int bpos = __ffsll((unsigned long long)bal) - 1;
      bal &= bal - 1;
      float cv = readlane_f(cand, bpos);
      if(cv > theta){
        int ci = (j < 4) ? (4*bpos + j) : (256 + 4*bpos + (j-4));
        INSERT_CAND(cv, ci)
      }
    }
  }
  for(int ms=512; ms<NN; ms+=256){
    float4 c4 = *(const float4*)&dr[ms + 4*lane];
    #pragma unroll
    for(int j=0;j<4;j++){
      float cand = (j==0)?c4.x:(j==1)?c4.y:(j==2)?c4.z:c4.w;
      unsigned long long bal = __ballot(cand > theta);
      while(bal){
        int bpos = __ffsll((unsigned long long)bal) - 1;
        bal &= bal - 1;
        float cv = readlane_f(cand, bpos);
        if(cv > theta){
          int ci = ms + 4*bpos + j;
          INSERT_CAND(cv, ci)
        }
      }
    }
  }
  if(lane < KK) id[((size_t)b0*NN + w)*KK + lane] = li;
}

// L1 fused: inline C=3 distances + inline sqnorm, max-of-8 bitonic warm start.
__launch_bounds__(256) __global__ void sel3_k(const float* __restrict__ X, int* __restrict__ id){
  const int gw = (blockIdx.x*256 + threadIdx.x) >> 6;
  const int lane = threadIdx.x & 63;
  const int b = gw >> 11, n = gw & 2047;
  const float* Xb  = X + (size_t)b*NN*3;
  const float x0v = Xb[n*3], x1v = Xb[n*3+1], x2v = Xb[n*3+2];
  float xxn = 0.f;
  xxn = fmaf(x0v, x0v, xxn); xxn = fmaf(x1v, x1v, xxn); xxn = fmaf(x2v, x2v, xxn);
  float lv, theta; int li;
  {
    float cd[8];
    #pragma unroll
    for(int g=0; g<2; g++){
      const float* p = Xb + (size_t)(g*256 + 4*lane)*3;
      float4 va = *(const float4*)p;
      float4 vb = *(const float4*)(p+4);
      float4 vc = *(const float4*)(p+8);
      float cx[4] = {va.x, va.w, vb.z, vc.y};
      float cy[4] = {va.y, vb.x, vb.w, vc.z};
      float cz[4] = {va.z, vb.y, vc.x, vc.w};
      #pragma unroll
      for(int j=0;j<4;j++){
        float s = 0.f;
        s = fmaf(x0v, cx[j], s); s = fmaf(x1v, cy[j], s); s = fmaf(x2v, cz[j], s);
        float xxm = 0.f;
        xxm = fmaf(cx[j], cx[j], xxm); xxm = fmaf(cy[j], cy[j], xxm); xxm = fmaf(cz[j], cz[j], xxm);
        cd[g*4 + j] = (2.f*s - xxn) - xxm;
      }
    }
    int jbest = 0; float v = cd[0];
    #pragma unroll
    for(int j=1;j<8;j++){ if(cd[j] > v){ v = cd[j]; jbest = j; } }
    int vi = (jbest < 4) ? (4*lane + jbest) : (256 + 4*lane + (jbest-4));
    BITONIC64_DESC(v, vi)
    lv = (lane < KK) ? v : -INFINITY;
    li = (lane < KK) ? vi : 0;
    theta = readlane_f(lv, KK-1);
    #pragma unroll
    for(int j=0;j<8;j++){
      float cand = (j == jbest) ? -INFINITY : cd[j];
      unsigned long long bal = __ballot(cand > theta);
      while(bal){
        int bpos = __ffsll((unsigned long long)bal) - 1;
        bal &= bal - 1;
        float cv = readlane_f(cand, bpos);
        if(cv > theta){
          int ci = (j < 4) ? (4*bpos + j) : (256 + 4*bpos + (j-4));
          INSERT_CAND(cv, ci)
        }
      }
    }
  }
  for(int ms=512; ms<NN; ms+=256){
    const float* p = Xb + (size_t)(ms + 4*lane)*3;
    float4 va = *(const float4*)p;
    float4 vb = *(const float4*)(p+4);
    float4 vc = *(const float4*)(p+8);
    float cx[4] = {va.x, va.w, vb.z, vc.y};
    float cy[4] = {va.y, vb.x, vb.w, vc.z};
    float cz[4] = {va.z, vb.y, vc.x, vc.w};
    float cd[4];
    #pragma unroll
    for(int j=0;j<4;j++){
      float s = 0.f;
      s = fmaf(x0v, cx[j], s); s = fmaf(x1v, cy[j], s); s = fmaf(x2v, cz[j], s);
      float xxm = 0.f;
      xxm = fmaf(cx[j], cx[j], xxm); xxm = fmaf(cy[j], cy[j], xxm); xxm = fmaf(cz[j], cz[j], xxm);
      cd[j] = (2.f*s - xxn) - xxm;
    }
    #pragma unroll
    for(int j=0;j<4;j++){
      float cand = cd[j];
      unsigned long long bal = __ballot(cand > theta);
      while(bal){
        int bpos = __ffsll((unsigned long long)bal) - 1;
        bal &= bal - 1;
        float cv = readlane_f(cand, bpos);
        if(cv > theta){
          int ci = ms + 4*bpos + j;
          INSERT_CAND(cv, ci)
        }
      }
    }
  }
  if(lane < KK) id[(size_t)gw*KK + lane] = li;
}

// ---------------- qp ----------------
// L1: writes interleaved qp[row][128]: q at 0..63, p at 64..127
__launch_bounds__(256) __global__ void qp3_k(const float* X, const float* W, float* qp){
  const int t   = blockIdx.x*256 + threadIdx.x;
  const int row = t >> 3;
  const int c0  = (t & 7) * 8;
  float xn[3];
  #pragma unroll
  for(int c=0;c<3;c++) xn[c] = X[(size_t)row*3 + c];
  for(int oi=c0; oi<c0+8; oi++){
    const float* w = W + (size_t)oi*6;
    float aq=0.f, ap=0.f;
    #pragma unroll
    for(int c=0;c<3;c++){ aq = fmaf(xn[c], w[c], aq); ap = fmaf(xn[c], w[3+c], ap); }
    qp[(size_t)row*128 + oi]      = aq;
    qp[(size_t)row*128 + 64 + oi] = ap;
  }
}

// qp via split-bf16 MFMA: qp[BN][W2C] = Xsplit * WTsplit.
// FULL=true: 6-product (KNN-critical layers 2/3). FULL=false: 3-product (terminal layer 4).
// Grid (BN/128, W2C/64); block 128r x 64c; wave 64r x 32c.
template<int KT, int W2C, bool FULL>
__launch_bounds__(256) __global__ void qp_mfma_k(const u16* __restrict__ xh, const u16* __restrict__ xm,
    const u16* __restrict__ xl,
    const u16* __restrict__ wh, const u16* __restrict__ wm, const u16* __restrict__ wl,
    float* __restrict__ qp){
  const int tid = threadIdx.x;
  const int l  = tid & 63, wv = tid >> 6;
  const int lg = l >> 4, lr = l & 15;
  const int row0 = blockIdx.x*128 + (wv>>1)*64;
  const int col0 = blockIdx.y*64 + (wv&1)*32;
  f32x4 acc[4][2];
  #pragma unroll
  for(int m=0;m<4;m++){
    #pragma unroll
    for(int n=0;n<2;n++) acc[m][n] = (f32x4){0.f,0.f,0.f,0.f};
  }
  const size_t abase = (size_t)(row0>>4)*KT*512 + (size_t)l*8;
  const size_t bbase = (size_t)(col0>>4)*KT*512 + (size_t)l*8;
  for(int kt=0; kt<KT; kt++){
    short8 Ah[4], Am[4], Al[4], Bh[2], Bm[2], Bl[2];
    #pragma unroll
    for(int m=0;m<4;m++){
      size_t o = abase + (size_t)(m*KT + kt)*512;
      Ah[m] = *(const short8*)(xh + o);
      Am[m] = *(const short8*)(xm + o);
      if constexpr (FULL) Al[m] = *(const short8*)(xl + o);
    }
    #pragma unroll
    for(int n=0;n<2;n++){
      size_t o = bbase + (size_t)(n*KT + kt)*512;
      Bh[n] = *(const short8*)(wh + o);
      Bm[n] = *(const short8*)(wm + o);
      if constexpr (FULL) Bl[n] = *(const short8*)(wl + o);
    }
    #pragma unroll
    for(int m=0;m<4;m++){
      #pragma unroll
      for(int n=0;n<2;n++){
        if constexpr (FULL) {
          MFMA6(acc[m][n], Ah[m], Am[m], Al[m], Bh[n], Bm[n], Bl[n])
        } else {
          MFMA3(acc[m][n], Ah[m], Am[m], Bh[n], Bm[n])
        }
      }
    }
  }
  #pragma unroll
  for(int m=0;m<4;m++){
    #pragma unroll
    for(int r=0;r<4;r++){
      int row = row0 + m*16 + 4*lg + r;
      float* dp = qp + (size_t)row*W2C + col0;
      #pragma unroll
      for(int n=0;n<2;n++) dp[n*16 + lr] = acc[m][n][r];
    }
  }
}

// Gather from interleaved qp[row][2*COUT] (q | p); base = p - q computed here.
template<int COUT>
__launch_bounds__(256) __global__ void gather_qp_k(const float* __restrict__ qp, const int* __restrict__ idx,
    const float* g, const float* bb, float* out){
  const int t  = blockIdx.x*256 + threadIdx.x;   // BN*COUT
  const int o  = t % COUT;
  const int bn = t / COUT;
  const int b  = bn >> 11;
  const int* id = idx + (size_t)bn*KK;
  float qv = qp[(size_t)bn*(2*COUT) + o];
  float pv = qp[(size_t)bn*(2*COUT) + COUT + o];
  float base = pv - qv;
  float mx = -INFINITY, mn = INFINITY;
  #pragma unroll
  for(int k=0;k<KK;k++){
    int ik = id[k];
    float v = qp[((size_t)((b<<11) + ik))*(2*COUT) + o];
    mx = fmaxf(mx, v); mn = fminf(mn, v);
  }
  float a  = g[o] * RSQ;
  float bo = bb[o];
  out[(size_t)bn*COUT + o] = lrelu((a >= 0.f ? a*(mx+base) : a*(mn+base)) + bo);
}

// ---- fallback chunked qp (cat weight layout) + chunked gather ----
template<int CIN, int COUT>
__launch_bounds__(256) __global__ void qp64T_k(const float* __restrict__ X, const float* __restrict__ WT,
                                               int cb, float* __restrict__ q, float* __restrict__ bs){
  const int t   = blockIdx.x*256 + threadIdx.x;
  const int row = t >> 3;
  const int o0  = cb + (t & 7) * 8;
  float xn[CIN];
  #pragma unroll
  for(int c=0;c<CIN;c+=4){ float4 v = *(const float4*)(X + (size_t)row*CIN + c);
    xn[c]=v.x; xn[c+1]=v.y; xn[c+2]=v.z; xn[c+3]=v.w; }
  float aq[8], ap[8];
  #pragma unroll
  for(int j=0;j<8;j++){ aq[j]=0.f; ap[j]=0.f; }
  #pragma unroll 4
  for(int c=0;c<CIN;c++){
    float xc = xn[c];
    float4 wa0 = *(const float4*)&WT[(size_t)c*(2*COUT) + o0];
    float4 wa1 = *(const float4*)&WT[(size_t)c*(2*COUT) + o0 + 4];
    float4 wb0 = *(const float4*)&WT[(size_t)c*(2*COUT) + COUT + o0];
    float4 wb1 = *(const float4*)&WT[(size_t)c*(2*COUT) + COUT + o0 + 4];
    aq[0]=fmaf(xc,wa0.x,aq[0]); aq[1]=fmaf(xc,wa0.y,aq[1]); aq[2]=fmaf(xc,wa0.z,aq[2]); aq[3]=fmaf(xc,wa0.w,aq[3]);
    aq[4]=fmaf(xc,wa1.x,aq[4]); aq[5]=fmaf(xc,wa1.y,aq[5]); aq[6]=fmaf(xc,wa1.z,aq[6]); aq[7]=fmaf(xc,wa1.w,aq[7]);
    ap[0]=fmaf(xc,wb0.x,ap[0]); ap[1]=fmaf(xc,wb0.y,ap[1]); ap[2]=fmaf(xc,wb0.z,ap[2]); ap[3]=fmaf(xc,wb0.w,ap[3]);
    ap[4]=fmaf(xc,wb1.x,ap[4]); ap[5]=fmaf(xc,wb1.y,ap[5]); ap[6]=fmaf(xc,wb1.z,ap[6]); ap[7]=fmaf(xc,wb1.w,ap[7]);
  }
  float* qpp = q  + (size_t)row*64 + (o0-cb);
  float* bpp = bs + (size_t)row*64 + (o0-cb);
  *(float4*)qpp     = make_float4(aq[0],aq[1],aq[2],aq[3]);
  *(float4*)(qpp+4) = make_float4(aq[4],aq[5],aq[6],aq[7]);
  *(float4*)bpp     = make_float4(ap[0]-aq[0],ap[1]-aq[1],ap[2]-aq[2],ap[3]-aq[3]);
  *(float4*)(bpp+4) = make_float4(ap[4]-aq[4],ap[5]-aq[5],ap[6]-aq[6],ap[7]-aq[7]);
}

template<int CFULL>
__launch_bounds__(256) __global__ void gather_chunk_k(const float* q, const float* bs, const int* idx,
    const float* g, const float* bb, int cb, float* out){
  const int t  = blockIdx.x*256 + threadIdx.x;
  const int o  = t & 63;
  const int bn = t >> 6;
  const int b  = bn >> 11;
  const int* id = idx + (size_t)bn*KK;
  float base = bs[t];
  float mx = -INFINITY, mn = INFINITY;
  #pragma unroll
  for(int k=0;k<KK;k++){
    int ik = id[k];
    float v = q[((size_t)((b<<11) + ik))*64 + o];
    mx = fmaxf(mx, v); mn = fminf(mn, v);
  }
  float a  = g[cb+o] * RSQ;
  float bo = bb[cb+o];
  out[(size_t)bn*CFULL + cb + o] = lrelu((a >= 0.f ? a*(mx+base) : a*(mn+base)) + bo);
}

// ---------------- head (fallback): fp32 GEMM-tiled cat x W5T with fused max/min ----------------
__launch_bounds__(256) __global__ void w5gemm_k(const float* __restrict__ x1, const float* __restrict__ x2,
    const float* __restrict__ x3, const float* __restrict__ x4,
    const float* __restrict__ W5T, unsigned* mxe, unsigned* mne){
  constexpr int ASTA = 92;
  constexpr int ASTB = 188;
  __shared__ __align__(16) float a_sh[16*ASTA];
  __shared__ __align__(16) float b_sh[16*ASTB];
  const int tid = threadIdx.x;
  const int otile = blockIdx.x*128;
  const int rtile = blockIdx.y*64;
  const int b     = blockIdx.z;
  const int tn = tid & 15, tm = tid >> 4;
  const int aoff = 4*tn + 4*(tn>>1);
  const size_t row0 = (size_t)b*NN + rtile;
  float acc[4][8];
  #pragma unroll
  for(int i=0;i<4;i++){
    #pragma unroll
    for(int j=0;j<8;j++) acc[i][j]=0.f;
  }
  for(int cc=0; cc<512; cc+=16){
    const float* src; int stride, coff;
    if(cc<64)      { src=x1; stride=64;  coff=cc; }
    else if(cc<128){ src=x2; stride=64;  coff=cc-64; }
    else if(cc<256){ src=x3; stride=128; coff=cc-128; }
    else           { src=x4; stride=256; coff=cc-256; }
    __syncthreads();
    { int r = tid>>2, q = tid&3;
      int pr = r + 4*(r>>3);
      float4 va = *(const float4*)&src[(row0 + r)*stride + coff + 4*q];
      a_sh[(4*q+0)*ASTA + pr]=va.x; a_sh[(4*q+1)*ASTA + pr]=va.y;
      a_sh[(4*q+2)*ASTA + pr]=va.z; a_sh[(4*q+3)*ASTA + pr]=va.w; }
    #pragma unroll
    for(int s=0;s<2;s++){
      int ii = tid + 256*s;
      int cl = ii>>5, o4 = ii&31;
      float4 vb = *(const float4*)&W5T[(size_t)(cc+cl)*512 + otile + 4*o4];
      *(float4*)&b_sh[cl*ASTB + 4*o4 + 4*(o4>>1)] = vb;
    }
    __syncthreads();
    #pragma unroll
    for(int c=0;c<16;c++){
      float4 A0 = *(const float4*)&a_sh[c*ASTA + aoff];
      float4 B0 = *(const float4*)&b_sh[c*ASTB + 12*tm];
      float4 B1 = *(const float4*)&b_sh[c*ASTB + 12*tm + 4];
      float b0v=B0.x,b1v=B0.y,b2v=B0.z,b3v=B0.w,b4v=B1.x,b5v=B1.y,b6v=B1.z,b7v=B1.w;
      float a;
      a=A0.x; FMA_ROW(0)
      a=A0.y; FMA_ROW(1)
      a=A0.z; FMA_ROW(2)
      a=A0.w; FMA_ROW(3)
    }
  }
  #pragma unroll
  for(int j=0;j<8;j++){
    float M=-INFINITY, m=INFINITY;
    #pragma unroll
    for(int i=0;i<4;i++){ M=fmaxf(M,acc[i][j]); m=fminf(m,acc[i][j]); }
    #pragma unroll
    for(int d=1; d<16; d<<=1){
      M = fmaxf(M, __shfl_xor(M, d));
      m = fminf(m, __shfl_xor(m, d));
    }
    if(tn == 0){
      int o = otile + tm*8 + j;
      atomicMax(&mxe[b*512+o], encf(M));
      atomicMin(&mne[b*512+o], encf(m));
    }
  }
}

// ---------------- head (big): split-bf16 MFMA (3-product, terminal) ----------------
// xcat 2-split (h/m only) into fragment-major tiled layout (KT=16, row space = BN).
__launch_bounds__(256) __global__ void cvt_k(const float* __restrict__ x1, const float* __restrict__ x2,
    const float* __restrict__ x3, const float* __restrict__ x4,
    u16* __restrict__ xh, u16* __restrict__ xm){
  const size_t t = (size_t)blockIdx.x*256 + threadIdx.x;   // BN*512/8 chunks
  const int l = (int)(t & 63);
  const size_t tile = t >> 6;           // rgG*16 + kt
  const int kt = (int)(tile & 15);
  const size_t rgG = tile >> 4;
  const size_t row = rgG*16 + (l & 15);
  const int col = kt*32 + ((l>>4)<<3);
  const float* src; int stride, coff;
  if(col<64)      { src=x1; stride=64;  coff=col; }
  else if(col<128){ src=x2; stride=64;  coff=col-64; }
  else if(col<256){ src=x3; stride=128; coff=col-128; }
  else            { src=x4; stride=256; coff=col-256; }
  const float* p = src + row*stride + coff;
  float4 v0 = *(const float4*)p;
  float4 v1 = *(const float4*)(p+4);
  float vs[8] = {v0.x,v0.y,v0.z,v0.w,v1.x,v1.y,v1.z,v1.w};
  ushort8 H, M;
  #pragma unroll
  for(int j=0;j<8;j++){ u16 h,m,lo; bf16split3(vs[j],h,m,lo); H[j]=h; M[j]=m; (void)lo; }
  *(ushort8*)(xh + t*8) = H;
  *(ushort8*)(xm + t*8) = M;
}

// C[16384x512] = xcat * W5^T via 3 bf16 MFMA products (hh+hm+mh, terminal-GEMM precision),
// fused per-column max/min. 64-col tiles: grid (128 rowblk, 8 colblk); A-sharing blocks
// 128 apart -> same XCD L2.
__launch_bounds__(256) __global__ void w5mfma_k(const u16* __restrict__ xh, const u16* __restrict__ xm,
    const u16* __restrict__ wh, const u16* __restrict__ wm,
    unsigned* mxe, unsigned* mne){
  const int tid = threadIdx.x;
  const int l  = tid & 63, wv = tid >> 6;
  const int lg = l >> 4, lr = l & 15;
  const int row0 = blockIdx.x*128 + (wv>>1)*64;   // M base of this wave (global BN rows)
  const int col0 = blockIdx.y*64 + (wv&1)*32;     // N base of this wave
  const int b = blockIdx.x >> 4;                  // 16 M-blocks per batch
  f32x4 acc[4][2];
  #pragma unroll
  for(int m=0;m<4;m++){
    #pragma unroll
    for(int n=0;n<2;n++) acc[m][n] = (f32x4){0.f,0.f,0.f,0.f};
  }
  const size_t abase = (size_t)(row0>>4)*16*512 + (size_t)l*8;
  const size_t bbase = (size_t)(col0>>4)*16*512 + (size_t)l*8;
  for(int kt=0; kt<16; kt++){
    short8 Ah[4], Am[4], Bh[2], Bm[2];
    #pragma unroll
    for(int m=0;m<4;m++){
      size_t o = abase + (size_t)(m*16 + kt)*512;
      Ah[m] = *(const short8*)(xh + o);
      Am[m] = *(const short8*)(xm + o);
    }
    #pragma unroll
    for(int n=0;n<2;n++){
      size_t o = bbase + (size_t)(n*16 + kt)*512;
      Bh[n] = *(const short8*)(wh + o);
      Bm[n] = *(const short8*)(wm + o);
    }
    #pragma unroll
    for(int m=0;m<4;m++){
      #pragma unroll
      for(int n=0;n<2;n++){
        MFMA3(acc[m][n], Ah[m], Am[m], Bh[n], Bm[n])
      }
    }
  }
  #pragma unroll
  for(int n=0;n<2;n++){
    float M = -INFINITY, mnv = INFINITY;
    #pragma unroll
    for(int m=0;m<4;m++){
      #pragma unroll
      for(int r=0;r<4;r++){ float v = acc[m][n][r]; M = fmaxf(M, v); mnv = fminf(mnv, v); }
    }
    M   = fmaxf(M,   __shfl_xor(M, 16));   M   = fmaxf(M,   __shfl_xor(M, 32));
    mnv = fminf(mnv, __shfl_xor(mnv, 16)); mnv = fminf(mnv, __shfl_xor(mnv, 32));
    if(lg == 0){
      int o = col0 + n*16 + lr;
      atomicMax(&mxe[b*512+o], encf(M));
      atomicMin(&mne[b*512+o], encf(mnv));
    }
  }
}

__launch_bounds__(256) __global__ void final_k(const unsigned* mxe, const unsigned* mne,
    const float* g5, const float* b5, const float* Wemb, float* out){
  const int b = blockIdx.x, t = threadIdx.x;
  __shared__ float h[512];
  for(int o=t; o<512; o+=256){
    float mx = decf(mxe[b*512+o]);
    float mn = decf(mne[b*512+o]);
    float a  = g5[o] * RSQ;
    float bo = b5[o];
    float hv = lrelu((a >= 0.f ? a*mx : a*mn) + bo);
    h[o] = hv;
    out[b*512+o] = hv;
  }
  __syncthreads();
  const float* wr = Wemb + (size_t)t*512;
  float s = 0.f;
  for(int o=0;o<512;o+=4){
    float4 w4 = *(const float4*)(wr+o);
    s = fmaf(h[o],w4.x, fmaf(h[o+1],w4.y, fmaf(h[o+2],w4.z, fmaf(h[o+3],w4.w, s))));
  }
  out[4096 + b*256 + t] = s;
}

// ---------------- launch ----------------
extern "C" void kernel_launch(void* const* d_in, const int* in_sizes, int n_in,
                              void* d_out, int out_size, void* d_ws, size_t ws_size,
                              hipStream_t stream) {
  if (ws_size < WS_END * sizeof(float)) return;
  const bool big = ws_size >= WS_BIG_END * sizeof(float);   // deterministic per call

  const float* x0   = (const float*)d_in[0];
  const float* W1   = (const float*)d_in[1];
  const float* g1   = (const float*)d_in[2];
  const float* b1   = (const float*)d_in[3];
  const float* W2   = (const float*)d_in[4];
  const float* g2   = (const float*)d_in[5];
  const float* b2   = (const float*)d_in[6];
  const float* W3   = (const float*)d_in[7];
  const float* g3   = (const float*)d_in[8];
  const float* b3   = (const float*)d_in[9];
  const float* W4   = (const float*)d_in[10];
  const float* g4   = (const float*)d_in[11];
  const float* b4   = (const float*)d_in[12];
  const float* W5   = (const float*)d_in[13];
  const float* g5   = (const float*)d_in[14];
  const float* b5   = (const float*)d_in[15];
  const float* Wemb = (const float*)d_in[16];

  float* ws = (float*)d_ws;
  float* xx = ws + OFF_XX;
  float* x1 = ws + OFF_X1;  float* x2 = ws + OFF_X2;
  float* x3 = ws + OFF_X3;  float* x4 = ws + OFF_X4;
  float* qpS = ws + OFF_SC;               // L1 qp (width 128) + fallback chunked q/bs
  float* bsS = ws + OFF_SC + (size_t)BN*64;
  int*   id = (int*)(ws + OFF_ID);
  float* W5Tf = ws + OFF_W5T;
  unsigned* mxe = (unsigned*)(ws + OFF_MX);
  unsigned* mne = (unsigned*)(ws + OFF_MN);
  float* WT2 = ws + OFF_WT2;
  float* WT3 = ws + OFF_WT3;
  float* WT4 = ws + OFF_WT4;
  float* distD = ws + OFF_X3;   // fallback dual-batch
  float* distS = ws + OFF_X4;   // fallback single-batch
  float* distB = ws + OFF_BIG;  // big: 4-batch dist chunk, then reused as qp buffer / bf16 xcat
  u16* w5h = (u16*)(ws + OFF_SC + (size_t)BN*128);   // SC tail (free in both paths): 3x256KB
  u16* w5m = w5h + 512*512;
  u16* w5l = w5m + 512*512;
  u16* wts = (u16*)W5Tf;         // big path: tiled WT splits live in the (unused) W5T region
  float* out = (float*)d_out;

  prep_k<<<1024,256,0,stream>>>(W5, W2, W3, W4, W5Tf, WT2, WT3, WT4,
                                w5h, w5m, w5l, wts, mxe, mne, big ? 1 : 0);

  // layer 1 (3 -> 64)
  sel3_k<<<BN*64/256,256,0,stream>>>(x0, id);
  qp3_k<<<BN*8/256,256,0,stream>>>(x0, W1, qpS);
  gather_qp_k<64><<<BN*64/256,256,0,stream>>>(qpS, id, g1, b1, x1);

  if(big){
    float* qpB = distB;                      // reuse dist region post-sel
    // split scratch lives in x4 region (dead until layer-4 gather)
    u16* sh = (u16*)x4;
    // layer 2 (CIN=64 -> COUT=64, qp width 128)
    { u16* sm = sh + (size_t)BN*64; u16* sl = sm + (size_t)BN*64;
      sqnorm_k<64><<<BN/256,256,0,stream>>>(x1, xx);
      split_k<64><<<BN*64/8/256,256,0,stream>>>(x1, sh, sm, sl);
      for(int c0=0;c0<BB;c0+=4){
        mfma_dist_k<64><<<dim3(32,16,4),256,0,stream>>>(sh, sm, sl, xx, distB, c0);
        sel_k<<<(4*NN)/4,256,0,stream>>>(distB, id, c0, 4*NN);
      }
      qp_mfma_k<2,128,true><<<dim3(BN/128,2),256,0,stream>>>(sh, sm, sl,
          wts+WTS_2H, wts+WTS_2M, wts+WTS_2L, qpB);
      gather_qp_k<64><<<BN*64/256,256,0,stream>>>(qpB, id, g2, b2, x2); }
    // layer 3 (64 -> 128, qp width 256)
    { u16* sm = sh + (size_t)BN*64; u16* sl = sm + (size_t)BN*64;
      sqnorm_k<64><<<BN/256,256,0,stream>>>(x2, xx);
      split_k<64><<<BN*64/8/256,256,0,stream>>>(x2, sh, sm, sl);
      for(int c0=0;c0<BB;c0+=4){
        mfma_dist_k<64><<<dim3(32,16,4),256,0,stream>>>(sh, sm, sl, xx, distB, c0);
        sel_k<<<(4*NN)/4,256,0,stream>>>(distB, id, c0, 4*NN);
      }
      qp_mfma_k<2,256,true><<<dim3(BN/128,4),256,0,stream>>>(sh, sm, sl,
          wts+WTS_3H, wts+WTS_3M, wts+WTS_3L, qpB);
      gather_qp_k<128><<<BN*128/256,256,0,stream>>>(qpB, id, g3, b3, x3); }
    // layer 4 (128 -> 256, qp width 512): terminal for KNN -> 3-product qp
    { u16* sm = sh + (size_t)BN*128; u16* sl = sm + (size_t)BN*128;
      sqnorm_k<128><<<BN/256,256,0,stream>>>(x3, xx);
      split_k<128><<<BN*128/8/256,256,0,stream>>>(x3, sh, sm, sl);
      for(int c0=0;c0<BB;c0+=4){
        mfma_dist_k<128><<<dim3(32,16,4),256,0,stream>>>(sh, sm, sl, xx, distB, c0);
        sel_k<<<(4*NN)/4,256,0,stream>>>(distB, id, c0, 4*NN);
      }
      qp_mfma_k<4,512,false><<<dim3(BN/128,8),256,0,stream>>>(sh, sm, sl,
          wts+WTS_4H, wts+WTS_4M, wts+WTS_4L, qpB);
      gather_qp_k<256><<<BN*256/256,256,0,stream>>>(qpB, id, g4, b4, x4); }
    // head: bf16 2-split (tiled) + 3-product MFMA (terminal-GEMM precision)
    u16* xh = (u16*)(ws + OFF_XCAT);
    u16* xm = xh + (size_t)BN*512;
    cvt_k<<<BN*512/8/256,256,0,stream>>>(x1, x2, x3, x4, xh, xm);
    w5mfma_k<<<dim3(128,8),256,0,stream>>>(xh, xm, w5h, w5m, mxe, mne);
  } else {
    // fallback: chunked (R12 structure, cat weight layout)
    sqnorm_k<64><<<BN/256,256,0,stream>>>(x1, xx);
    for(int r=0;r<4;r++){
      gemm_dist_k<64><<<dim3(16,16,2),256,0,stream>>>(x1, xx, distD, 2*r);
      sel_k<<<(2*NN)/4,256,0,stream>>>(distD, id, 2*r, 2*NN);
    }
    qp64T_k<64,64><<<BN*8/256,256,0,stream>>>(x1, WT2, 0, qpS, bsS);
    gather_chunk_k<64><<<BN*64/256,256,0,stream>>>(qpS, bsS, id, g2, b2, 0, x2);

    sqnorm_k<64><<<BN/256,256,0,stream>>>(x2, xx);
    for(int r=0;r<4;r++){
      gemm_dist_k<64><<<dim3(16,16,2),256,0,stream>>>(x2, xx, distD, 2*r);
      sel_k<<<(2*NN)/4,256,0,stream>>>(distD, id, 2*r, 2*NN);
    }
    for(int cb=0; cb<128; cb+=64){
      qp64T_k<64,128><<<BN*8/256,256,0,stream>>>(x2, WT3, cb, qpS, bsS);
      gather_chunk_k<128><<<BN*64/256,256,0,stream>>>(qpS, bsS, id, g3, b3, cb, x3);
    }

    sqnorm_k<128><<<BN/256,256,0,stream>>>(x3, xx);
    for(int r=0;r<8;r++){
      gemm_dist_k<128><<<dim3(16,16,1),256,0,stream>>>(x3, xx, distS, r);
      sel_k<<<NN/4,256,0,stream>>>(distS, id, r, NN);
    }
    for(int cb=0; cb<256; cb+=64){
      qp64T_k<128,256><<<BN*8/256,256,0,stream>>>(x3, WT4, cb, qpS, bsS);
      gather_chunk_k<256><<<BN*64/256,256,0,stream>>>(qpS, bsS, id, g4, b4, cb, x4);
    }
    w5gemm_k<<<dim3(4,32,8),256,0,stream>>>(x1, x2, x3, x4, W5Tf, mxe, mne);
  }

  final_k<<<BB,256,0,stream>>>(mxe, mne, g5, b5, Wemb, out);
}

// Round 17
// 517.999 us; speedup vs baseline: 1.2242x; 1.0525x over previous
//
#include <hip/hip_runtime.h>
#include <hip/hip_bf16.h>

#define BB 8
#define NN 2048
#define KK 20
#define BN (BB*NN)
#define RSQ 0.99999500003749969f   // 1/sqrt(1+1e-5)

// ---------------- workspace layout (float-slot units) ----------------
constexpr size_t OFF_XX  = 0;                          // BN
constexpr size_t OFF_X1  = OFF_XX  + BN;               // BN*64
constexpr size_t OFF_X2  = OFF_X1  + (size_t)BN*64;    // BN*64
constexpr size_t OFF_X3  = OFF_X2  + (size_t)BN*64;    // BN*128
constexpr size_t OFF_X4  = OFF_X3  + (size_t)BN*128;   // BN*256 (split-scratch pre-gather)
constexpr size_t OFF_SC  = OFF_X4  + (size_t)BN*256;   // BN*160 (L1 qp + fallback chunked qp + W5 bf16 tail)
constexpr size_t OFF_ID  = OFF_SC  + (size_t)BN*160;   // int BN*20
constexpr size_t OFF_W5T = OFF_ID  + (size_t)BN*20;    // 512*512 (big path: tiled WT splits live here)
constexpr size_t OFF_MX  = OFF_W5T + 512*512;
constexpr size_t OFF_MN  = OFF_MX  + BB*512;
constexpr size_t OFF_WT2 = OFF_MN  + BB*512;           // cat [64][128]
constexpr size_t OFF_WT3 = OFF_WT2 + 8192;             // cat [64][256]
constexpr size_t OFF_WT4 = OFF_WT3 + 16384;            // cat [128][512]
constexpr size_t WS_END  = OFF_WT4 + 65536;            // 11,714,560 floats
// big region (probed at runtime): dist chunk (4 batches) + qp buffer + bf16 xcat post-sel
constexpr size_t OFF_BIG = WS_END;
constexpr size_t OFF_XCAT = OFF_BIG + (size_t)16*1024*1024;  // bf16 xcat h/m (dist region tail, post-KNN)
constexpr size_t WS_BIG_END = OFF_BIG + (size_t)BB*NN*NN;   // 172.7 MiB
static_assert(OFF_ID - OFF_X3 >= (size_t)4096*2048, "fallback dual dist fits");
static_assert(OFF_XCAT + (size_t)BN*512 <= WS_BIG_END, "xcat h/m fits in dist region");

typedef unsigned short u16;
typedef __attribute__((ext_vector_type(8))) short short8;
typedef __attribute__((ext_vector_type(8))) unsigned short ushort8;
typedef __attribute__((ext_vector_type(4))) float f32x4;

// tiled WT split offsets (u16 units) within the W5T region (big path only)
constexpr size_t WTS_2H = 0,      WTS_2M = 8192,   WTS_2L = 16384;
constexpr size_t WTS_3H = 24576,  WTS_3M = 40960,  WTS_3L = 57344;
constexpr size_t WTS_4H = 73728,  WTS_4M = 139264, WTS_4L = 204800;   // end 270336 u16 <= 524288

__device__ inline unsigned encf(float f){ unsigned u=__float_as_uint(f); return (u&0x80000000u)? ~u : (u|0x80000000u); }
__device__ inline float decf(unsigned e){ unsigned u=(e&0x80000000u)? (e&0x7fffffffu) : ~e; return __uint_as_float(u); }
__device__ inline float lrelu(float h){ return h>=0.f ? h : 0.2f*h; }
__device__ inline u16 bf16rne(float x){
  unsigned u = __float_as_uint(x);
  return (u16)((u + 0x7FFFu + ((u>>16)&1u)) >> 16);
}
__device__ inline float bf16f(u16 h){ return __uint_as_float((unsigned)h<<16); }
// exact 3-way split: x == h + m + l for normal fp32 (24 mantissa bits covered)
__device__ inline void bf16split3(float v, u16& h, u16& m, u16& l){
  h = bf16rne(v);  float r1 = v  - bf16f(h);
  m = bf16rne(r1); float r2 = r1 - bf16f(m);
  l = bf16rne(r2);
}

__device__ inline float readlane_f(float v, int sl){
  return __int_as_float(__builtin_amdgcn_readlane(__float_as_int(v), sl));
}

// Wave-cooperative sorted-top-20 insertion (cv known > theta on call).
#define INSERT_CAND(cv, ci) { \
  unsigned long long mge = __ballot((lv > cv) || (lv == cv && li < ci)); \
  int pos = __popcll(mge); \
  float upv = __shfl_up(lv, 1); \
  int   upi = __shfl_up(li, 1); \
  bool shift = (lane > pos) && (lane < KK); \
  lv = (lane == pos) ? cv : (shift ? upv : lv); \
  li = (lane == pos) ? ci : (shift ? upi : li); \
  theta = readlane_f(lv, KK-1); }

// Bitonic full sort of 64 (value desc, index asc on ties) across lanes; (v,vi) in registers.
#define BITONIC64_DESC(v, vi) { \
  _Pragma("unroll") \
  for(int k=2; k<=64; k<<=1){ \
    _Pragma("unroll") \
    for(int j=k>>1; j>=1; j>>=1){ \
      float ov = __shfl_xor(v, j); \
      int   oi = __shfl_xor(vi, j); \
      int partner = lane ^ j; \
      bool keepFirst = (((lane & k) == 0)) == (lane < partner); \
      bool before = (v > ov) || (v == ov && vi < oi); \
      if(keepFirst != before){ v = ov; vi = oi; } \
    } \
  } }

// 6-product split-bf16 MFMA macro (fp32-exact to ~2^-27): KNN-critical GEMMs.
#define MFMA6(ACC, AH, AM, AL, BH, BM, BL) { \
  ACC = __builtin_amdgcn_mfma_f32_16x16x32_bf16(AH, BH, ACC, 0, 0, 0); \
  ACC = __builtin_amdgcn_mfma_f32_16x16x32_bf16(AH, BM, ACC, 0, 0, 0); \
  ACC = __builtin_amdgcn_mfma_f32_16x16x32_bf16(AM, BH, ACC, 0, 0, 0); \
  ACC = __builtin_amdgcn_mfma_f32_16x16x32_bf16(AH, BL, ACC, 0, 0, 0); \
  ACC = __builtin_amdgcn_mfma_f32_16x16x32_bf16(AL, BH, ACC, 0, 0, 0); \
  ACC = __builtin_amdgcn_mfma_f32_16x16x32_bf16(AM, BM, ACC, 0, 0, 0); }

// 3-product variant (error ~3*2^-18 relative): terminal GEMMs only (head, layer-4 qp).
#define MFMA3(ACC, AH, AM, BH, BM) { \
  ACC = __builtin_amdgcn_mfma_f32_16x16x32_bf16(AH, BH, ACC, 0, 0, 0); \
  ACC = __builtin_amdgcn_mfma_f32_16x16x32_bf16(AH, BM, ACC, 0, 0, 0); \
  ACC = __builtin_amdgcn_mfma_f32_16x16x32_bf16(AM, BH, ACC, 0, 0, 0); }

// ======== fragment-major tiled split layout ========
// split[rowGroup][kTile][lane=64][8]  (u16). lane l -> row = rg*16 + (l&15), k = kt*32 + (l>>4)*8.

// ---------------- prep: weights transposes + splits + enc ----------------
__global__ void prep_k(const float* W5, const float* W2, const float* W3, const float* W4,
                       float* W5T, float* WT2, float* WT3, float* WT4,
                       u16* w5h, u16* w5m, u16* w5l, u16* wts,
                       unsigned* mx, unsigned* mn, int big){
  int i = blockIdx.x*256 + threadIdx.x;     // 262144
  if(!big){ int o = i>>9, c = i&511; W5T[c*512+o] = W5[i]; }   // fp32 W5T only for fallback
  { // tiled split of W5 (B-side rows = output cols o, k = input c). KT=16.
    int rg = i>>13, kt = (i>>9)&15, l = (i>>3)&63, j = i&7;
    int o = rg*16 + (l&15);
    int c = kt*32 + ((l>>4)<<3) + j;
    u16 h,m,lo; bf16split3(W5[(size_t)o*512 + c], h, m, lo);
    w5h[i]=h; w5m[i]=m; w5l[i]=lo; }
  if(i < 65536){ int c = i>>9, o = i&511;   // W4: [256][256] -> cat [128][512]
    WT4[i] = (o<256) ? W4[(size_t)o*256 + c] : W4[(size_t)(o-256)*256 + 128 + c]; }
  if(i < 16384){ int c = i>>8, o = i&255;   // W3: [128][128] -> cat [64][256]
    WT3[i] = (o<128) ? W3[(size_t)o*128 + c] : W3[(size_t)(o-128)*128 + 64 + c]; }
  if(i <  8192){ int c = i>>7, o = i&127;   // W2: [64][128] -> cat [64][128]
    WT2[i] = (o<64) ? W2[(size_t)o*128 + c] : W2[(size_t)(o-64)*128 + 64 + c]; }
  if(big){
    if(i < 65536){ // WT4 tiled split: rg over o (32), kt over c (4)
      int rg=i>>11, kt=(i>>9)&3, l=(i>>3)&63, j=i&7;
      int o = rg*16 + (l&15);
      int c = kt*32 + ((l>>4)<<3) + j;
      float v = (o<256) ? W4[(size_t)o*256 + c] : W4[(size_t)(o-256)*256 + 128 + c];
      u16 h,m,lo; bf16split3(v,h,m,lo);
      wts[WTS_4H+i]=h; wts[WTS_4M+i]=m; wts[WTS_4L+i]=lo; }
    if(i < 16384){ // WT3 tiled split: rg over o (16), kt over c (2)
      int rg=i>>10, kt=(i>>9)&1, l=(i>>3)&63, j=i&7;
      int o = rg*16 + (l&15);
      int c = kt*32 + ((l>>4)<<3) + j;
      float v = (o<128) ? W3[(size_t)o*128 + c] : W3[(size_t)(o-128)*128 + 64 + c];
      u16 h,m,lo; bf16split3(v,h,m,lo);
      wts[WTS_3H+i]=h; wts[WTS_3M+i]=m; wts[WTS_3L+i]=lo; }
    if(i < 8192){  // WT2 tiled split: rg over o (8), kt over c (2)
      int rg=i>>10, kt=(i>>9)&1, l=(i>>3)&63, j=i&7;
      int o = rg*16 + (l&15);
      int c = kt*32 + ((l>>4)<<3) + j;
      float v = (o<64) ? W2[(size_t)o*128 + c] : W2[(size_t)(o-64)*128 + 64 + c];
      u16 h,m,lo; bf16split3(v,h,m,lo);
      wts[WTS_2H+i]=h; wts[WTS_2M+i]=m; wts[WTS_2L+i]=lo; }
  }
  if(i <  4096){ mx[i] = 0x007FFFFFu; mn[i] = 0xFF800000u; }
}

// ---------------- KNN ----------------
template<int C>
__launch_bounds__(256) __global__ void sqnorm_k(const float* X, float* xx){
  int i = blockIdx.x*256 + threadIdx.x;   // BN
  const float* r = X + (size_t)i*C;
  float s = 0.f;
  #pragma unroll
  for(int c=0;c<C;c++) s = fmaf(r[c], r[c], s);
  xx[i] = s;
}

// 3-way bf16 split of X [BN][C] into fragment-major tiled layout.
template<int C>
__launch_bounds__(256) __global__ void split_k(const float* __restrict__ X,
    u16* __restrict__ xh, u16* __restrict__ xm, u16* __restrict__ xl){
  constexpr int KT = C/32;
  const size_t t = (size_t)blockIdx.x*256 + threadIdx.x;   // BN*C/8 chunks
  const int l = (int)(t & 63);
  const size_t tile = t >> 6;               // rgG*KT + kt
  const int kt = (int)(tile & (KT-1));
  const size_t rgG = tile / KT;             // global row group (BN/16 total)
  const size_t row = rgG*16 + (l & 15);
  const int k = kt*32 + ((l>>4)<<3);
  const float* p = X + row*C + k;
  float4 v0 = *(const float4*)p;
  float4 v1 = *(const float4*)(p+4);
  float vs[8] = {v0.x,v0.y,v0.z,v0.w,v1.x,v1.y,v1.z,v1.w};
  ushort8 H,M,L;
  #pragma unroll
  for(int j=0;j<8;j++){ u16 h,m,lo; bf16split3(vs[j],h,m,lo); H[j]=h; M[j]=m; L[j]=lo; }
  *(ushort8*)(xh + t*8) = H;
  *(ushort8*)(xm + t*8) = M;
  *(ushort8*)(xl + t*8) = L;
}

#define FMA_ROW(I) \
  acc[I][0]=fmaf(a,b0v,acc[I][0]); acc[I][1]=fmaf(a,b1v,acc[I][1]); \
  acc[I][2]=fmaf(a,b2v,acc[I][2]); acc[I][3]=fmaf(a,b3v,acc[I][3]); \
  acc[I][4]=fmaf(a,b4v,acc[I][4]); acc[I][5]=fmaf(a,b5v,acc[I][5]); \
  acc[I][6]=fmaf(a,b6v,acc[I][6]); acc[I][7]=fmaf(a,b7v,acc[I][7]);

// fallback fp32 dist GEMM
template<int C>
__launch_bounds__(256) __global__ void gemm_dist_k(const float* __restrict__ X, const float* __restrict__ xx,
                                                   float* __restrict__ dist, int b0){
  constexpr int AST = 188;
  __shared__ __align__(16) float a_sh[16*AST];
  __shared__ __align__(16) float b_sh[16*AST];
  __shared__ float sxn[128], sxm[128];
  const int tid = threadIdx.x;
  const int b   = b0 + blockIdx.z;
  const int mtile = blockIdx.x*128;
  const int ntile = blockIdx.y*128;
  const int tn = tid & 15, tm = tid >> 4;
  const float* Xb  = X  + (size_t)b*NN*C;
  const float* xxb = xx + (size_t)b*NN;
  if(tid < 128) sxn[tid] = xxb[ntile + tid];
  else          sxm[tid-128] = xxb[mtile + tid-128];
  float acc[8][8];
  #pragma unroll
  for(int i=0;i<8;i++){
    #pragma unroll
    for(int j=0;j<8;j++) acc[i][j]=0.f;
  }
  for(int cc=0; cc<C; cc+=16){
    __syncthreads();
    #pragma unroll
    for(int s=0;s<2;s++){
      int ii = tid + 256*s; int r = ii>>2, q = ii&3;
      int pr = r + 4*(r>>3);
      float4 va = *(const float4*)&Xb[(size_t)(ntile + r)*C + cc + 4*q];
      a_sh[(4*q+0)*AST + pr]=va.x; a_sh[(4*q+1)*AST + pr]=va.y;
      a_sh[(4*q+2)*AST + pr]=va.z; a_sh[(4*q+3)*AST + pr]=va.w;
      float4 vb = *(const float4*)&Xb[(size_t)(mtile + r)*C + cc + 4*q];
      b_sh[(4*q+0)*AST + pr]=vb.x; b_sh[(4*q+1)*AST + pr]=vb.y;
      b_sh[(4*q+2)*AST + pr]=vb.z; b_sh[(4*q+3)*AST + pr]=vb.w;
    }
    __syncthreads();
    #pragma unroll
    for(int c=0;c<16;c++){
      float4 A0 = *(const float4*)&a_sh[c*AST + 12*tn];
      float4 A1 = *(const float4*)&a_sh[c*AST + 12*tn + 4];
      float4 B0 = *(const float4*)&b_sh[c*AST + 12*tm];
      float4 B1 = *(const float4*)&b_sh[c*AST + 12*tm + 4];
      float b0v=B0.x,b1v=B0.y,b2v=B0.z,b3v=B0.w,b4v=B1.x,b5v=B1.y,b6v=B1.z,b7v=B1.w;
      float a;
      a=A0.x; FMA_ROW(0)
      a=A0.y; FMA_ROW(1)
      a=A0.z; FMA_ROW(2)
      a=A0.w; FMA_ROW(3)
      a=A1.x; FMA_ROW(4)
      a=A1.y; FMA_ROW(5)
      a=A1.z; FMA_ROW(6)
      a=A1.w; FMA_ROW(7)
    }
  }
  float xnr[8], xmr[8];
  #pragma unroll
  for(int i=0;i<8;i++){ xnr[i]=sxn[tn*8+i]; xmr[i]=sxm[tm*8+i]; }
  const size_t rowb = (size_t)blockIdx.z*NN + ntile + tn*8;
  #pragma unroll
  for(int i=0;i<8;i++){
    float4 w0, w1;
    w0.x=(2.f*acc[i][0]-xnr[i])-xmr[0]; w0.y=(2.f*acc[i][1]-xnr[i])-xmr[1];
    w0.z=(2.f*acc[i][2]-xnr[i])-xmr[2]; w0.w=(2.f*acc[i][3]-xnr[i])-xmr[3];
    w1.x=(2.f*acc[i][4]-xnr[i])-xmr[4]; w1.y=(2.f*acc[i][5]-xnr[i])-xmr[5];
    w1.z=(2.f*acc[i][6]-xnr[i])-xmr[6]; w1.w=(2.f*acc[i][7]-xnr[i])-xmr[7];
    float* dp = dist + (rowb + i)*NN + mtile + tm*8;
    *(float4*)dp = w0;
    *(float4*)(dp+4) = w1;
  }
}

// big path: exact-fp32-quality dist via split-bf16 MFMA (6 products of 3-way split).
// 64-col tiles for occupancy: grid (NN/64, 16, 4chunk); block 128q x 64c; wave 64q x 32c.
template<int C>
__launch_bounds__(256) __global__ void mfma_dist_k(const u16* __restrict__ xh, const u16* __restrict__ xm,
    const u16* __restrict__ xl, const float* __restrict__ xx, float* __restrict__ dist, int b0){
  constexpr int KT = C/32;
  const int tid = threadIdx.x;
  const int l  = tid & 63, wv = tid >> 6;
  const int lg = l >> 4, lr = l & 15;
  const int cz = blockIdx.z;
  const int b  = b0 + cz;
  const int qrow0 = blockIdx.y*128 + (wv>>1)*64;   // query rows (A side, dist row)
  const int crow0 = blockIdx.x*64 + (wv&1)*32;     // candidate rows (B side, dist col)
  const size_t brg = (size_t)b*(NN/16);
  f32x4 acc[4][2];
  #pragma unroll
  for(int m=0;m<4;m++){
    #pragma unroll
    for(int n=0;n<2;n++) acc[m][n] = (f32x4){0.f,0.f,0.f,0.f};
  }
  const size_t abase = (brg + (qrow0>>4))*KT*512 + (size_t)l*8;
  const size_t bbase = (brg + (crow0>>4))*KT*512 + (size_t)l*8;
  for(int kt=0; kt<KT; kt++){
    short8 Ah[4], Am[4], Al[4], Bh[2], Bm[2], Bl[2];
    #pragma unroll
    for(int m=0;m<4;m++){
      size_t o = abase + (size_t)(m*KT + kt)*512;
      Ah[m] = *(const short8*)(xh + o);
      Am[m] = *(const short8*)(xm + o);
      Al[m] = *(const short8*)(xl + o);
    }
    #pragma unroll
    for(int n=0;n<2;n++){
      size_t o = bbase + (size_t)(n*KT + kt)*512;
      Bh[n] = *(const short8*)(xh + o);
      Bm[n] = *(const short8*)(xm + o);
      Bl[n] = *(const short8*)(xl + o);
    }
    #pragma unroll
    for(int m=0;m<4;m++){
      #pragma unroll
      for(int n=0;n<2;n++){
        MFMA6(acc[m][n], Ah[m], Am[m], Al[m], Bh[n], Bm[n], Bl[n])
      }
    }
  }
  const float* xxb = xx + (size_t)b*NN;
  float xxc[2];
  #pragma unroll
  for(int n=0;n<2;n++) xxc[n] = xxb[crow0 + n*16 + lr];
  #pragma unroll
  for(int m=0;m<4;m++){
    #pragma unroll
    for(int r=0;r<4;r++){
      int qr = qrow0 + m*16 + 4*lg + r;
      float xq = xxb[qr];
      float* dp = dist + ((size_t)cz*NN + qr)*NN + crow0;
      #pragma unroll
      for(int n=0;n<2;n++) dp[n*16 + lr] = (2.f*acc[m][n][r] - xq) - xxc[n];
    }
  }
}

// Wave-cooperative top-20: max-of-16 bitonic warm start (1024 cands) + slim insertions.
__launch_bounds__(256) __global__ void sel_k(const float* __restrict__ dist, int* __restrict__ id,
                                             int b0, int nrows){
  const int w = (blockIdx.x*256 + threadIdx.x) >> 6;
  const int lane = threadIdx.x & 63;
  if(w >= nrows) return;
  const float* dr = dist + (size_t)w*NN;
  float cd0[16];
  #pragma unroll
  for(int g=0; g<4; g++){
    float4 c = *(const float4*)&dr[g*256 + 4*lane];
    cd0[g*4+0]=c.x; cd0[g*4+1]=c.y; cd0[g*4+2]=c.z; cd0[g*4+3]=c.w;
  }
  int jbest = 0; float v = cd0[0];
  #pragma unroll
  for(int j=1;j<16;j++){ if(cd0[j] > v){ v = cd0[j]; jbest = j; } }
  int vi = (jbest>>2)*256 + 4*lane + (jbest&3);
  BITONIC64_DESC(v, vi)
  float lv = (lane < KK) ? v : -INFINITY;
  int   li = (lane < KK) ? vi : 0;
  float theta = readlane_f(lv, KK-1);
  #pragma unroll
  for(int j=0;j<16;j++){
    float cand = (j == jbest) ? -INFINITY : cd0[j];
    unsigned long long bal = __ballot(cand > theta);
    while(bal){
      int bpos = __ffsll((unsigned long long)bal) - 1;
      bal &= bal - 1;
      float cv = readlane_f(cand, bpos);
      if(cv > theta){
        int ci = (j>>2)*256 + 4*bpos + (j&3);
        INSERT_CAND(cv, ci)
      }
    }
  }
  for(int ms=1024; ms<NN; ms+=256){
    float4 c4 = *(const float4*)&dr[ms + 4*lane];
    #pragma unroll
    for(int j=0;j<4;j++){
      float cand = (j==0)?c4.x:(j==1)?c4.y:(j==2)?c4.z:c4.w;
      unsigned long long bal = __ballot(cand > theta);
      while(bal){
        int bpos = __ffsll((unsigned long long)bal) - 1;
        bal &= bal - 1;
        float cv = readlane_f(cand, bpos);
        if(cv > theta){
          int ci = ms + 4*bpos + j;
          INSERT_CAND(cv, ci)
        }
      }
    }
  }
  if(lane < KK) id[((size_t)b0*NN + w)*KK + lane] = li;
}

// L1 fused: inline C=3 distances + inline sqnorm, max-of-16 bitonic warm start.
__launch_bounds__(256) __global__ void sel3_k(const float* __restrict__ X, int* __restrict__ id){
  const int gw = (blockIdx.x*256 + threadIdx.x) >> 6;
  const int lane = threadIdx.x & 63;
  const int b = gw >> 11, n = gw & 2047;
  const float* Xb  = X + (size_t)b*NN*3;
  const float x0v = Xb[n*3], x1v = Xb[n*3+1], x2v = Xb[n*3+2];
  float xxn = 0.f;
  xxn = fmaf(x0v, x0v, xxn); xxn = fmaf(x1v, x1v, xxn); xxn = fmaf(x2v, x2v, xxn);
  float lv, theta; int li;
  {
    float cd[16];
    #pragma unroll
    for(int g=0; g<4; g++){
      const float* p = Xb + (size_t)(g*256 + 4*lane)*3;
      float4 va = *(const float4*)p;
      float4 vb = *(const float4*)(p+4);
      float4 vc = *(const float4*)(p+8);
      float cx[4] = {va.x, va.w, vb.z, vc.y};
      float cy[4] = {va.y, vb.x, vb.w, vc.z};
      float cz[4] = {va.z, vb.y, vc.x, vc.w};
      #pragma unroll
      for(int j=0;j<4;j++){
        float s = 0.f;
        s = fmaf(x0v, cx[j], s); s = fmaf(x1v, cy[j], s); s = fmaf(x2v, cz[j], s);
        float xxm = 0.f;
        xxm = fmaf(cx[j], cx[j], xxm); xxm = fmaf(cy[j], cy[j], xxm); xxm = fmaf(cz[j], cz[j], xxm);
        cd[g*4 + j] = (2.f*s - xxn) - xxm;
      }
    }
    int jbest = 0; float v = cd[0];
    #pragma unroll
    for(int j=1;j<16;j++){ if(cd[j] > v){ v = cd[j]; jbest = j; } }
    int vi = (jbest>>2)*256 + 4*lane + (jbest&3);
    BITONIC64_DESC(v, vi)
    lv = (lane < KK) ? v : -INFINITY;
    li = (lane < KK) ? vi : 0;
    theta = readlane_f(lv, KK-1);
    #pragma unroll
    for(int j=0;j<16;j++){
      float cand = (j == jbest) ? -INFINITY : cd[j];
      unsigned long long bal = __ballot(cand > theta);
      while(bal){
        int bpos = __ffsll((unsigned long long)bal) - 1;
        bal &= bal - 1;
        float cv = readlane_f(cand, bpos);
        if(cv > theta){
          int ci = (j>>2)*256 + 4*bpos + (j&3);
          INSERT_CAND(cv, ci)
        }
      }
    }
  }
  for(int ms=1024; ms<NN; ms+=256){
    const float* p = Xb + (size_t)(ms + 4*lane)*3;
    float4 va = *(const float4*)p;
    float4 vb = *(const float4*)(p+4);
    float4 vc = *(const float4*)(p+8);
    float cx[4] = {va.x, va.w, vb.z, vc.y};
    float cy[4] = {va.y, vb.x, vb.w, vc.z};
    float cz[4] = {va.z, vb.y, vc.x, vc.w};
    float cd[4];
    #pragma unroll
    for(int j=0;j<4;j++){
      float s = 0.f;
      s = fmaf(x0v, cx[j], s); s = fmaf(x1v, cy[j], s); s = fmaf(x2v, cz[j], s);
      float xxm = 0.f;
      xxm = fmaf(cx[j], cx[j], xxm); xxm = fmaf(cy[j], cy[j], xxm); xxm = fmaf(cz[j], cz[j], xxm);
      cd[j] = (2.f*s - xxn) - xxm;
    }
    #pragma unroll
    for(int j=0;j<4;j++){
      float cand = cd[j];
      unsigned long long bal = __ballot(cand > theta);
      while(bal){
        int bpos = __ffsll((unsigned long long)bal) - 1;
        bal &= bal - 1;
        float cv = readlane_f(cand, bpos);
        if(cv > theta){
          int ci = ms + 4*bpos + j;
          INSERT_CAND(cv, ci)
        }
      }
    }
  }
  if(lane < KK) id[(size_t)gw*KK + lane] = li;
}

// ---------------- qp ----------------
// L1: writes interleaved qp[row][128]: q at 0..63, p at 64..127
__launch_bounds__(256) __global__ void qp3_k(const float* X, const float* W, float* qp){
  const int t   = blockIdx.x*256 + threadIdx.x;
  const int row = t >> 3;
  const int c0  = (t & 7) * 8;
  float xn[3];
  #pragma unroll
  for(int c=0;c<3;c++) xn[c] = X[(size_t)row*3 + c];
  for(int oi=c0; oi<c0+8; oi++){
    const float* w = W + (size_t)oi*6;
    float aq=0.f, ap=0.f;
    #pragma unroll
    for(int c=0;c<3;c++){ aq = fmaf(xn[c], w[c], aq); ap = fmaf(xn[c], w[3+c], ap); }
    qp[(size_t)row*128 + oi]      = aq;
    qp[(size_t)row*128 + 64 + oi] = ap;
  }
}

// qp via split-bf16 MFMA: qp[BN][W2C] = Xsplit * WTsplit.
// FULL=true: 6-product (KNN-critical layers 2/3). FULL=false: 3-product (terminal layer 4).
// Grid (BN/128, W2C/64); block 128r x 64c; wave 64r x 32c.
template<int KT, int W2C, bool FULL>
__launch_bounds__(256) __global__ void qp_mfma_k(const u16* __restrict__ xh, const u16* __restrict__ xm,
    const u16* __restrict__ xl,
    const u16* __restrict__ wh, const u16* __restrict__ wm, const u16* __restrict__ wl,
    float* __restrict__ qp){
  const int tid = threadIdx.x;
  const int l  = tid & 63, wv = tid >> 6;
  const int lg = l >> 4, lr = l & 15;
  const int row0 = blockIdx.x*128 + (wv>>1)*64;
  const int col0 = blockIdx.y*64 + (wv&1)*32;
  f32x4 acc[4][2];
  #pragma unroll
  for(int m=0;m<4;m++){
    #pragma unroll
    for(int n=0;n<2;n++) acc[m][n] = (f32x4){0.f,0.f,0.f,0.f};
  }
  const size_t abase = (size_t)(row0>>4)*KT*512 + (size_t)l*8;
  const size_t bbase = (size_t)(col0>>4)*KT*512 + (size_t)l*8;
  for(int kt=0; kt<KT; kt++){
    short8 Ah[4], Am[4], Al[4], Bh[2], Bm[2], Bl[2];
    #pragma unroll
    for(int m=0;m<4;m++){
      size_t o = abase + (size_t)(m*KT + kt)*512;
      Ah[m] = *(const short8*)(xh + o);
      Am[m] = *(const short8*)(xm + o);
      if constexpr (FULL) Al[m] = *(const short8*)(xl + o);
    }
    #pragma unroll
    for(int n=0;n<2;n++){
      size_t o = bbase + (size_t)(n*KT + kt)*512;
      Bh[n] = *(const short8*)(wh + o);
      Bm[n] = *(const short8*)(wm + o);
      if constexpr (FULL) Bl[n] = *(const short8*)(wl + o);
    }
    #pragma unroll
    for(int m=0;m<4;m++){
      #pragma unroll
      for(int n=0;n<2;n++){
        if constexpr (FULL) {
          MFMA6(acc[m][n], Ah[m], Am[m], Al[m], Bh[n], Bm[n], Bl[n])
        } else {
          MFMA3(acc[m][n], Ah[m], Am[m], Bh[n], Bm[n])
        }
      }
    }
  }
  #pragma unroll
  for(int m=0;m<4;m++){
    #pragma unroll
    for(int r=0;r<4;r++){
      int row = row0 + m*16 + 4*lg + r;
      float* dp = qp + (size_t)row*W2C + col0;
      #pragma unroll
      for(int n=0;n<2;n++) dp[n*16 + lr] = acc[m][n][r];
    }
  }
}

// Gather from interleaved qp[row][2*COUT] (q | p); base = p - q computed here.
template<int COUT>
__launch_bounds__(256) __global__ void gather_qp_k(const float* __restrict__ qp, const int* __restrict__ idx,
    const float* g, const float* bb, float* out){
  const int t  = blockIdx.x*256 + threadIdx.x;   // BN*COUT
  const int o  = t % COUT;
  const int bn = t / COUT;
  const int b  = bn >> 11;
  const int* id = idx + (size_t)bn*KK;
  float qv = qp[(size_t)bn*(2*COUT) + o];
  float pv = qp[(size_t)bn*(2*COUT) + COUT + o];
  float base = pv - qv;
  float mx = -INFINITY, mn = INFINITY;
  #pragma unroll
  for(int k=0;k<KK;k++){
    int ik = id[k];
    float v = qp[((size_t)((b<<11) + ik))*(2*COUT) + o];
    mx = fmaxf(mx, v); mn = fminf(mn, v);
  }
  float a  = g[o] * RSQ;
  float bo = bb[o];
  out[(size_t)bn*COUT + o] = lrelu((a >= 0.f ? a*(mx+base) : a*(mn+base)) + bo);
}

// ---- fallback chunked qp (cat weight layout) + chunked gather ----
template<int CIN, int COUT>
__launch_bounds__(256) __global__ void qp64T_k(const float* __restrict__ X, const float* __restrict__ WT,
                                               int cb, float* __restrict__ q, float* __restrict__ bs){
  const int t   = blockIdx.x*256 + threadIdx.x;
  const int row = t >> 3;
  const int o0  = cb + (t & 7) * 8;
  float xn[CIN];
  #pragma unroll
  for(int c=0;c<CIN;c+=4){ float4 v = *(const float4*)(X + (size_t)row*CIN + c);
    xn[c]=v.x; xn[c+1]=v.y; xn[c+2]=v.z; xn[c+3]=v.w; }
  float aq[8], ap[8];
  #pragma unroll
  for(int j=0;j<8;j++){ aq[j]=0.f; ap[j]=0.f; }
  #pragma unroll 4
  for(int c=0;c<CIN;c++){
    float xc = xn[c];
    float4 wa0 = *(const float4*)&WT[(size_t)c*(2*COUT) + o0];
    float4 wa1 = *(const float4*)&WT[(size_t)c*(2*COUT) + o0 + 4];
    float4 wb0 = *(const float4*)&WT[(size_t)c*(2*COUT) + COUT + o0];
    float4 wb1 = *(const float4*)&WT[(size_t)c*(2*COUT) + COUT + o0 + 4];
    aq[0]=fmaf(xc,wa0.x,aq[0]); aq[1]=fmaf(xc,wa0.y,aq[1]); aq[2]=fmaf(xc,wa0.z,aq[2]); aq[3]=fmaf(xc,wa0.w,aq[3]);
    aq[4]=fmaf(xc,wa1.x,aq[4]); aq[5]=fmaf(xc,wa1.y,aq[5]); aq[6]=fmaf(xc,wa1.z,aq[6]); aq[7]=fmaf(xc,wa1.w,aq[7]);
    ap[0]=fmaf(xc,wb0.x,ap[0]); ap[1]=fmaf(xc,wb0.y,ap[1]); ap[2]=fmaf(xc,wb0.z,ap[2]); ap[3]=fmaf(xc,wb0.w,ap[3]);
    ap[4]=fmaf(xc,wb1.x,ap[4]); ap[5]=fmaf(xc,wb1.y,ap[5]); ap[6]=fmaf(xc,wb1.z,ap[6]); ap[7]=fmaf(xc,wb1.w,ap[7]);
  }
  float* qpp = q  + (size_t)row*64 + (o0-cb);
  float* bpp = bs + (size_t)row*64 + (o0-cb);
  *(float4*)qpp     = make_float4(aq[0],aq[1],aq[2],aq[3]);
  *(float4*)(qpp+4) = make_float4(aq[4],aq[5],aq[6],aq[7]);
  *(float4*)bpp     = make_float4(ap[0]-aq[0],ap[1]-aq[1],ap[2]-aq[2],ap[3]-aq[3]);
  *(float4*)(bpp+4) = make_float4(ap[4]-aq[4],ap[5]-aq[5],ap[6]-aq[6],ap[7]-aq[7]);
}

template<int CFULL>
__launch_bounds__(256) __global__ void gather_chunk_k(const float* q, const float* bs, const int* idx,
    const float* g, const float* bb, int cb, float* out){
  const int t  = blockIdx.x*256 + threadIdx.x;
  const int o  = t & 63;
  const int bn = t >> 6;
  const int b  = bn >> 11;
  const int* id = idx + (size_t)bn*KK;
  float base = bs[t];
  float mx = -INFINITY, mn = INFINITY;
  #pragma unroll
  for(int k=0;k<KK;k++){
    int ik = id[k];
    float v = q[((size_t)((b<<11) + ik))*64 + o];
    mx = fmaxf(mx, v); mn = fminf(mn, v);
  }
  float a  = g[cb+o] * RSQ;
  float bo = bb[cb+o];
  out[(size_t)bn*CFULL + cb + o] = lrelu((a >= 0.f ? a*(mx+base) : a*(mn+base)) + bo);
}

// ---------------- head (fallback): fp32 GEMM-tiled cat x W5T with fused max/min ----------------
__launch_bounds__(256) __global__ void w5gemm_k(const float* __restrict__ x1, const float* __restrict__ x2,
    const float* __restrict__ x3, const float* __restrict__ x4,
    const float* __restrict__ W5T, unsigned* mxe, unsigned* mne){
  constexpr int ASTA = 92;
  constexpr int ASTB = 188;
  __shared__ __align__(16) float a_sh[16*ASTA];
  __shared__ __align__(16) float b_sh[16*ASTB];
  const int tid = threadIdx.x;
  const int otile = blockIdx.x*128;
  const int rtile = blockIdx.y*64;
  const int b     = blockIdx.z;
  const int tn = tid & 15, tm = tid >> 4;
  const int aoff = 4*tn + 4*(tn>>1);
  const size_t row0 = (size_t)b*NN + rtile;
  float acc[4][8];
  #pragma unroll
  for(int i=0;i<4;i++){
    #pragma unroll
    for(int j=0;j<8;j++) acc[i][j]=0.f;
  }
  for(int cc=0; cc<512; cc+=16){
    const float* src; int stride, coff;
    if(cc<64)      { src=x1; stride=64;  coff=cc; }
    else if(cc<128){ src=x2; stride=64;  coff=cc-64; }
    else if(cc<256){ src=x3; stride=128; coff=cc-128; }
    else           { src=x4; stride=256; coff=cc-256; }
    __syncthreads();
    { int r = tid>>2, q = tid&3;
      int pr = r + 4*(r>>3);
      float4 va = *(const float4*)&src[(row0 + r)*stride + coff + 4*q];
      a_sh[(4*q+0)*ASTA + pr]=va.x; a_sh[(4*q+1)*ASTA + pr]=va.y;
      a_sh[(4*q+2)*ASTA + pr]=va.z; a_sh[(4*q+3)*ASTA + pr]=va.w; }
    #pragma unroll
    for(int s=0;s<2;s++){
      int ii = tid + 256*s;
      int cl = ii>>5, o4 = ii&31;
      float4 vb = *(const float4*)&W5T[(size_t)(cc+cl)*512 + otile + 4*o4];
      *(float4*)&b_sh[cl*ASTB + 4*o4 + 4*(o4>>1)] = vb;
    }
    __syncthreads();
    #pragma unroll
    for(int c=0;c<16;c++){
      float4 A0 = *(const float4*)&a_sh[c*ASTA + aoff];
      float4 B0 = *(const float4*)&b_sh[c*ASTB + 12*tm];
      float4 B1 = *(const float4*)&b_sh[c*ASTB + 12*tm + 4];
      float b0v=B0.x,b1v=B0.y,b2v=B0.z,b3v=B0.w,b4v=B1.x,b5v=B1.y,b6v=B1.z,b7v=B1.w;
      float a;
      a=A0.x; FMA_ROW(0)
      a=A0.y; FMA_ROW(1)
      a=A0.z; FMA_ROW(2)
      a=A0.w; FMA_ROW(3)
    }
  }
  #pragma unroll
  for(int j=0;j<8;j++){
    float M=-INFINITY, m=INFINITY;
    #pragma unroll
    for(int i=0;i<4;i++){ M=fmaxf(M,acc[i][j]); m=fminf(m,acc[i][j]); }
    #pragma unroll
    for(int d=1; d<16; d<<=1){
      M = fmaxf(M, __shfl_xor(M, d));
      m = fminf(m, __shfl_xor(m, d));
    }
    if(tn == 0){
      int o = otile + tm*8 + j;
      atomicMax(&mxe[b*512+o], encf(M));
      atomicMin(&mne[b*512+o], encf(m));
    }
  }
}

// ---------------- head (big): split-bf16 MFMA (3-product, terminal) ----------------
// xcat 2-split (h/m only) into fragment-major tiled layout (KT=16, row space = BN).
__launch_bounds__(256) __global__ void cvt_k(const float* __restrict__ x1, const float* __restrict__ x2,
    const float* __restrict__ x3, const float* __restrict__ x4,
    u16* __restrict__ xh, u16* __restrict__ xm){
  const size_t t = (size_t)blockIdx.x*256 + threadIdx.x;   // BN*512/8 chunks
  const int l = (int)(t & 63);
  const size_t tile = t >> 6;           // rgG*16 + kt
  const int kt = (int)(tile & 15);
  const size_t rgG = tile >> 4;
  const size_t row = rgG*16 + (l & 15);
  const int col = kt*32 + ((l>>4)<<3);
  const float* src; int stride, coff;
  if(col<64)      { src=x1; stride=64;  coff=col; }
  else if(col<128){ src=x2; stride=64;  coff=col-64; }
  else if(col<256){ src=x3; stride=128; coff=col-128; }
  else            { src=x4; stride=256; coff=col-256; }
  const float* p = src + row*stride + coff;
  float4 v0 = *(const float4*)p;
  float4 v1 = *(const float4*)(p+4);
  float vs[8] = {v0.x,v0.y,v0.z,v0.w,v1.x,v1.y,v1.z,v1.w};
  ushort8 H, M;
  #pragma unroll
  for(int j=0;j<8;j++){ u16 h,m,lo; bf16split3(vs[j],h,m,lo); H[j]=h; M[j]=m; (void)lo; }
  *(ushort8*)(xh + t*8) = H;
  *(ushort8*)(xm + t*8) = M;
}

// C[16384x512] = xcat * W5^T via 3 bf16 MFMA products (hh+hm+mh, terminal-GEMM precision),
// fused per-column max/min. 64-col tiles: grid (128 rowblk, 8 colblk); A-sharing blocks
// 128 apart -> same XCD L2.
__launch_bounds__(256) __global__ void w5mfma_k(const u16* __restrict__ xh, const u16* __restrict__ xm,
    const u16* __restrict__ wh, const u16* __restrict__ wm,
    unsigned* mxe, unsigned* mne){
  const int tid = threadIdx.x;
  const int l  = tid & 63, wv = tid >> 6;
  const int lg = l >> 4, lr = l & 15;
  const int row0 = blockIdx.x*128 + (wv>>1)*64;   // M base of this wave (global BN rows)
  const int col0 = blockIdx.y*64 + (wv&1)*32;     // N base of this wave
  const int b = blockIdx.x >> 4;                  // 16 M-blocks per batch
  f32x4 acc[4][2];
  #pragma unroll
  for(int m=0;m<4;m++){
    #pragma unroll
    for(int n=0;n<2;n++) acc[m][n] = (f32x4){0.f,0.f,0.f,0.f};
  }
  const size_t abase = (size_t)(row0>>4)*16*512 + (size_t)l*8;
  const size_t bbase = (size_t)(col0>>4)*16*512 + (size_t)l*8;
  for(int kt=0; kt<16; kt++){
    short8 Ah[4], Am[4], Bh[2], Bm[2];
    #pragma unroll
    for(int m=0;m<4;m++){
      size_t o = abase + (size_t)(m*16 + kt)*512;
      Ah[m] = *(const short8*)(xh + o);
      Am[m] = *(const short8*)(xm + o);
    }
    #pragma unroll
    for(int n=0;n<2;n++){
      size_t o = bbase + (size_t)(n*16 + kt)*512;
      Bh[n] = *(const short8*)(wh + o);
      Bm[n] = *(const short8*)(wm + o);
    }
    #pragma unroll
    for(int m=0;m<4;m++){
      #pragma unroll
      for(int n=0;n<2;n++){
        MFMA3(acc[m][n], Ah[m], Am[m], Bh[n], Bm[n])
      }
    }
  }
  #pragma unroll
  for(int n=0;n<2;n++){
    float M = -INFINITY, mnv = INFINITY;
    #pragma unroll
    for(int m=0;m<4;m++){
      #pragma unroll
      for(int r=0;r<4;r++){ float v = acc[m][n][r]; M = fmaxf(M, v); mnv = fminf(mnv, v); }
    }
    M   = fmaxf(M,   __shfl_xor(M, 16));   M   = fmaxf(M,   __shfl_xor(M, 32));
    mnv = fminf(mnv, __shfl_xor(mnv, 16)); mnv = fminf(mnv, __shfl_xor(mnv, 32));
    if(lg == 0){
      int o = col0 + n*16 + lr;
      atomicMax(&mxe[b*512+o], encf(M));
      atomicMin(&mne[b*512+o], encf(mnv));
    }
  }
}

__launch_bounds__(256) __global__ void final_k(const unsigned* mxe, const unsigned* mne,
    const float* g5, const float* b5, const float* Wemb, float* out){
  const int b = blockIdx.x, t = threadIdx.x;
  __shared__ float h[512];
  for(int o=t; o<512; o+=256){
    float mx = decf(mxe[b*512+o]);
    float mn = decf(mne[b*512+o]);
    float a  = g5[o] * RSQ;
    float bo = b5[o];
    float hv = lrelu((a >= 0.f ? a*mx : a*mn) + bo);
    h[o] = hv;
    out[b*512+o] = hv;
  }
  __syncthreads();
  const float* wr = Wemb + (size_t)t*512;
  float s = 0.f;
  for(int o=0;o<512;o+=4){
    float4 w4 = *(const float4*)(wr+o);
    s = fmaf(h[o],w4.x, fmaf(h[o+1],w4.y, fmaf(h[o+2],w4.z, fmaf(h[o+3],w4.w, s))));
  }
  out[4096 + b*256 + t] = s;
}

// ---------------- launch ----------------
extern "C" void kernel_launch(void* const* d_in, const int* in_sizes, int n_in,
                              void* d_out, int out_size, void* d_ws, size_t ws_size,
                              hipStream_t stream) {
  if (ws_size < WS_END * sizeof(float)) return;
  const bool big = ws_size >= WS_BIG_END * sizeof(float);   // deterministic per call

  const float* x0   = (const float*)d_in[0];
  const float* W1   = (const float*)d_in[1];
  const float* g1   = (const float*)d_in[2];
  const float* b1   = (const float*)d_in[3];
  const float* W2   = (const float*)d_in[4];
  const float* g2   = (const float*)d_in[5];
  const float* b2   = (const float*)d_in[6];
  const float* W3   = (const float*)d_in[7];
  const float* g3   = (const float*)d_in[8];
  const float* b3   = (const float*)d_in[9];
  const float* W4   = (const float*)d_in[10];
  const float* g4   = (const float*)d_in[11];
  const float* b4   = (const float*)d_in[12];
  const float* W5   = (const float*)d_in[13];
  const float* g5   = (const float*)d_in[14];
  const float* b5   = (const float*)d_in[15];
  const float* Wemb = (const float*)d_in[16];

  float* ws = (float*)d_ws;
  float* xx = ws + OFF_XX;
  float* x1 = ws + OFF_X1;  float* x2 = ws + OFF_X2;
  float* x3 = ws + OFF_X3;  float* x4 = ws + OFF_X4;
  float* qpS = ws + OFF_SC;               // L1 qp (width 128) + fallback chunked q/bs
  float* bsS = ws + OFF_SC + (size_t)BN*64;
  int*   id = (int*)(ws + OFF_ID);
  float* W5Tf = ws + OFF_W5T;
  unsigned* mxe = (unsigned*)(ws + OFF_MX);
  unsigned* mne = (unsigned*)(ws + OFF_MN);
  float* WT2 = ws + OFF_WT2;
  float* WT3 = ws + OFF_WT3;
  float* WT4 = ws + OFF_WT4;
  float* distD = ws + OFF_X3;   // fallback dual-batch
  float* distS = ws + OFF_X4;   // fallback single-batch
  float* distB = ws + OFF_BIG;  // big: 4-batch dist chunk, then reused as qp buffer / bf16 xcat
  u16* w5h = (u16*)(ws + OFF_SC + (size_t)BN*128);   // SC tail (free in both paths): 3x256KB
  u16* w5m = w5h + 512*512;
  u16* w5l = w5m + 512*512;
  u16* wts = (u16*)W5Tf;         // big path: tiled WT splits live in the (unused) W5T region
  float* out = (float*)d_out;

  prep_k<<<1024,256,0,stream>>>(W5, W2, W3, W4, W5Tf, WT2, WT3, WT4,
                                w5h, w5m, w5l, wts, mxe, mne, big ? 1 : 0);

  // layer 1 (3 -> 64)
  sel3_k<<<BN*64/256,256,0,stream>>>(x0, id);
  qp3_k<<<BN*8/256,256,0,stream>>>(x0, W1, qpS);
  gather_qp_k<64><<<BN*64/256,256,0,stream>>>(qpS, id, g1, b1, x1);

  if(big){
    float* qpB = distB;                      // reuse dist region post-sel
    // split scratch lives in x4 region (dead until layer-4 gather)
    u16* sh = (u16*)x4;
    // layer 2 (CIN=64 -> COUT=64, qp width 128)
    { u16* sm = sh + (size_t)BN*64; u16* sl = sm + (size_t)BN*64;
      sqnorm_k<64><<<BN/256,256,0,stream>>>(x1, xx);
      split_k<64><<<BN*64/8/256,256,0,stream>>>(x1, sh, sm, sl);
      for(int c0=0;c0<BB;c0+=4){
        mfma_dist_k<64><<<dim3(32,16,4),256,0,stream>>>(sh, sm, sl, xx, distB, c0);
        sel_k<<<(4*NN)/4,256,0,stream>>>(distB, id, c0, 4*NN);
      }
      qp_mfma_k<2,128,true><<<dim3(BN/128,2),256,0,stream>>>(sh, sm, sl,
          wts+WTS_2H, wts+WTS_2M, wts+WTS_2L, qpB);
      gather_qp_k<64><<<BN*64/256,256,0,stream>>>(qpB, id, g2, b2, x2); }
    // layer 3 (64 -> 128, qp width 256)
    { u16* sm = sh + (size_t)BN*64; u16* sl = sm + (size_t)BN*64;
      sqnorm_k<64><<<BN/256,256,0,stream>>>(x2, xx);
      split_k<64><<<BN*64/8/256,256,0,stream>>>(x2, sh, sm, sl);
      for(int c0=0;c0<BB;c0+=4){
        mfma_dist_k<64><<<dim3(32,16,4),256,0,stream>>>(sh, sm, sl, xx, distB, c0);
        sel_k<<<(4*NN)/4,256,0,stream>>>(distB, id, c0, 4*NN);
      }
      qp_mfma_k<2,256,true><<<dim3(BN/128,4),256,0,stream>>>(sh, sm, sl,
          wts+WTS_3H, wts+WTS_3M, wts+WTS_3L, qpB);
      gather_qp_k<128><<<BN*128/256,256,0,stream>>>(qpB, id, g3, b3, x3); }
    // layer 4 (128 -> 256, qp width 512): terminal for KNN -> 3-product qp
    { u16* sm = sh + (size_t)BN*128; u16* sl = sm + (size_t)BN*128;
      sqnorm_k<128><<<BN/256,256,0,stream>>>(x3, xx);
      split_k<128><<<BN*128/8/256,256,0,stream>>>(x3, sh, sm, sl);
      for(int c0=0;c0<BB;c0+=4){
        mfma_dist_k<128><<<dim3(32,16,4),256,0,stream>>>(sh, sm, sl, xx, distB, c0);
        sel_k<<<(4*NN)/4,256,0,stream>>>(distB, id, c0, 4*NN);
      }
      qp_mfma_k<4,512,false><<<dim3(BN/128,8),256,0,stream>>>(sh, sm, sl,
          wts+WTS_4H, wts+WTS_4M, wts+WTS_4L, qpB);
      gather_qp_k<256><<<BN*256/256,256,0,stream>>>(qpB, id, g4, b4, x4); }
    // head: bf16 2-split (tiled) + 3-product MFMA (terminal-GEMM precision)
    u16* xh = (u16*)(ws + OFF_XCAT);
    u16* xm = xh + (size_t)BN*512;
    cvt_k<<<BN*512/8/256,256,0,stream>>>(x1, x2, x3, x4, xh, xm);
    w5mfma_k<<<dim3(128,8),256,0,stream>>>(xh, xm, w5h, w5m, mxe, mne);
  } else {
    // fallback: chunked (R12 structure, cat weight layout)
    sqnorm_k<64><<<BN/256,256,0,stream>>>(x1, xx);
    for(int r=0;r<4;r++){
      gemm_dist_k<64><<<dim3(16,16,2),256,0,stream>>>(x1, xx, distD, 2*r);
      sel_k<<<(2*NN)/4,256,0,stream>>>(distD, id, 2*r, 2*NN);
    }
    qp64T_k<64,64><<<BN*8/256,256,0,stream>>>(x1, WT2, 0, qpS, bsS);
    gather_chunk_k<64><<<BN*64/256,256,0,stream>>>(qpS, bsS, id, g2, b2, 0, x2);

    sqnorm_k<64><<<BN/256,256,0,stream>>>(x2, xx);
    for(int r=0;r<4;r++){
      gemm_dist_k<64><<<dim3(16,16,2),256,0,stream>>>(x2, xx, distD, 2*r);
      sel_k<<<(2*NN)/4,256,0,stream>>>(distD, id, 2*r, 2*NN);
    }
    for(int cb=0; cb<128; cb+=64){
      qp64T_k<64,128><<<BN*8/256,256,0,stream>>>(x2, WT3, cb, qpS, bsS);
      gather_chunk_k<128><<<BN*64/256,256,0,stream>>>(qpS, bsS, id, g3, b3, cb, x3);
    }

    sqnorm_k<128><<<BN/256,256,0,stream>>>(x3, xx);
    for(int r=0;r<8;r++){
      gemm_dist_k<128><<<dim3(16,16,1),256,0,stream>>>(x3, xx, distS, r);
      sel_k<<<NN/4,256,0,stream>>>(distS, id, r, NN);
    }
    for(int cb=0; cb<256; cb+=64){
      qp64T_k<128,256><<<BN*8/256,256,0,stream>>>(x3, WT4, cb, qpS, bsS);
      gather_chunk_k<256><<<BN*64/256,256,0,stream>>>(qpS, bsS, id, g4, b4, cb, x4);
    }
    w5gemm_k<<<dim3(4,32,8),256,0,stream>>>(x1, x2, x3, x4, W5Tf, mxe, mne);
  }

  final_k<<<BB,256,0,stream>>>(mxe, mne, g5, b5, Wemb, out);
}

// Round 18
// 502.246 us; speedup vs baseline: 1.2626x; 1.0314x over previous
//
#include <hip/hip_runtime.h>
#include <hip/hip_bf16.h>

#define BB 8
#define NN 2048
#define KK 20
#define BN (BB*NN)
#define RSQ 0.99999500003749969f   // 1/sqrt(1+1e-5)

// ---------------- workspace layout (float-slot units) ----------------
constexpr size_t OFF_XX  = 0;                          // BN
constexpr size_t OFF_X1  = OFF_XX  + BN;               // BN*64
constexpr size_t OFF_X2  = OFF_X1  + (size_t)BN*64;    // BN*64
constexpr size_t OFF_X3  = OFF_X2  + (size_t)BN*64;    // BN*128
constexpr size_t OFF_X4  = OFF_X3  + (size_t)BN*128;   // BN*256 (split-scratch pre-gather)
constexpr size_t OFF_SC  = OFF_X4  + (size_t)BN*256;   // BN*160 (L1 qp + fallback chunked qp + W5 bf16 tail)
constexpr size_t OFF_ID  = OFF_SC  + (size_t)BN*160;   // int BN*20
constexpr size_t OFF_W5T = OFF_ID  + (size_t)BN*20;    // 512*512 (big path: tiled WT splits live here)
constexpr size_t OFF_MX  = OFF_W5T + 512*512;
constexpr size_t OFF_MN  = OFF_MX  + BB*512;
constexpr size_t OFF_WT2 = OFF_MN  + BB*512;           // cat [64][128]
constexpr size_t OFF_WT3 = OFF_WT2 + 8192;             // cat [64][256]
constexpr size_t OFF_WT4 = OFF_WT3 + 16384;            // cat [128][512]
constexpr size_t WS_END  = OFF_WT4 + 65536;            // 11,714,560 floats
// big region (probed at runtime): dist chunk (4 batches) + qp buffer + bf16 xcat post-sel
constexpr size_t OFF_BIG = WS_END;
constexpr size_t OFF_XCAT = OFF_BIG + (size_t)16*1024*1024;  // bf16 xcat h/m (dist region tail, post-KNN)
constexpr size_t WS_BIG_END = OFF_BIG + (size_t)BB*NN*NN;   // 172.7 MiB
static_assert(OFF_ID - OFF_X3 >= (size_t)4096*2048, "fallback dual dist fits");
static_assert(OFF_XCAT + (size_t)BN*512 <= WS_BIG_END, "xcat h/m fits in dist region");

typedef unsigned short u16;
typedef __attribute__((ext_vector_type(8))) short short8;
typedef __attribute__((ext_vector_type(8))) unsigned short ushort8;
typedef __attribute__((ext_vector_type(4))) float f32x4;

// tiled WT split offsets (u16 units) within the W5T region (big path only)
constexpr size_t WTS_2H = 0,      WTS_2M = 8192,   WTS_2L = 16384;
constexpr size_t WTS_3H = 24576,  WTS_3M = 40960,  WTS_3L = 57344;
constexpr size_t WTS_4H = 73728,  WTS_4M = 139264, WTS_4L = 204800;   // end 270336 u16 <= 524288

__device__ inline unsigned encf(float f){ unsigned u=__float_as_uint(f); return (u&0x80000000u)? ~u : (u|0x80000000u); }
__device__ inline float decf(unsigned e){ unsigned u=(e&0x80000000u)? (e&0x7fffffffu) : ~e; return __uint_as_float(u); }
__device__ inline float lrelu(float h){ return h>=0.f ? h : 0.2f*h; }
__device__ inline u16 bf16rne(float x){
  unsigned u = __float_as_uint(x);
  return (u16)((u + 0x7FFFu + ((u>>16)&1u)) >> 16);
}
__device__ inline float bf16f(u16 h){ return __uint_as_float((unsigned)h<<16); }
// exact 3-way split: x == h + m + l for normal fp32 (24 mantissa bits covered)
__device__ inline void bf16split3(float v, u16& h, u16& m, u16& l){
  h = bf16rne(v);  float r1 = v  - bf16f(h);
  m = bf16rne(r1); float r2 = r1 - bf16f(m);
  l = bf16rne(r2);
}

__device__ inline float readlane_f(float v, int sl){
  return __int_as_float(__builtin_amdgcn_readlane(__float_as_int(v), sl));
}

// Wave-cooperative sorted-top-20 insertion (cv known > theta on call).
#define INSERT_CAND(cv, ci) { \
  unsigned long long mge = __ballot((lv > cv) || (lv == cv && li < ci)); \
  int pos = __popcll(mge); \
  float upv = __shfl_up(lv, 1); \
  int   upi = __shfl_up(li, 1); \
  bool shift = (lane > pos) && (lane < KK); \
  lv = (lane == pos) ? cv : (shift ? upv : lv); \
  li = (lane == pos) ? ci : (shift ? upi : li); \
  theta = readlane_f(lv, KK-1); }

// Bitonic full sort of 64 (value desc, index asc on ties) across lanes; (v,vi) in registers.
#define BITONIC64_DESC(v, vi) { \
  _Pragma("unroll") \
  for(int k=2; k<=64; k<<=1){ \
    _Pragma("unroll") \
    for(int j=k>>1; j>=1; j>>=1){ \
      float ov = __shfl_xor(v, j); \
      int   oi = __shfl_xor(vi, j); \
      int partner = lane ^ j; \
      bool keepFirst = (((lane & k) == 0)) == (lane < partner); \
      bool before = (v > ov) || (v == ov && vi < oi); \
      if(keepFirst != before){ v = ov; vi = oi; } \
    } \
  } }

// 6-product split-bf16 MFMA macro (fp32-exact to ~2^-27): KNN-critical GEMMs.
#define MFMA6(ACC, AH, AM, AL, BH, BM, BL) { \
  ACC = __builtin_amdgcn_mfma_f32_16x16x32_bf16(AH, BH, ACC, 0, 0, 0); \
  ACC = __builtin_amdgcn_mfma_f32_16x16x32_bf16(AH, BM, ACC, 0, 0, 0); \
  ACC = __builtin_amdgcn_mfma_f32_16x16x32_bf16(AM, BH, ACC, 0, 0, 0); \
  ACC = __builtin_amdgcn_mfma_f32_16x16x32_bf16(AH, BL, ACC, 0, 0, 0); \
  ACC = __builtin_amdgcn_mfma_f32_16x16x32_bf16(AL, BH, ACC, 0, 0, 0); \
  ACC = __builtin_amdgcn_mfma_f32_16x16x32_bf16(AM, BM, ACC, 0, 0, 0); }

// 3-product variant (error ~3*2^-18 relative): terminal GEMMs only (head, layer-4 qp).
#define MFMA3(ACC, AH, AM, BH, BM) { \
  ACC = __builtin_amdgcn_mfma_f32_16x16x32_bf16(AH, BH, ACC, 0, 0, 0); \
  ACC = __builtin_amdgcn_mfma_f32_16x16x32_bf16(AH, BM, ACC, 0, 0, 0); \
  ACC = __builtin_amdgcn_mfma_f32_16x16x32_bf16(AM, BH, ACC, 0, 0, 0); }

// ======== fragment-major tiled split layout ========
// split[rowGroup][kTile][lane=64][8]  (u16). lane l -> row = rg*16 + (l&15), k = kt*32 + (l>>4)*8.

// ---------------- prep: weights transposes + splits + enc ----------------
__global__ void prep_k(const float* W5, const float* W2, const float* W3, const float* W4,
                       float* W5T, float* WT2, float* WT3, float* WT4,
                       u16* w5h, u16* w5m, u16* w5l, u16* wts,
                       unsigned* mx, unsigned* mn, int big){
  int i = blockIdx.x*256 + threadIdx.x;     // 262144
  if(!big){ int o = i>>9, c = i&511; W5T[c*512+o] = W5[i]; }   // fp32 W5T only for fallback
  { // tiled split of W5 (B-side rows = output cols o, k = input c). KT=16.
    int rg = i>>13, kt = (i>>9)&15, l = (i>>3)&63, j = i&7;
    int o = rg*16 + (l&15);
    int c = kt*32 + ((l>>4)<<3) + j;
    u16 h,m,lo; bf16split3(W5[(size_t)o*512 + c], h, m, lo);
    w5h[i]=h; w5m[i]=m; w5l[i]=lo; }
  if(i < 65536){ int c = i>>9, o = i&511;   // W4: [256][256] -> cat [128][512]
    WT4[i] = (o<256) ? W4[(size_t)o*256 + c] : W4[(size_t)(o-256)*256 + 128 + c]; }
  if(i < 16384){ int c = i>>8, o = i&255;   // W3: [128][128] -> cat [64][256]
    WT3[i] = (o<128) ? W3[(size_t)o*128 + c] : W3[(size_t)(o-128)*128 + 64 + c]; }
  if(i <  8192){ int c = i>>7, o = i&127;   // W2: [64][128] -> cat [64][128]
    WT2[i] = (o<64) ? W2[(size_t)o*128 + c] : W2[(size_t)(o-64)*128 + 64 + c]; }
  if(big){
    if(i < 65536){ // WT4 tiled split: rg over o (32), kt over c (4)
      int rg=i>>11, kt=(i>>9)&3, l=(i>>3)&63, j=i&7;
      int o = rg*16 + (l&15);
      int c = kt*32 + ((l>>4)<<3) + j;
      float v = (o<256) ? W4[(size_t)o*256 + c] : W4[(size_t)(o-256)*256 + 128 + c];
      u16 h,m,lo; bf16split3(v,h,m,lo);
      wts[WTS_4H+i]=h; wts[WTS_4M+i]=m; wts[WTS_4L+i]=lo; }
    if(i < 16384){ // WT3 tiled split: rg over o (16), kt over c (2)
      int rg=i>>10, kt=(i>>9)&1, l=(i>>3)&63, j=i&7;
      int o = rg*16 + (l&15);
      int c = kt*32 + ((l>>4)<<3) + j;
      float v = (o<128) ? W3[(size_t)o*128 + c] : W3[(size_t)(o-128)*128 + 64 + c];
      u16 h,m,lo; bf16split3(v,h,m,lo);
      wts[WTS_3H+i]=h; wts[WTS_3M+i]=m; wts[WTS_3L+i]=lo; }
    if(i < 8192){  // WT2 tiled split: rg over o (8), kt over c (2)
      int rg=i>>10, kt=(i>>9)&1, l=(i>>3)&63, j=i&7;
      int o = rg*16 + (l&15);
      int c = kt*32 + ((l>>4)<<3) + j;
      float v = (o<64) ? W2[(size_t)o*128 + c] : W2[(size_t)(o-64)*128 + 64 + c];
      u16 h,m,lo; bf16split3(v,h,m,lo);
      wts[WTS_2H+i]=h; wts[WTS_2M+i]=m; wts[WTS_2L+i]=lo; }
  }
  if(i <  4096){ mx[i] = 0x007FFFFFu; mn[i] = 0xFF800000u; }
}

// ---------------- KNN ----------------
template<int C>
__launch_bounds__(256) __global__ void sqnorm_k(const float* X, float* xx){
  int i = blockIdx.x*256 + threadIdx.x;   // BN
  const float* r = X + (size_t)i*C;
  float s = 0.f;
  #pragma unroll
  for(int c=0;c<C;c++) s = fmaf(r[c], r[c], s);
  xx[i] = s;
}

// 3-way bf16 split of X [BN][C] into fragment-major tiled layout.
template<int C>
__launch_bounds__(256) __global__ void split_k(const float* __restrict__ X,
    u16* __restrict__ xh, u16* __restrict__ xm, u16* __restrict__ xl){
  constexpr int KT = C/32;
  const size_t t = (size_t)blockIdx.x*256 + threadIdx.x;   // BN*C/8 chunks
  const int l = (int)(t & 63);
  const size_t tile = t >> 6;               // rgG*KT + kt
  const int kt = (int)(tile & (KT-1));
  const size_t rgG = tile / KT;             // global row group (BN/16 total)
  const size_t row = rgG*16 + (l & 15);
  const int k = kt*32 + ((l>>4)<<3);
  const float* p = X + row*C + k;
  float4 v0 = *(const float4*)p;
  float4 v1 = *(const float4*)(p+4);
  float vs[8] = {v0.x,v0.y,v0.z,v0.w,v1.x,v1.y,v1.z,v1.w};
  ushort8 H,M,L;
  #pragma unroll
  for(int j=0;j<8;j++){ u16 h,m,lo; bf16split3(vs[j],h,m,lo); H[j]=h; M[j]=m; L[j]=lo; }
  *(ushort8*)(xh + t*8) = H;
  *(ushort8*)(xm + t*8) = M;
  *(ushort8*)(xl + t*8) = L;
}

#define FMA_ROW(I) \
  acc[I][0]=fmaf(a,b0v,acc[I][0]); acc[I][1]=fmaf(a,b1v,acc[I][1]); \
  acc[I][2]=fmaf(a,b2v,acc[I][2]); acc[I][3]=fmaf(a,b3v,acc[I][3]); \
  acc[I][4]=fmaf(a,b4v,acc[I][4]); acc[I][5]=fmaf(a,b5v,acc[I][5]); \
  acc[I][6]=fmaf(a,b6v,acc[I][6]); acc[I][7]=fmaf(a,b7v,acc[I][7]);

// fallback fp32 dist GEMM
template<int C>
__launch_bounds__(256) __global__ void gemm_dist_k(const float* __restrict__ X, const float* __restrict__ xx,
                                                   float* __restrict__ dist, int b0){
  constexpr int AST = 188;
  __shared__ __align__(16) float a_sh[16*AST];
  __shared__ __align__(16) float b_sh[16*AST];
  __shared__ float sxn[128], sxm[128];
  const int tid = threadIdx.x;
  const int b   = b0 + blockIdx.z;
  const int mtile = blockIdx.x*128;
  const int ntile = blockIdx.y*128;
  const int tn = tid & 15, tm = tid >> 4;
  const float* Xb  = X  + (size_t)b*NN*C;
  const float* xxb = xx + (size_t)b*NN;
  if(tid < 128) sxn[tid] = xxb[ntile + tid];
  else          sxm[tid-128] = xxb[mtile + tid-128];
  float acc[8][8];
  #pragma unroll
  for(int i=0;i<8;i++){
    #pragma unroll
    for(int j=0;j<8;j++) acc[i][j]=0.f;
  }
  for(int cc=0; cc<C; cc+=16){
    __syncthreads();
    #pragma unroll
    for(int s=0;s<2;s++){
      int ii = tid + 256*s; int r = ii>>2, q = ii&3;
      int pr = r + 4*(r>>3);
      float4 va = *(const float4*)&Xb[(size_t)(ntile + r)*C + cc + 4*q];
      a_sh[(4*q+0)*AST + pr]=va.x; a_sh[(4*q+1)*AST + pr]=va.y;
      a_sh[(4*q+2)*AST + pr]=va.z; a_sh[(4*q+3)*AST + pr]=va.w;
      float4 vb = *(const float4*)&Xb[(size_t)(mtile + r)*C + cc + 4*q];
      b_sh[(4*q+0)*AST + pr]=vb.x; b_sh[(4*q+1)*AST + pr]=vb.y;
      b_sh[(4*q+2)*AST + pr]=vb.z; b_sh[(4*q+3)*AST + pr]=vb.w;
    }
    __syncthreads();
    #pragma unroll
    for(int c=0;c<16;c++){
      float4 A0 = *(const float4*)&a_sh[c*AST + 12*tn];
      float4 A1 = *(const float4*)&a_sh[c*AST + 12*tn + 4];
      float4 B0 = *(const float4*)&b_sh[c*AST + 12*tm];
      float4 B1 = *(const float4*)&b_sh[c*AST + 12*tm + 4];
      float b0v=B0.x,b1v=B0.y,b2v=B0.z,b3v=B0.w,b4v=B1.x,b5v=B1.y,b6v=B1.z,b7v=B1.w;
      float a;
      a=A0.x; FMA_ROW(0)
      a=A0.y; FMA_ROW(1)
      a=A0.z; FMA_ROW(2)
      a=A0.w; FMA_ROW(3)
      a=A1.x; FMA_ROW(4)
      a=A1.y; FMA_ROW(5)
      a=A1.z; FMA_ROW(6)
      a=A1.w; FMA_ROW(7)
    }
  }
  float xnr[8], xmr[8];
  #pragma unroll
  for(int i=0;i<8;i++){ xnr[i]=sxn[tn*8+i]; xmr[i]=sxm[tm*8+i]; }
  const size_t rowb = (size_t)blockIdx.z*NN + ntile + tn*8;
  #pragma unroll
  for(int i=0;i<8;i++){
    float4 w0, w1;
    w0.x=(2.f*acc[i][0]-xnr[i])-xmr[0]; w0.y=(2.f*acc[i][1]-xnr[i])-xmr[1];
    w0.z=(2.f*acc[i][2]-xnr[i])-xmr[2]; w0.w=(2.f*acc[i][3]-xnr[i])-xmr[3];
    w1.x=(2.f*acc[i][4]-xnr[i])-xmr[4]; w1.y=(2.f*acc[i][5]-xnr[i])-xmr[5];
    w1.z=(2.f*acc[i][6]-xnr[i])-xmr[6]; w1.w=(2.f*acc[i][7]-xnr[i])-xmr[7];
    float* dp = dist + (rowb + i)*NN + mtile + tm*8;
    *(float4*)dp = w0;
    *(float4*)(dp+4) = w1;
  }
}

// big path: exact-fp32-quality dist via split-bf16 MFMA (6 products of 3-way split).
// 64-col tiles for occupancy: grid (NN/64, 16, 4chunk); block 128q x 64c; wave 64q x 32c.
template<int C>
__launch_bounds__(256) __global__ void mfma_dist_k(const u16* __restrict__ xh, const u16* __restrict__ xm,
    const u16* __restrict__ xl, const float* __restrict__ xx, float* __restrict__ dist, int b0){
  constexpr int KT = C/32;
  const int tid = threadIdx.x;
  const int l  = tid & 63, wv = tid >> 6;
  const int lg = l >> 4, lr = l & 15;
  const int cz = blockIdx.z;
  const int b  = b0 + cz;
  const int qrow0 = blockIdx.y*128 + (wv>>1)*64;   // query rows (A side, dist row)
  const int crow0 = blockIdx.x*64 + (wv&1)*32;     // candidate rows (B side, dist col)
  const size_t brg = (size_t)b*(NN/16);
  f32x4 acc[4][2];
  #pragma unroll
  for(int m=0;m<4;m++){
    #pragma unroll
    for(int n=0;n<2;n++) acc[m][n] = (f32x4){0.f,0.f,0.f,0.f};
  }
  const size_t abase = (brg + (qrow0>>4))*KT*512 + (size_t)l*8;
  const size_t bbase = (brg + (crow0>>4))*KT*512 + (size_t)l*8;
  for(int kt=0; kt<KT; kt++){
    short8 Ah[4], Am[4], Al[4], Bh[2], Bm[2], Bl[2];
    #pragma unroll
    for(int m=0;m<4;m++){
      size_t o = abase + (size_t)(m*KT + kt)*512;
      Ah[m] = *(const short8*)(xh + o);
      Am[m] = *(const short8*)(xm + o);
      Al[m] = *(const short8*)(xl + o);
    }
    #pragma unroll
    for(int n=0;n<2;n++){
      size_t o = bbase + (size_t)(n*KT + kt)*512;
      Bh[n] = *(const short8*)(xh + o);
      Bm[n] = *(const short8*)(xm + o);
      Bl[n] = *(const short8*)(xl + o);
    }
    #pragma unroll
    for(int m=0;m<4;m++){
      #pragma unroll
      for(int n=0;n<2;n++){
        MFMA6(acc[m][n], Ah[m], Am[m], Al[m], Bh[n], Bm[n], Bl[n])
      }
    }
  }
  const float* xxb = xx + (size_t)b*NN;
  float xxc[2];
  #pragma unroll
  for(int n=0;n<2;n++) xxc[n] = xxb[crow0 + n*16 + lr];
  #pragma unroll
  for(int m=0;m<4;m++){
    #pragma unroll
    for(int r=0;r<4;r++){
      int qr = qrow0 + m*16 + 4*lg + r;
      float xq = xxb[qr];
      float* dp = dist + ((size_t)cz*NN + qr)*NN + crow0;
      #pragma unroll
      for(int n=0;n<2;n++) dp[n*16 + lr] = (2.f*acc[m][n][r] - xq) - xxc[n];
    }
  }
}

// Wave-cooperative top-20: FULL-ROW warm start (max-of-32, 2048 cands) + collision-only insertions.
__launch_bounds__(256) __global__ void sel_k(const float* __restrict__ dist, int* __restrict__ id,
                                             int b0, int nrows){
  const int w = (blockIdx.x*256 + threadIdx.x) >> 6;
  const int lane = threadIdx.x & 63;
  if(w >= nrows) return;
  const float* dr = dist + (size_t)w*NN;
  float cd0[32];
  #pragma unroll
  for(int g=0; g<8; g++){
    float4 c = *(const float4*)&dr[g*256 + 4*lane];
    cd0[g*4+0]=c.x; cd0[g*4+1]=c.y; cd0[g*4+2]=c.z; cd0[g*4+3]=c.w;
  }
  int jbest = 0; float v = cd0[0];
  #pragma unroll
  for(int j=1;j<32;j++){ if(cd0[j] > v){ v = cd0[j]; jbest = j; } }
  int vi = (jbest>>2)*256 + 4*lane + (jbest&3);
  BITONIC64_DESC(v, vi)
  float lv = (lane < KK) ? v : -INFINITY;
  int   li = (lane < KK) ? vi : 0;
  float theta = readlane_f(lv, KK-1);
  #pragma unroll
  for(int j=0;j<32;j++){
    float cand = (j == jbest) ? -INFINITY : cd0[j];
    unsigned long long bal = __ballot(cand > theta);
    while(bal){
      int bpos = __ffsll((unsigned long long)bal) - 1;
      bal &= bal - 1;
      float cv = readlane_f(cand, bpos);
      if(cv > theta){
        int ci = (j>>2)*256 + 4*bpos + (j&3);
        INSERT_CAND(cv, ci)
      }
    }
  }
  if(lane < KK) id[((size_t)b0*NN + w)*KK + lane] = li;
}

// L1 fused: inline C=3 distances + inline sqnorm, full-row max-of-32 warm start.
__launch_bounds__(256) __global__ void sel3_k(const float* __restrict__ X, int* __restrict__ id){
  const int gw = (blockIdx.x*256 + threadIdx.x) >> 6;
  const int lane = threadIdx.x & 63;
  const int b = gw >> 11, n = gw & 2047;
  const float* Xb  = X + (size_t)b*NN*3;
  const float x0v = Xb[n*3], x1v = Xb[n*3+1], x2v = Xb[n*3+2];
  float xxn = 0.f;
  xxn = fmaf(x0v, x0v, xxn); xxn = fmaf(x1v, x1v, xxn); xxn = fmaf(x2v, x2v, xxn);
  float cd[32];
  #pragma unroll
  for(int g=0; g<8; g++){
    const float* p = Xb + (size_t)(g*256 + 4*lane)*3;
    float4 va = *(const float4*)p;
    float4 vb = *(const float4*)(p+4);
    float4 vc = *(const float4*)(p+8);
    float cx[4] = {va.x, va.w, vb.z, vc.y};
    float cy[4] = {va.y, vb.x, vb.w, vc.z};
    float cz[4] = {va.z, vb.y, vc.x, vc.w};
    #pragma unroll
    for(int j=0;j<4;j++){
      float s = 0.f;
      s = fmaf(x0v, cx[j], s); s = fmaf(x1v, cy[j], s); s = fmaf(x2v, cz[j], s);
      float xxm = 0.f;
      xxm = fmaf(cx[j], cx[j], xxm); xxm = fmaf(cy[j], cy[j], xxm); xxm = fmaf(cz[j], cz[j], xxm);
      cd[g*4 + j] = (2.f*s - xxn) - xxm;
    }
  }
  int jbest = 0; float v = cd[0];
  #pragma unroll
  for(int j=1;j<32;j++){ if(cd[j] > v){ v = cd[j]; jbest = j; } }
  int vi = (jbest>>2)*256 + 4*lane + (jbest&3);
  BITONIC64_DESC(v, vi)
  float lv = (lane < KK) ? v : -INFINITY;
  int   li = (lane < KK) ? vi : 0;
  float theta = readlane_f(lv, KK-1);
  #pragma unroll
  for(int j=0;j<32;j++){
    float cand = (j == jbest) ? -INFINITY : cd[j];
    unsigned long long bal = __ballot(cand > theta);
    while(bal){
      int bpos = __ffsll((unsigned long long)bal) - 1;
      bal &= bal - 1;
      float cv = readlane_f(cand, bpos);
      if(cv > theta){
        int ci = (j>>2)*256 + 4*bpos + (j&3);
        INSERT_CAND(cv, ci)
      }
    }
  }
  if(lane < KK) id[(size_t)gw*KK + lane] = li;
}

// ---------------- qp ----------------
// L1: writes interleaved qp[row][128]: q at 0..63, p at 64..127
__launch_bounds__(256) __global__ void qp3_k(const float* X, const float* W, float* qp){
  const int t   = blockIdx.x*256 + threadIdx.x;
  const int row = t >> 3;
  const int c0  = (t & 7) * 8;
  float xn[3];
  #pragma unroll
  for(int c=0;c<3;c++) xn[c] = X[(size_t)row*3 + c];
  for(int oi=c0; oi<c0+8; oi++){
    const float* w = W + (size_t)oi*6;
    float aq=0.f, ap=0.f;
    #pragma unroll
    for(int c=0;c<3;c++){ aq = fmaf(xn[c], w[c], aq); ap = fmaf(xn[c], w[3+c], ap); }
    qp[(size_t)row*128 + oi]      = aq;
    qp[(size_t)row*128 + 64 + oi] = ap;
  }
}

// qp via split-bf16 MFMA: qp[BN][W2C] = Xsplit * WTsplit.
// FULL=true: 6-product (KNN-critical layers 2/3). FULL=false: 3-product (terminal layer 4).
// Grid (BN/128, W2C/64); block 128r x 64c; wave 64r x 32c.
template<int KT, int W2C, bool FULL>
__launch_bounds__(256) __global__ void qp_mfma_k(const u16* __restrict__ xh, const u16* __restrict__ xm,
    const u16* __restrict__ xl,
    const u16* __restrict__ wh, const u16* __restrict__ wm, const u16* __restrict__ wl,
    float* __restrict__ qp){
  const int tid = threadIdx.x;
  const int l  = tid & 63, wv = tid >> 6;
  const int lg = l >> 4, lr = l & 15;
  const int row0 = blockIdx.x*128 + (wv>>1)*64;
  const int col0 = blockIdx.y*64 + (wv&1)*32;
  f32x4 acc[4][2];
  #pragma unroll
  for(int m=0;m<4;m++){
    #pragma unroll
    for(int n=0;n<2;n++) acc[m][n] = (f32x4){0.f,0.f,0.f,0.f};
  }
  const size_t abase = (size_t)(row0>>4)*KT*512 + (size_t)l*8;
  const size_t bbase = (size_t)(col0>>4)*KT*512 + (size_t)l*8;
  for(int kt=0; kt<KT; kt++){
    short8 Ah[4], Am[4], Al[4], Bh[2], Bm[2], Bl[2];
    #pragma unroll
    for(int m=0;m<4;m++){
      size_t o = abase + (size_t)(m*KT + kt)*512;
      Ah[m] = *(const short8*)(xh + o);
      Am[m] = *(const short8*)(xm + o);
      if constexpr (FULL) Al[m] = *(const short8*)(xl + o);
    }
    #pragma unroll
    for(int n=0;n<2;n++){
      size_t o = bbase + (size_t)(n*KT + kt)*512;
      Bh[n] = *(const short8*)(wh + o);
      Bm[n] = *(const short8*)(wm + o);
      if constexpr (FULL) Bl[n] = *(const short8*)(wl + o);
    }
    #pragma unroll
    for(int m=0;m<4;m++){
      #pragma unroll
      for(int n=0;n<2;n++){
        if constexpr (FULL) {
          MFMA6(acc[m][n], Ah[m], Am[m], Al[m], Bh[n], Bm[n], Bl[n])
        } else {
          MFMA3(acc[m][n], Ah[m], Am[m], Bh[n], Bm[n])
        }
      }
    }
  }
  #pragma unroll
  for(int m=0;m<4;m++){
    #pragma unroll
    for(int r=0;r<4;r++){
      int row = row0 + m*16 + 4*lg + r;
      float* dp = qp + (size_t)row*W2C + col0;
      #pragma unroll
      for(int n=0;n<2;n++) dp[n*16 + lr] = acc[m][n][r];
    }
  }
}

// Gather from interleaved qp[row][2*COUT] (q | p); base = p - q computed here.
template<int COUT>
__launch_bounds__(256) __global__ void gather_qp_k(const float* __restrict__ qp, const int* __restrict__ idx,
    const float* g, const float* bb, float* out){
  const int t  = blockIdx.x*256 + threadIdx.x;   // BN*COUT
  const int o  = t % COUT;
  const int bn = t / COUT;
  const int b  = bn >> 11;
  const int* id = idx + (size_t)bn*KK;
  float qv = qp[(size_t)bn*(2*COUT) + o];
  float pv = qp[(size_t)bn*(2*COUT) + COUT + o];
  float base = pv - qv;
  float mx = -INFINITY, mn = INFINITY;
  #pragma unroll
  for(int k=0;k<KK;k++){
    int ik = id[k];
    float v = qp[((size_t)((b<<11) + ik))*(2*COUT) + o];
    mx = fmaxf(mx, v); mn = fminf(mn, v);
  }
  float a  = g[o] * RSQ;
  float bo = bb[o];
  out[(size_t)bn*COUT + o] = lrelu((a >= 0.f ? a*(mx+base) : a*(mn+base)) + bo);
}

// ---- fallback chunked qp (cat weight layout) + chunked gather ----
template<int CIN, int COUT>
__launch_bounds__(256) __global__ void qp64T_k(const float* __restrict__ X, const float* __restrict__ WT,
                                               int cb, float* __restrict__ q, float* __restrict__ bs){
  const int t   = blockIdx.x*256 + threadIdx.x;
  const int row = t >> 3;
  const int o0  = cb + (t & 7) * 8;
  float xn[CIN];
  #pragma unroll
  for(int c=0;c<CIN;c+=4){ float4 v = *(const float4*)(X + (size_t)row*CIN + c);
    xn[c]=v.x; xn[c+1]=v.y; xn[c+2]=v.z; xn[c+3]=v.w; }
  float aq[8], ap[8];
  #pragma unroll
  for(int j=0;j<8;j++){ aq[j]=0.f; ap[j]=0.f; }
  #pragma unroll 4
  for(int c=0;c<CIN;c++){
    float xc = xn[c];
    float4 wa0 = *(const float4*)&WT[(size_t)c*(2*COUT) + o0];
    float4 wa1 = *(const float4*)&WT[(size_t)c*(2*COUT) + o0 + 4];
    float4 wb0 = *(const float4*)&WT[(size_t)c*(2*COUT) + COUT + o0];
    float4 wb1 = *(const float4*)&WT[(size_t)c*(2*COUT) + COUT + o0 + 4];
    aq[0]=fmaf(xc,wa0.x,aq[0]); aq[1]=fmaf(xc,wa0.y,aq[1]); aq[2]=fmaf(xc,wa0.z,aq[2]); aq[3]=fmaf(xc,wa0.w,aq[3]);
    aq[4]=fmaf(xc,wa1.x,aq[4]); aq[5]=fmaf(xc,wa1.y,aq[5]); aq[6]=fmaf(xc,wa1.z,aq[6]); aq[7]=fmaf(xc,wa1.w,aq[7]);
    ap[0]=fmaf(xc,wb0.x,ap[0]); ap[1]=fmaf(xc,wb0.y,ap[1]); ap[2]=fmaf(xc,wb0.z,ap[2]); ap[3]=fmaf(xc,wb0.w,ap[3]);
    ap[4]=fmaf(xc,wb1.x,ap[4]); ap[5]=fmaf(xc,wb1.y,ap[5]); ap[6]=fmaf(xc,wb1.z,ap[6]); ap[7]=fmaf(xc,wb1.w,ap[7]);
  }
  float* qpp = q  + (size_t)row*64 + (o0-cb);
  float* bpp = bs + (size_t)row*64 + (o0-cb);
  *(float4*)qpp     = make_float4(aq[0],aq[1],aq[2],aq[3]);
  *(float4*)(qpp+4) = make_float4(aq[4],aq[5],aq[6],aq[7]);
  *(float4*)bpp     = make_float4(ap[0]-aq[0],ap[1]-aq[1],ap[2]-aq[2],ap[3]-aq[3]);
  *(float4*)(bpp+4) = make_float4(ap[4]-aq[4],ap[5]-aq[5],ap[6]-aq[6],ap[7]-aq[7]);
}

template<int CFULL>
__launch_bounds__(256) __global__ void gather_chunk_k(const float* q, const float* bs, const int* idx,
    const float* g, const float* bb, int cb, float* out){
  const int t  = blockIdx.x*256 + threadIdx.x;
  const int o  = t & 63;
  const int bn = t >> 6;
  const int b  = bn >> 11;
  const int* id = idx + (size_t)bn*KK;
  float base = bs[t];
  float mx = -INFINITY, mn = INFINITY;
  #pragma unroll
  for(int k=0;k<KK;k++){
    int ik = id[k];
    float v = q[((size_t)((b<<11) + ik))*64 + o];
    mx = fmaxf(mx, v); mn = fminf(mn, v);
  }
  float a  = g[cb+o] * RSQ;
  float bo = bb[cb+o];
  out[(size_t)bn*CFULL + cb + o] = lrelu((a >= 0.f ? a*(mx+base) : a*(mn+base)) + bo);
}

// ---------------- head (fallback): fp32 GEMM-tiled cat x W5T with fused max/min ----------------
__launch_bounds__(256) __global__ void w5gemm_k(const float* __restrict__ x1, const float* __restrict__ x2,
    const float* __restrict__ x3, const float* __restrict__ x4,
    const float* __restrict__ W5T, unsigned* mxe, unsigned* mne){
  constexpr int ASTA = 92;
  constexpr int ASTB = 188;
  __shared__ __align__(16) float a_sh[16*ASTA];
  __shared__ __align__(16) float b_sh[16*ASTB];
  const int tid = threadIdx.x;
  const int otile = blockIdx.x*128;
  const int rtile = blockIdx.y*64;
  const int b     = blockIdx.z;
  const int tn = tid & 15, tm = tid >> 4;
  const int aoff = 4*tn + 4*(tn>>1);
  const size_t row0 = (size_t)b*NN + rtile;
  float acc[4][8];
  #pragma unroll
  for(int i=0;i<4;i++){
    #pragma unroll
    for(int j=0;j<8;j++) acc[i][j]=0.f;
  }
  for(int cc=0; cc<512; cc+=16){
    const float* src; int stride, coff;
    if(cc<64)      { src=x1; stride=64;  coff=cc; }
    else if(cc<128){ src=x2; stride=64;  coff=cc-64; }
    else if(cc<256){ src=x3; stride=128; coff=cc-128; }
    else           { src=x4; stride=256; coff=cc-256; }
    __syncthreads();
    { int r = tid>>2, q = tid&3;
      int pr = r + 4*(r>>3);
      float4 va = *(const float4*)&src[(row0 + r)*stride + coff + 4*q];
      a_sh[(4*q+0)*ASTA + pr]=va.x; a_sh[(4*q+1)*ASTA + pr]=va.y;
      a_sh[(4*q+2)*ASTA + pr]=va.z; a_sh[(4*q+3)*ASTA + pr]=va.w; }
    #pragma unroll
    for(int s=0;s<2;s++){
      int ii = tid + 256*s;
      int cl = ii>>5, o4 = ii&31;
      float4 vb = *(const float4*)&W5T[(size_t)(cc+cl)*512 + otile + 4*o4];
      *(float4*)&b_sh[cl*ASTB + 4*o4 + 4*(o4>>1)] = vb;
    }
    __syncthreads();
    #pragma unroll
    for(int c=0;c<16;c++){
      float4 A0 = *(const float4*)&a_sh[c*ASTA + aoff];
      float4 B0 = *(const float4*)&b_sh[c*ASTB + 12*tm];
      float4 B1 = *(const float4*)&b_sh[c*ASTB + 12*tm + 4];
      float b0v=B0.x,b1v=B0.y,b2v=B0.z,b3v=B0.w,b4v=B1.x,b5v=B1.y,b6v=B1.z,b7v=B1.w;
      float a;
      a=A0.x; FMA_ROW(0)
      a=A0.y; FMA_ROW(1)
      a=A0.z; FMA_ROW(2)
      a=A0.w; FMA_ROW(3)
    }
  }
  #pragma unroll
  for(int j=0;j<8;j++){
    float M=-INFINITY, m=INFINITY;
    #pragma unroll
    for(int i=0;i<4;i++){ M=fmaxf(M,acc[i][j]); m=fminf(m,acc[i][j]); }
    #pragma unroll
    for(int d=1; d<16; d<<=1){
      M = fmaxf(M, __shfl_xor(M, d));
      m = fminf(m, __shfl_xor(m, d));
    }
    if(tn == 0){
      int o = otile + tm*8 + j;
      atomicMax(&mxe[b*512+o], encf(M));
      atomicMin(&mne[b*512+o], encf(m));
    }
  }
}

// ---------------- head (big): split-bf16 MFMA (3-product, terminal) ----------------
// xcat 2-split (h/m only) into fragment-major tiled layout (KT=16, row space = BN).
__launch_bounds__(256) __global__ void cvt_k(const float* __restrict__ x1, const float* __restrict__ x2,
    const float* __restrict__ x3, const float* __restrict__ x4,
    u16* __restrict__ xh, u16* __restrict__ xm){
  const size_t t = (size_t)blockIdx.x*256 + threadIdx.x;   // BN*512/8 chunks
  const int l = (int)(t & 63);
  const size_t tile = t >> 6;           // rgG*16 + kt
  const int kt = (int)(tile & 15);
  const size_t rgG = tile >> 4;
  const size_t row = rgG*16 + (l & 15);
  const int col = kt*32 + ((l>>4)<<3);
  const float* src; int stride, coff;
  if(col<64)      { src=x1; stride=64;  coff=col; }
  else if(col<128){ src=x2; stride=64;  coff=col-64; }
  else if(col<256){ src=x3; stride=128; coff=col-128; }
  else            { src=x4; stride=256; coff=col-256; }
  const float* p = src + row*stride + coff;
  float4 v0 = *(const float4*)p;
  float4 v1 = *(const float4*)(p+4);
  float vs[8] = {v0.x,v0.y,v0.z,v0.w,v1.x,v1.y,v1.z,v1.w};
  ushort8 H, M;
  #pragma unroll
  for(int j=0;j<8;j++){ u16 h,m,lo; bf16split3(vs[j],h,m,lo); H[j]=h; M[j]=m; (void)lo; }
  *(ushort8*)(xh + t*8) = H;
  *(ushort8*)(xm + t*8) = M;
}

// C[16384x512] = xcat * W5^T via 3 bf16 MFMA products (hh+hm+mh, terminal-GEMM precision),
// fused per-column max/min. 64-col tiles: grid (128 rowblk, 8 colblk); A-sharing blocks
// 128 apart -> same XCD L2.
__launch_bounds__(256) __global__ void w5mfma_k(const u16* __restrict__ xh, const u16* __restrict__ xm,
    const u16* __restrict__ wh, const u16* __restrict__ wm,
    unsigned* mxe, unsigned* mne){
  const int tid = threadIdx.x;
  const int l  = tid & 63, wv = tid >> 6;
  const int lg = l >> 4, lr = l & 15;
  const int row0 = blockIdx.x*128 + (wv>>1)*64;   // M base of this wave (global BN rows)
  const int col0 = blockIdx.y*64 + (wv&1)*32;     // N base of this wave
  const int b = blockIdx.x >> 4;                  // 16 M-blocks per batch
  f32x4 acc[4][2];
  #pragma unroll
  for(int m=0;m<4;m++){
    #pragma unroll
    for(int n=0;n<2;n++) acc[m][n] = (f32x4){0.f,0.f,0.f,0.f};
  }
  const size_t abase = (size_t)(row0>>4)*16*512 + (size_t)l*8;
  const size_t bbase = (size_t)(col0>>4)*16*512 + (size_t)l*8;
  for(int kt=0; kt<16; kt++){
    short8 Ah[4], Am[4], Bh[2], Bm[2];
    #pragma unroll
    for(int m=0;m<4;m++){
      size_t o = abase + (size_t)(m*16 + kt)*512;
      Ah[m] = *(const short8*)(xh + o);
      Am[m] = *(const short8*)(xm + o);
    }
    #pragma unroll
    for(int n=0;n<2;n++){
      size_t o = bbase + (size_t)(n*16 + kt)*512;
      Bh[n] = *(const short8*)(wh + o);
      Bm[n] = *(const short8*)(wm + o);
    }
    #pragma unroll
    for(int m=0;m<4;m++){
      #pragma unroll
      for(int n=0;n<2;n++){
        MFMA3(acc[m][n], Ah[m], Am[m], Bh[n], Bm[n])
      }
    }
  }
  #pragma unroll
  for(int n=0;n<2;n++){
    float M = -INFINITY, mnv = INFINITY;
    #pragma unroll
    for(int m=0;m<4;m++){
      #pragma unroll
      for(int r=0;r<4;r++){ float v = acc[m][n][r]; M = fmaxf(M, v); mnv = fminf(mnv, v); }
    }
    M   = fmaxf(M,   __shfl_xor(M, 16));   M   = fmaxf(M,   __shfl_xor(M, 32));
    mnv = fminf(mnv, __shfl_xor(mnv, 16)); mnv = fminf(mnv, __shfl_xor(mnv, 32));
    if(lg == 0){
      int o = col0 + n*16 + lr;
      atomicMax(&mxe[b*512+o], encf(M));
      atomicMin(&mne[b*512+o], encf(mnv));
    }
  }
}

__launch_bounds__(256) __global__ void final_k(const unsigned* mxe, const unsigned* mne,
    const float* g5, const float* b5, const float* Wemb, float* out){
  const int b = blockIdx.x, t = threadIdx.x;
  __shared__ float h[512];
  for(int o=t; o<512; o+=256){
    float mx = decf(mxe[b*512+o]);
    float mn = decf(mne[b*512+o]);
    float a  = g5[o] * RSQ;
    float bo = b5[o];
    float hv = lrelu((a >= 0.f ? a*mx : a*mn) + bo);
    h[o] = hv;
    out[b*512+o] = hv;
  }
  __syncthreads();
  const float* wr = Wemb + (size_t)t*512;
  float s = 0.f;
  for(int o=0;o<512;o+=4){
    float4 w4 = *(const float4*)(wr+o);
    s = fmaf(h[o],w4.x, fmaf(h[o+1],w4.y, fmaf(h[o+2],w4.z, fmaf(h[o+3],w4.w, s))));
  }
  out[4096 + b*256 + t] = s;
}

// ---------------- launch ----------------
extern "C" void kernel_launch(void* const* d_in, const int* in_sizes, int n_in,
                              void* d_out, int out_size, void* d_ws, size_t ws_size,
                              hipStream_t stream) {
  if (ws_size < WS_END * sizeof(float)) return;
  const bool big = ws_size >= WS_BIG_END * sizeof(float);   // deterministic per call

  const float* x0   = (const float*)d_in[0];
  const float* W1   = (const float*)d_in[1];
  const float* g1   = (const float*)d_in[2];
  const float* b1   = (const float*)d_in[3];
  const float* W2   = (const float*)d_in[4];
  const float* g2   = (const float*)d_in[5];
  const float* b2   = (const float*)d_in[6];
  const float* W3   = (const float*)d_in[7];
  const float* g3   = (const float*)d_in[8];
  const float* b3   = (const float*)d_in[9];
  const float* W4   = (const float*)d_in[10];
  const float* g4   = (const float*)d_in[11];
  const float* b4   = (const float*)d_in[12];
  const float* W5   = (const float*)d_in[13];
  const float* g5   = (const float*)d_in[14];
  const float* b5   = (const float*)d_in[15];
  const float* Wemb = (const float*)d_in[16];

  float* ws = (float*)d_ws;
  float* xx = ws + OFF_XX;
  float* x1 = ws + OFF_X1;  float* x2 = ws + OFF_X2;
  float* x3 = ws + OFF_X3;  float* x4 = ws + OFF_X4;
  float* qpS = ws + OFF_SC;               // L1 qp (width 128) + fallback chunked q/bs
  float* bsS = ws + OFF_SC + (size_t)BN*64;
  int*   id = (int*)(ws + OFF_ID);
  float* W5Tf = ws + OFF_W5T;
  unsigned* mxe = (unsigned*)(ws + OFF_MX);
  unsigned* mne = (unsigned*)(ws + OFF_MN);
  float* WT2 = ws + OFF_WT2;
  float* WT3 = ws + OFF_WT3;
  float* WT4 = ws + OFF_WT4;
  float* distD = ws + OFF_X3;   // fallback dual-batch
  float* distS = ws + OFF_X4;   // fallback single-batch
  float* distB = ws + OFF_BIG;  // big: 4-batch dist chunk, then reused as qp buffer / bf16 xcat
  u16* w5h = (u16*)(ws + OFF_SC + (size_t)BN*128);   // SC tail (free in both paths): 3x256KB
  u16* w5m = w5h + 512*512;
  u16* w5l = w5m + 512*512;
  u16* wts = (u16*)W5Tf;         // big path: tiled WT splits live in the (unused) W5T region
  float* out = (float*)d_out;

  prep_k<<<1024,256,0,stream>>>(W5, W2, W3, W4, W5Tf, WT2, WT3, WT4,
                                w5h, w5m, w5l, wts, mxe, mne, big ? 1 : 0);

  // layer 1 (3 -> 64)
  sel3_k<<<BN*64/256,256,0,stream>>>(x0, id);
  qp3_k<<<BN*8/256,256,0,stream>>>(x0, W1, qpS);
  gather_qp_k<64><<<BN*64/256,256,0,stream>>>(qpS, id, g1, b1, x1);

  if(big){
    float* qpB = distB;                      // reuse dist region post-sel
    // split scratch lives in x4 region (dead until layer-4 gather)
    u16* sh = (u16*)x4;
    // layer 2 (CIN=64 -> COUT=64, qp width 128)
    { u16* sm = sh + (size_t)BN*64; u16* sl = sm + (size_t)BN*64;
      sqnorm_k<64><<<BN/256,256,0,stream>>>(x1, xx);
      split_k<64><<<BN*64/8/256,256,0,stream>>>(x1, sh, sm, sl);
      for(int c0=0;c0<BB;c0+=4){
        mfma_dist_k<64><<<dim3(32,16,4),256,0,stream>>>(sh, sm, sl, xx, distB, c0);
        sel_k<<<(4*NN)/4,256,0,stream>>>(distB, id, c0, 4*NN);
      }
      qp_mfma_k<2,128,true><<<dim3(BN/128,2),256,0,stream>>>(sh, sm, sl,
          wts+WTS_2H, wts+WTS_2M, wts+WTS_2L, qpB);
      gather_qp_k<64><<<BN*64/256,256,0,stream>>>(qpB, id, g2, b2, x2); }
    // layer 3 (64 -> 128, qp width 256)
    { u16* sm = sh + (size_t)BN*64; u16* sl = sm + (size_t)BN*64;
      sqnorm_k<64><<<BN/256,256,0,stream>>>(x2, xx);
      split_k<64><<<BN*64/8/256,256,0,stream>>>(x2, sh, sm, sl);
      for(int c0=0;c0<BB;c0+=4){
        mfma_dist_k<64><<<dim3(32,16,4),256,0,stream>>>(sh, sm, sl, xx, distB, c0);
        sel_k<<<(4*NN)/4,256,0,stream>>>(distB, id, c0, 4*NN);
      }
      qp_mfma_k<2,256,true><<<dim3(BN/128,4),256,0,stream>>>(sh, sm, sl,
          wts+WTS_3H, wts+WTS_3M, wts+WTS_3L, qpB);
      gather_qp_k<128><<<BN*128/256,256,0,stream>>>(qpB, id, g3, b3, x3); }
    // layer 4 (128 -> 256, qp width 512): terminal for KNN -> 3-product qp
    { u16* sm = sh + (size_t)BN*128; u16* sl = sm + (size_t)BN*128;
      sqnorm_k<128><<<BN/256,256,0,stream>>>(x3, xx);
      split_k<128><<<BN*128/8/256,256,0,stream>>>(x3, sh, sm, sl);
      for(int c0=0;c0<BB;c0+=4){
        mfma_dist_k<128><<<dim3(32,16,4),256,0,stream>>>(sh, sm, sl, xx, distB, c0);
        sel_k<<<(4*NN)/4,256,0,stream>>>(distB, id, c0, 4*NN);
      }
      qp_mfma_k<4,512,false><<<dim3(BN/128,8),256,0,stream>>>(sh, sm, sl,
          wts+WTS_4H, wts+WTS_4M, wts+WTS_4L, qpB);
      gather_qp_k<256><<<BN*256/256,256,0,stream>>>(qpB, id, g4, b4, x4); }
    // head: bf16 2-split (tiled) + 3-product MFMA (terminal-GEMM precision)
    u16* xh = (u16*)(ws + OFF_XCAT);
    u16* xm = xh + (size_t)BN*512;
    cvt_k<<<BN*512/8/256,256,0,stream>>>(x1, x2, x3, x4, xh, xm);
    w5mfma_k<<<dim3(128,8),256,0,stream>>>(xh, xm, w5h, w5m, mxe, mne);
  } else {
    // fallback: chunked (R12 structure, cat weight layout)
    sqnorm_k<64><<<BN/256,256,0,stream>>>(x1, xx);
    for(int r=0;r<4;r++){
      gemm_dist_k<64><<<dim3(16,16,2),256,0,stream>>>(x1, xx, distD, 2*r);
      sel_k<<<(2*NN)/4,256,0,stream>>>(distD, id, 2*r, 2*NN);
    }
    qp64T_k<64,64><<<BN*8/256,256,0,stream>>>(x1, WT2, 0, qpS, bsS);
    gather_chunk_k<64><<<BN*64/256,256,0,stream>>>(qpS, bsS, id, g2, b2, 0, x2);

    sqnorm_k<64><<<BN/256,256,0,stream>>>(x2, xx);
    for(int r=0;r<4;r++){
      gemm_dist_k<64><<<dim3(16,16,2),256,0,stream>>>(x2, xx, distD, 2*r);
      sel_k<<<(2*NN)/4,256,0,stream>>>(distD, id, 2*r, 2*NN);
    }
    for(int cb=0; cb<128; cb+=64){
      qp64T_k<64,128><<<BN*8/256,256,0,stream>>>(x2, WT3, cb, qpS, bsS);
      gather_chunk_k<128><<<BN*64/256,256,0,stream>>>(qpS, bsS, id, g3, b3, cb, x3);
    }

    sqnorm_k<128><<<BN/256,256,0,stream>>>(x3, xx);
    for(int r=0;r<8;r++){
      gemm_dist_k<128><<<dim3(16,16,1),256,0,stream>>>(x3, xx, distS, r);
      sel_k<<<NN/4,256,0,stream>>>(distS, id, r, NN);
    }
    for(int cb=0; cb<256; cb+=64){
      qp64T_k<128,256><<<BN*8/256,256,0,stream>>>(x3, WT4, cb, qpS, bsS);
      gather_chunk_k<256><<<BN*64/256,256,0,stream>>>(qpS, bsS, id, g4, b4, cb, x4);
    }
    w5gemm_k<<<dim3(4,32,8),256,0,stream>>>(x1, x2, x3, x4, W5Tf, mxe, mne);
  }

  final_k<<<BB,256,0,stream>>>(mxe, mne, g5, b5, Wemb, out);
}